// Round 13
// baseline (160.589 us; speedup 1.0000x reference)
//
#include <hip/hip_runtime.h>
#include <math.h>

#define BB 2
#define DD 128
#define HH 256
#define WW 256
#define KK 4
#define HWC (HH*WW)
#define SROW2 320   // d-slice stride in S (fused fallback kernels)

typedef unsigned int u32;
typedef unsigned short ushort;
typedef __attribute__((ext_vector_type(8))) short bf16x8;
typedef __attribute__((ext_vector_type(4))) float f32x4;

// ws float layout
#define OA_OFF    0
#define WTT_OFF   1572864
#define WP_OFF    1589248
#define STATS_OFF 1603072
#define PART_OFF  1603392
#define BEVT_OFF  1605440       // full3: bevtb bf16 (16.8M ushort); tier2: f32 bevt
#define PACC_OFF  18382656
#define PART2_OFF PACC_OFF      // full3: k2f block stats (2*128*4096 f32 = 4MB) - not aliasing bevtb
#define WBF_OFF   26771264      // proj W bf16
#define WCB_OFF   26779456      // conv W bf16 padded: 9*16*128 ushort
#define WS_NEED_BEVT  ((size_t)PACC_OFF * 4)
#define WS_NEED_FULL3 ((size_t)(WCB_OFF + 9216) * 4)

__device__ __forceinline__ u32 f2bf(float x) {
    u32 u = __builtin_bit_cast(u32, x);
    return (u + 0x7fffu + ((u >> 16) & 1u)) >> 16;
}
__device__ __forceinline__ u32 pkbf(float a, float b) {
    return f2bf(a) | (f2bf(b) << 16);
}
__device__ __forceinline__ float bflo(u32 d) { return __builtin_bit_cast(float, d << 16); }
__device__ __forceinline__ float bfhi(u32 d) { return __builtin_bit_cast(float, d & 0xffff0000u); }

// ---------------- Kernel 0: weight prep (fallback tiers only) ----------------
__global__ __launch_bounds__(256) void k0_prep(
    const float* __restrict__ projw, const float* __restrict__ offw,
    const float* __restrict__ wtw, float* __restrict__ wtT, float* __restrict__ wp)
{
    int idx = blockIdx.x * 256 + threadIdx.x;
    if (idx < 16384) {
        int d = idx >> 7, o = idx & 127;
        wtT[d * 128 + o] = projw[o * 128 + d];
    }
    if (idx < 13824) {
        int c = idx / 108; int r = idx % 108; int o = r / 9; int t = r % 9;
        wp[idx] = (o < 8) ? offw[(o*128 + c)*9 + t] : wtw[((o-8)*128 + c)*9 + t];
    }
}

// ---------------- Kernel 0bc: bf16 weight prep (proj + conv), merged ----------------
__global__ __launch_bounds__(256) void k0bc(
    const float* __restrict__ projw, const float* __restrict__ offw,
    const float* __restrict__ wtw, ushort* __restrict__ wbf,
    ushort* __restrict__ wcb)
{
    int idx = blockIdx.x * 256 + threadIdx.x;
    if (idx < 16384) wbf[idx] = (ushort)f2bf(projw[idx]);
    if (idx < 18432) {
        int tap = idx >> 11;
        int rem = idx & 2047;
        int oo = rem >> 7, c = rem & 127;
        float v = 0.f;
        if (oo < 8)       v = offw[(oo*128 + c)*9 + tap];
        else if (oo < 12) v = wtw[((oo-8)*128 + c)*9 + tap];
        wcb[idx] = (ushort)f2bf(v);
    }
}

// ---------------- Kernel Tb: NCHW f32 -> NHWC bf16 ----------------
__global__ __launch_bounds__(256) void k2t_bf(
    const float* __restrict__ bev, ushort* __restrict__ bevtb)
{
    __shared__ float T[64 * 128];
    int tid = threadIdx.x;
    int bidx = blockIdx.x;
    int b = bidx >> 10;
    int rem = bidx & 1023;
    int yrow = rem >> 2;
    int x0 = (rem & 3) << 6;

    const float* src = bev + ((size_t)b * DD) * HWC + (size_t)yrow * WW + x0;
    #pragma unroll 4
    for (int k = 0; k < 32; k++) {
        int flat = k * 256 + tid;
        int d = flat >> 6, xl = flat & 63;
        float v = src[(size_t)d * HWC + xl];
        T[xl * 128 + (((d >> 2) ^ (xl & 31)) << 2) + (d & 3)] = v;
    }
    __syncthreads();
    ushort* dst = bevtb + (((size_t)b * HH + yrow) * WW + x0) * 128;
    #pragma unroll 4
    for (int k = 0; k < 8; k++) {
        int flat = k * 256 + tid;
        int d4 = flat & 31, xl = (flat >> 5) & 63;
        float4 v = *(const float4*)&T[xl * 128 + ((d4 ^ (xl & 31)) << 2)];
        uint2 pk;
        pk.x = pkbf(v.x, v.y);
        pk.y = pkbf(v.z, v.w);
        *(uint2*)(dst + (size_t)xl * 128 + (d4 << 2)) = pk;
    }
}

// ---------------- Kernel 1m: 3x3 convs as implicit-GEMM MFMA, LDS-staged ----------------
__global__ __launch_bounds__(256) void k1m_conv_mfma(
    const ushort* __restrict__ bevtb, const ushort* __restrict__ wcb,
    const float* __restrict__ offb, const float* __restrict__ wtb,
    float* __restrict__ oa)
{
    __shared__ uint4 lds4[3168];   // 3 rows x 66 px x 16 slots x 16B = 50688 B

    int tid = threadIdx.x;
    int wv = tid >> 6;
    int l = tid & 63;
    int lm = l & 15, lk = l >> 4;
    int wgid = blockIdx.x;
    int lin = (wgid & 7) * 256 + (wgid >> 3);   // bijective XCD-contiguous remap
    int b = lin >> 10;
    int i = (lin >> 2) & 255;
    int jt = lin & 3;
    int x0 = jt * 64;

    const ushort* bb = bevtb + (size_t)b * HWC * 128;
    for (int z = tid; z < 3168; z += 256) {
        int row = z / 1056;
        int rem = z - row * 1056;
        int pl = rem >> 4;
        int q  = rem & 15;
        int yy = i - 1 + row;
        int x  = x0 - 1 + pl;
        bool ok = ((unsigned)yy < HH) && ((unsigned)x < WW);
        uint4 v = make_uint4(0u, 0u, 0u, 0u);
        if (ok) v = *(const uint4*)(bb + ((size_t)(yy * WW + x) << 7) + q * 8);
        lds4[row * 1056 + pl * 16 + (q ^ (pl & 15))] = v;
    }
    __syncthreads();

    f32x4 acc = (f32x4)(0.f);
    #pragma unroll
    for (int dy = 0; dy < 3; dy++) {
        #pragma unroll
        for (int dx = 0; dx < 3; dx++) {
            int pl = wv * 16 + lm + dx;
            const uint4* bp = &lds4[dy * 1056 + pl * 16];
            int sx = pl & 15;
            const ushort* ap = wcb + (size_t)((dy*3 + dx) * 16 + lm) * 128 + lk * 8;
            #pragma unroll
            for (int kk = 0; kk < 4; kk++) {
                bf16x8 bfr = *(const bf16x8*)&bp[(kk*4 + lk) ^ sx];
                bf16x8 afr = *(const bf16x8*)(ap + kk * 32);
                acc = __builtin_amdgcn_mfma_f32_16x16x32_bf16(afr, bfr, acc, 0, 0, 0);
            }
        }
    }

    float v[4];
    #pragma unroll
    for (int r = 0; r < 4; r++) v[r] = acc[r];

    int j = x0 + wv * 16 + lm;
    if (lk < 2) {
        #pragma unroll
        for (int r = 0; r < 4; r++) v[r] += offb[lk*4 + r];   // OFFSET_SCALE = 1.0
    } else if (lk == 2) {
        float l4[4];
        #pragma unroll
        for (int r = 0; r < 4; r++) l4[r] = v[r] + wtb[r];
        float m = fmaxf(fmaxf(l4[0], l4[1]), fmaxf(l4[2], l4[3]));
        float e[4]; float se = 0.f;
        #pragma unroll
        for (int r = 0; r < 4; r++) { e[r] = expf(l4[r] - m); se += e[r]; }
        float inv = 1.f / se;
        #pragma unroll
        for (int r = 0; r < 4; r++) v[r] = e[r] * inv;
    }
    if (lk < 3) {
        size_t basep = (size_t)b * 12 * HWC + (size_t)i * WW + j;
        #pragma unroll
        for (int r = 0; r < 4; r++)
            oa[basep + (size_t)(lk*4 + r) * HWC] = v[r];
    }
}

// ---------------- Kernel 2f: FUSED sample + 1x1 MFMA proj + BN stats ----------------
// R12 post-mortem: VGPR=72 capped occupancy at 7 waves/SIMD -> gather latency-bound
// at 61us (floor ~14+GEMM).  Fix: thread = (pixel, d-EIGHTH): accumulators 32->16 f32,
// gather loads 64->32/thread; block = 32 px (8KB LDS), grid 4096.  Per tap, fixed-c
// instr: 8 q8-lanes read 128B contiguous (2 full lines/px) - same fully-consumed-line
// property.  GEMM de-hoisted: per-ot a4[4] (16 VGPR), bfr one-at-a-time from LDS.
// Channel<->slot mapping identical to proven k2b (slot kk*4+lk <-> ch lk*8+kk*32).
__global__ __launch_bounds__(256) void k2f_sample_proj(
    const ushort* __restrict__ bevtb, const float* __restrict__ oa,
    const ushort* __restrict__ wbf, float* __restrict__ y,
    float* __restrict__ part2)
{
    __shared__ uint4 P[32 * 16];   // 8 KB

    int tid = threadIdx.x;
    int wgid = blockIdx.x;                       // 0..4095
    int lin = (wgid & 7) * 512 + (wgid >> 3);    // bijective XCD-contiguous remap
    int b = lin >> 11;
    int pix0 = (lin & 2047) << 5;                // 32 px per block

    // ---- gather phase: thread = (pixel, d-eighth) ----
    int q8 = tid & 7;
    int pixl = tid >> 3;                         // 0..31
    int pix = pix0 + pixl;
    int p = pix >> 8;
    int q = pix & 255;

    const float* ob = oa + (size_t)b * 12 * HWC + (size_t)p * WW + q;
    unsigned pa[8]; float cw[16];
    #pragma unroll
    for (int k = 0; k < 4; k++) {
        float dx = ob[(size_t)(2*k)   * HWC];
        float dy = ob[(size_t)(2*k+1) * HWC];
        float a  = ob[(size_t)(8+k)   * HWC];
        float x  = fminf(fmaxf((float)p + dx, 0.f), (float)(WW-1));
        float yv = fminf(fmaxf((float)q + dy, 0.f), (float)(HH-1));
        float x0f = floorf(x); float y0f = floorf(yv);
        int x0 = (int)x0f; int y0 = (int)y0f;
        int x1 = min(x0 + 1, WW - 1); int y1 = min(y0 + 1, HH - 1);
        float wx = x - x0f; float wy = yv - y0f;
        pa[k*2+0] = (unsigned)(y0*WW + x0) | ((unsigned)(y0*WW + x1) << 16);
        pa[k*2+1] = (unsigned)(y1*WW + x0) | ((unsigned)(y1*WW + x1) << 16);
        cw[k*4+0] = a * (1.f - wx) * (1.f - wy);
        cw[k*4+1] = a * wx * (1.f - wy);
        cw[k*4+2] = a * (1.f - wx) * wy;
        cw[k*4+3] = a * wx * wy;
    }

    // thread owns channels {c*64 + q8*8 .. +8} for c=0,1
    const ushort* bt = bevtb + (size_t)b * HWC * 128 + q8 * 8;

    float s[2][8];
    #pragma unroll
    for (int c = 0; c < 2; c++)
        #pragma unroll
        for (int e = 0; e < 8; e++) s[c][e] = 0.f;

    #pragma unroll
    for (int t = 0; t < 16; t++) {
        unsigned a01 = pa[t >> 1];
        unsigned gp = (t & 1) ? (a01 >> 16) : (a01 & 0xffffu);
        const ushort* tp = bt + ((size_t)gp << 7);
        float w = cw[t];
        #pragma unroll
        for (int c = 0; c < 2; c++) {
            uint4 v = *(const uint4*)(tp + c * 64);
            s[c][0] = fmaf(w, bflo(v.x), s[c][0]);
            s[c][1] = fmaf(w, bfhi(v.x), s[c][1]);
            s[c][2] = fmaf(w, bflo(v.y), s[c][2]);
            s[c][3] = fmaf(w, bfhi(v.y), s[c][3]);
            s[c][4] = fmaf(w, bflo(v.z), s[c][4]);
            s[c][5] = fmaf(w, bfhi(v.z), s[c][5]);
            s[c][6] = fmaf(w, bflo(v.w), s[c][6]);
            s[c][7] = fmaf(w, bfhi(v.w), s[c][7]);
        }
    }

    int sxr = pixl & 15;
    #pragma unroll
    for (int c = 0; c < 2; c++) {
        uint4 pk;
        pk.x = pkbf(s[c][0], s[c][1]);
        pk.y = pkbf(s[c][2], s[c][3]);
        pk.z = pkbf(s[c][4], s[c][5]);
        pk.w = pkbf(s[c][6], s[c][7]);
        P[pixl * 16 + ((c * 8 + q8) ^ sxr)] = pk;   // slot s holds ch s*8..s*8+8
    }
    __syncthreads();

    // ---- GEMM phase ----
    int wv = tid >> 6;
    int l = tid & 63;
    int lm = l & 15, lk = l >> 4;
    int o0 = wv << 5;

    f32x4 acc[2][2];
    #pragma unroll
    for (int ot = 0; ot < 2; ot++)
        #pragma unroll
        for (int nt = 0; nt < 2; nt++)
            acc[ot][nt] = (f32x4)(0.f);

    #pragma unroll
    for (int ot = 0; ot < 2; ot++) {
        const ushort* ap = wbf + (size_t)(o0 + ot * 16 + lm) * 128 + lk * 8;
        bf16x8 a4[4];
        #pragma unroll
        for (int kk = 0; kk < 4; kk++)
            a4[kk] = *(const bf16x8*)(ap + kk * 32);
        #pragma unroll
        for (int nt = 0; nt < 2; nt++) {
            int row = nt * 16 + lm;
            #pragma unroll
            for (int kk = 0; kk < 4; kk++) {
                bf16x8 bfr = *(const bf16x8*)&P[row * 16 + ((kk * 4 + lk) ^ lm)];
                acc[ot][nt] = __builtin_amdgcn_mfma_f32_16x16x32_bf16(
                    a4[kk], bfr, acc[ot][nt], 0, 0, 0);
            }
        }
    }

    #pragma unroll
    for (int ot = 0; ot < 2; ot++)
        #pragma unroll
        for (int nt = 0; nt < 2; nt++)
            #pragma unroll
            for (int r = 0; r < 4; r++)
                y[((size_t)b * DD + o0 + ot * 16 + lk * 4 + r) * HWC + pix0 + nt * 16 + lm]
                    = acc[ot][nt][r];

    // ---- fused BN partial stats over this block's 32 pixels ----
    float sm[2][4], sq[2][4];
    #pragma unroll
    for (int ot = 0; ot < 2; ot++)
        #pragma unroll
        for (int r = 0; r < 4; r++) { sm[ot][r] = 0.f; sq[ot][r] = 0.f; }
    #pragma unroll
    for (int ot = 0; ot < 2; ot++)
        #pragma unroll
        for (int nt = 0; nt < 2; nt++)
            #pragma unroll
            for (int r = 0; r < 4; r++) {
                float v = acc[ot][nt][r];
                sm[ot][r] += v;
                sq[ot][r] = fmaf(v, v, sq[ot][r]);
            }
    #pragma unroll
    for (int m = 1; m < 16; m <<= 1) {
        #pragma unroll
        for (int ot = 0; ot < 2; ot++)
            #pragma unroll
            for (int r = 0; r < 4; r++) {
                sm[ot][r] += __shfl_xor(sm[ot][r], m);
                sq[ot][r] += __shfl_xor(sq[ot][r], m);
            }
    }
    if (lm == 0) {
        #pragma unroll
        for (int ot = 0; ot < 2; ot++)
            #pragma unroll
            for (int r = 0; r < 4; r++) {
                int o = o0 + ot * 16 + lk * 4 + r;
                part2[(size_t)o * 4096 + wgid] = sm[ot][r];
                part2[(size_t)128 * 4096 + (size_t)o * 4096 + wgid] = sq[ot][r];
            }
    }
}

// ---------------- Kernel 3b': finalize BN from k2f block partials ----------------
__global__ __launch_bounds__(256) void k3b_finalize2(
    const float* __restrict__ part2, const float* __restrict__ gamma,
    const float* __restrict__ beta, float* __restrict__ stats)
{
    int o = blockIdx.x; int tid = threadIdx.x;
    const float* ps = part2 + (size_t)o * 4096;
    const float* pq = part2 + (size_t)128 * 4096 + (size_t)o * 4096;
    double s = 0.0, s2 = 0.0;
    for (int i = tid; i < 4096; i += 256) { s += (double)ps[i]; s2 += (double)pq[i]; }
    __shared__ double ls[256], ls2[256];
    ls[tid] = s; ls2[tid] = s2;
    __syncthreads();
    for (int off = 128; off > 0; off >>= 1) {
        if (tid < off) { ls[tid] += ls[tid+off]; ls2[tid] += ls2[tid+off]; }
        __syncthreads();
    }
    if (tid == 0) {
        double N = (double)(BB * HWC);
        double mean = ls[0] / N;
        double var = ls2[0] / N - mean * mean;
        double invs = 1.0 / sqrt(var + 1e-5);
        double g = (double)gamma[o];
        stats[o*2]   = (float)(g * invs);
        stats[o*2+1] = (float)((double)beta[o] - mean * g * invs);
    }
}

// ---------------- Kernel 1 (tier2 fallback): full 128-channel conv ----------------
__global__ __launch_bounds__(256) void k1_convs(
    const float* __restrict__ bev, const float* __restrict__ wp,
    const float* __restrict__ offb, const float* __restrict__ wtb,
    float* __restrict__ oa)
{
    __shared__ float rows[2][3][260];
    int tid = threadIdx.x;
    int p = blockIdx.x;
    int b = p / HH; int i = p % HH; int j = tid;
    const float* bb = bev + (size_t)b * DD * HWC;

    if (tid < 12) { int bf = tid / 6, r = tid % 6; rows[bf][r >> 1][(r & 1) ? 257 : 0] = 0.f; }
    #pragma unroll
    for (int l = 0; l < 3; l++) {
        int yy = i + l - 1;
        rows[0][l][1 + tid] = ((unsigned)yy < HH) ? bb[yy * WW + tid] : 0.f;
    }
    __syncthreads();

    float acc[12];
    #pragma unroll
    for (int o = 0; o < 12; o++) acc[o] = 0.f;

    for (int c = 0; c < 128; c++) {
        int cb = c & 1, nb = cb ^ 1;
        float rv[3];
        if (c < 127) {
            const float* pln = bb + (size_t)(c + 1) * HWC;
            #pragma unroll
            for (int l = 0; l < 3; l++) {
                int yy = i + l - 1;
                rv[l] = ((unsigned)yy < HH) ? pln[yy * WW + tid] : 0.f;
            }
        }
        float v[9];
        #pragma unroll
        for (int dy = 0; dy < 3; dy++)
            #pragma unroll
            for (int dx = 0; dx < 3; dx++)
                v[dy*3 + dx] = rows[cb][dy][tid + dx];
        const float* wc = wp + c * 108;
        #pragma unroll
        for (int o = 0; o < 12; o++) {
            float s = acc[o];
            #pragma unroll
            for (int t = 0; t < 9; t++) s = fmaf(wc[o*9 + t], v[t], s);
            acc[o] = s;
        }
        if (c < 127) {
            #pragma unroll
            for (int l = 0; l < 3; l++) rows[nb][l][1 + tid] = rv[l];
        }
        __syncthreads();
    }

    float outv[12];
    #pragma unroll
    for (int o = 0; o < 8; o++) outv[o] = acc[o] + offb[o];
    float l4[4];
    #pragma unroll
    for (int k = 0; k < 4; k++) l4[k] = acc[8+k] + wtb[k];
    float m = fmaxf(fmaxf(l4[0], l4[1]), fmaxf(l4[2], l4[3]));
    float e[4]; float se = 0.f;
    #pragma unroll
    for (int k = 0; k < 4; k++) { e[k] = expf(l4[k] - m); se += e[k]; }
    float inv = 1.f / se;
    #pragma unroll
    for (int k = 0; k < 4; k++) outv[8+k] = e[k] * inv;

    size_t basep = (size_t)b * 12 * HWC + (size_t)i * WW + j;
    #pragma unroll
    for (int o = 0; o < 12; o++) oa[basep + (size_t)o * HWC] = outv[o];
}

// ---------------- Kernel T (tier2): NCHW -> NHWC f32 transpose ----------------
__global__ __launch_bounds__(256) void k2t_transpose(
    const float* __restrict__ bev, float* __restrict__ bevt)
{
    __shared__ float T[64 * 128];
    int tid = threadIdx.x;
    int bidx = blockIdx.x;
    int b = bidx >> 10;
    int rem = bidx & 1023;
    int yrow = rem >> 2;
    int x0 = (rem & 3) << 6;

    const float* src = bev + ((size_t)b * DD) * HWC + (size_t)yrow * WW + x0;
    #pragma unroll 4
    for (int k = 0; k < 32; k++) {
        int flat = k * 256 + tid;
        int d = flat >> 6, xl = flat & 63;
        float v = src[(size_t)d * HWC + xl];
        T[xl * 128 + (((d >> 2) ^ (xl & 31)) << 2) + (d & 3)] = v;
    }
    __syncthreads();
    float* dst = bevt + (((size_t)b * HH + yrow) * WW + x0) * 128;
    #pragma unroll 4
    for (int k = 0; k < 8; k++) {
        int flat = k * 256 + tid;
        int d4 = flat & 31, xl = (flat >> 5) & 63;
        float4 v = *(const float4*)&T[xl * 128 + ((d4 ^ (xl & 31)) << 2)];
        *(float4*)(dst + (size_t)xl * 128 + (d4 << 2)) = v;
    }
}

// ---------------- Kernel 2 fused fallback (tier2, NHWC f32) ----------------
__global__ __launch_bounds__(512, 2) void k2_sample_proj_t(
    const float* __restrict__ bevt, const float* __restrict__ oa,
    const float* __restrict__ wt, float* __restrict__ y)
{
    __shared__ float S[2][16 * SROW2];

    int tid = threadIdx.x;
    int bidx = blockIdx.x;
    int b  = bidx >> 8;
    int p0 = ((bidx >> 4) & 15) * 16;
    int q0 = (bidx & 15) * 16;

    int gpix = tid >> 1;
    int gp = gpix & 15;
    int gq = gpix >> 4;
    int dgrp = tid & 1;
    int swr = gp * 20 + gq;

    int wv = tid >> 6;
    int wvu = __builtin_amdgcn_readfirstlane(wv);
    int lane = tid & 63;
    int lp = lane >> 2;
    int q4 = (lane & 3) << 2;
    int soff = lp * 20 + q4;

    const float* ob = oa + (size_t)b * 12 * HWC + (size_t)(p0 + gp) * WW + (q0 + gq);
    unsigned pa[8]; float cw[16];
    #pragma unroll
    for (int k = 0; k < 4; k++) {
        float dx = ob[(size_t)(2*k)   * HWC];
        float dy = ob[(size_t)(2*k+1) * HWC];
        float a  = ob[(size_t)(8+k)   * HWC];
        float x  = fminf(fmaxf((float)(p0 + gp) + dx, 0.f), (float)(WW-1));
        float yv = fminf(fmaxf((float)(q0 + gq) + dy, 0.f), (float)(HH-1));
        float x0f = floorf(x); float y0f = floorf(yv);
        int x0 = (int)x0f; int y0 = (int)y0f;
        int x1 = min(x0 + 1, WW - 1); int y1 = min(y0 + 1, HH - 1);
        float wx = x - x0f; float wy = yv - y0f;
        pa[k*2+0] = (unsigned)(y0*WW + x0) | ((unsigned)(y0*WW + x1) << 16);
        pa[k*2+1] = (unsigned)(y1*WW + x0) | ((unsigned)(y1*WW + x1) << 16);
        cw[k*4+0] = a * (1.f - wx) * (1.f - wy);
        cw[k*4+1] = a * wx * (1.f - wy);
        cw[k*4+2] = a * (1.f - wx) * wy;
        cw[k*4+3] = a * wx * wy;
    }

    const float* bt = bevt + (size_t)b * HWC * 128 + dgrp * 8;

    float acc[64];
    #pragma unroll
    for (int t = 0; t < 64; t++) acc[t] = 0.f;

    {
        float4 s0 = make_float4(0,0,0,0), s1 = make_float4(0,0,0,0);
        #pragma unroll
        for (int t = 0; t < 16; t++) {
            unsigned pix = (t & 1) ? (pa[t >> 1] >> 16) : (pa[t >> 1] & 0xffffu);
            const float4* tp = (const float4*)(bt + ((size_t)pix << 7));
            float4 va = tp[0], vb = tp[1];
            float c = cw[t];
            s0.x = fmaf(c, va.x, s0.x); s0.y = fmaf(c, va.y, s0.y);
            s0.z = fmaf(c, va.z, s0.z); s0.w = fmaf(c, va.w, s0.w);
            s1.x = fmaf(c, vb.x, s1.x); s1.y = fmaf(c, vb.y, s1.y);
            s1.z = fmaf(c, vb.z, s1.z); s1.w = fmaf(c, vb.w, s1.w);
        }
        int r = dgrp * 8;
        S[0][(r+0)*SROW2 + swr] = s0.x; S[0][(r+1)*SROW2 + swr] = s0.y;
        S[0][(r+2)*SROW2 + swr] = s0.z; S[0][(r+3)*SROW2 + swr] = s0.w;
        S[0][(r+4)*SROW2 + swr] = s1.x; S[0][(r+5)*SROW2 + swr] = s1.y;
        S[0][(r+6)*SROW2 + swr] = s1.z; S[0][(r+7)*SROW2 + swr] = s1.w;
    }
    __syncthreads();

    for (int c = 0; c < 8; c++) {
        int cur = c & 1;
        const float* Sc = &S[cur][0];
        float* Sn = &S[cur ^ 1][0];
        int d0 = c * 16;
        int dn = d0 + 16;
        bool more = (c < 7);

        float4 g0 = make_float4(0,0,0,0), g1 = make_float4(0,0,0,0);
        float4 pf0, pf1;
        if (more) {
            unsigned pix = pa[0] & 0xffffu;
            const float4* tp = (const float4*)(bt + ((size_t)pix << 7) + dn);
            pf0 = tp[0]; pf1 = tp[1];
        }

        #pragma unroll
        for (int dl = 0; dl < 16; dl++) {
            float4 cur0 = pf0, cur1 = pf1;
            if (more && dl < 15) {
                int t = dl + 1;
                unsigned pix = (t & 1) ? (pa[t >> 1] >> 16) : (pa[t >> 1] & 0xffffu);
                const float4* tp = (const float4*)(bt + ((size_t)pix << 7) + dn);
                pf0 = tp[0]; pf1 = tp[1];
            }

            float4 sv = *(const float4*)(Sc + dl * SROW2 + soff);
            const float4* wq = (const float4*)(wt + (size_t)(d0 + dl) * 128 + wvu * 16);
            #pragma unroll
            for (int oi4 = 0; oi4 < 4; oi4++) {
                float4 w4 = wq[oi4];
                int ob4 = oi4 * 16;
                acc[ob4+ 0] = fmaf(w4.x, sv.x, acc[ob4+ 0]);
                acc[ob4+ 1] = fmaf(w4.x, sv.y, acc[ob4+ 1]);
                acc[ob4+ 2] = fmaf(w4.x, sv.z, acc[ob4+ 2]);
                acc[ob4+ 3] = fmaf(w4.x, sv.w, acc[ob4+ 3]);
                acc[ob4+ 4] = fmaf(w4.y, sv.x, acc[ob4+ 4]);
                acc[ob4+ 5] = fmaf(w4.y, sv.y, acc[ob4+ 5]);
                acc[ob4+ 6] = fmaf(w4.y, sv.z, acc[ob4+ 6]);
                acc[ob4+ 7] = fmaf(w4.y, sv.w, acc[ob4+ 7]);
                acc[ob4+ 8] = fmaf(w4.z, sv.x, acc[ob4+ 8]);
                acc[ob4+ 9] = fmaf(w4.z, sv.y, acc[ob4+ 9]);
                acc[ob4+10] = fmaf(w4.z, sv.z, acc[ob4+10]);
                acc[ob4+11] = fmaf(w4.z, sv.w, acc[ob4+11]);
                acc[ob4+12] = fmaf(w4.w, sv.x, acc[ob4+12]);
                acc[ob4+13] = fmaf(w4.w, sv.y, acc[ob4+13]);
                acc[ob4+14] = fmaf(w4.w, sv.z, acc[ob4+14]);
                acc[ob4+15] = fmaf(w4.w, sv.w, acc[ob4+15]);
            }

            if (more) {
                float cwt = cw[dl];
                g0.x = fmaf(cwt, cur0.x, g0.x); g0.y = fmaf(cwt, cur0.y, g0.y);
                g0.z = fmaf(cwt, cur0.z, g0.z); g0.w = fmaf(cwt, cur0.w, g0.w);
                g1.x = fmaf(cwt, cur1.x, g1.x); g1.y = fmaf(cwt, cur1.y, g1.y);
                g1.z = fmaf(cwt, cur1.z, g1.z); g1.w = fmaf(cwt, cur1.w, g1.w);
            }
        }

        if (more) {
            int r = dgrp * 8;
            Sn[(r+0)*SROW2 + swr] = g0.x; Sn[(r+1)*SROW2 + swr] = g0.y;
            Sn[(r+2)*SROW2 + swr] = g0.z; Sn[(r+3)*SROW2 + swr] = g0.w;
            Sn[(r+4)*SROW2 + swr] = g1.x; Sn[(r+5)*SROW2 + swr] = g1.y;
            Sn[(r+6)*SROW2 + swr] = g1.z; Sn[(r+7)*SROW2 + swr] = g1.w;
        }
        __syncthreads();
    }

    size_t base = (size_t)b * DD * HWC + (size_t)(p0 + lp) * WW + (q0 + q4);
    #pragma unroll
    for (int oi = 0; oi < 16; oi++) {
        int o = wv * 16 + oi;
        float4 v = make_float4(acc[oi*4+0], acc[oi*4+1], acc[oi*4+2], acc[oi*4+3]);
        *(float4*)(y + base + (size_t)o * HWC) = v;
    }
}

// ---------------- Kernel 2 fallback (tier3, NCHW) ----------------
__global__ __launch_bounds__(512, 2) void k2_sample_proj(
    const float* __restrict__ bev, const float* __restrict__ oa,
    const float* __restrict__ wt, float* __restrict__ y)
{
    __shared__ float S[2][16 * SROW2];
    int tid = threadIdx.x;
    int bidx = blockIdx.x;
    int b  = bidx >> 8;
    int p0 = ((bidx >> 4) & 15) * 16;
    int q0 = (bidx & 15) * 16;
    int pix = tid & 255;
    int gq = pix >> 4;
    int gp = pix & 15;
    int dgrp = tid >> 8;
    int swr = gp * 20 + gq;
    int wv = tid >> 6;
    int wvu = __builtin_amdgcn_readfirstlane(wv);
    int lane = tid & 63;
    int lp = lane >> 2;
    int q4 = (lane & 3) << 2;
    int soff = lp * 20 + q4;

    const float* ob = oa + (size_t)b * 12 * HWC + (size_t)(p0 + gp) * WW + (q0 + gq);
    unsigned pa[8]; float cw[16];
    #pragma unroll
    for (int k = 0; k < 4; k++) {
        float dx = ob[(size_t)(2*k)   * HWC];
        float dy = ob[(size_t)(2*k+1) * HWC];
        float a  = ob[(size_t)(8+k)   * HWC];
        float x  = fminf(fmaxf((float)(p0 + gp) + dx, 0.f), (float)(WW-1));
        float yv = fminf(fmaxf((float)(q0 + gq) + dy, 0.f), (float)(HH-1));
        float x0f = floorf(x); float y0f = floorf(yv);
        int x0 = (int)x0f; int y0 = (int)y0f;
        int x1 = min(x0 + 1, WW - 1); int y1 = min(y0 + 1, HH - 1);
        float wx = x - x0f; float wy = yv - y0f;
        pa[k*2+0] = (unsigned)(y0*WW + x0) | ((unsigned)(y0*WW + x1) << 16);
        pa[k*2+1] = (unsigned)(y1*WW + x0) | ((unsigned)(y1*WW + x1) << 16);
        cw[k*4+0] = a * (1.f - wx) * (1.f - wy);
        cw[k*4+1] = a * wx * (1.f - wy);
        cw[k*4+2] = a * (1.f - wx) * wy;
        cw[k*4+3] = a * wx * wy;
    }
    const float* bb = bev + (size_t)b * DD * HWC;
    float acc[64];
    #pragma unroll
    for (int t = 0; t < 64; t++) acc[t] = 0.f;
    #pragma unroll
    for (int dd = 0; dd < 8; dd++) {
        const float* pl = bb + (size_t)(dgrp*8 + dd) * HWC;
        float s = 0.f;
        #pragma unroll
        for (int t = 0; t < 8; t++) {
            unsigned a01 = pa[t];
            s = fmaf(cw[2*t],   pl[a01 & 0xffffu], s);
            s = fmaf(cw[2*t+1], pl[a01 >> 16], s);
        }
        S[0][(dgrp*8 + dd) * SROW2 + swr] = s;
    }
    __syncthreads();
    for (int c = 0; c < 8; c++) {
        int cur = c & 1;
        const float* Sc = &S[cur][0];
        float* Sn = &S[cur ^ 1][0];
        int d0 = c * 16;
        int d0n = d0 + 16;
        bool more = (c < 7);
        #pragma unroll
        for (int dl = 0; dl < 16; dl++) {
            if (dl < 8) {
                if (more) {
                    const float* pl = bb + (size_t)(d0n + dgrp*8 + dl) * HWC;
                    float s = 0.f;
                    #pragma unroll
                    for (int t = 0; t < 8; t++) {
                        unsigned a01 = pa[t];
                        s = fmaf(cw[2*t],   pl[a01 & 0xffffu], s);
                        s = fmaf(cw[2*t+1], pl[a01 >> 16], s);
                    }
                    Sn[(dgrp*8 + dl) * SROW2 + swr] = s;
                }
            }
            float4 sv = *(const float4*)(Sc + dl * SROW2 + soff);
            const float4* wq = (const float4*)(wt + (size_t)(d0 + dl) * 128 + wvu * 16);
            #pragma unroll
            for (int oi4 = 0; oi4 < 4; oi4++) {
                float4 w4 = wq[oi4];
                int ob4 = oi4 * 16;
                acc[ob4+ 0] = fmaf(w4.x, sv.x, acc[ob4+ 0]);
                acc[ob4+ 1] = fmaf(w4.x, sv.y, acc[ob4+ 1]);
                acc[ob4+ 2] = fmaf(w4.x, sv.z, acc[ob4+ 2]);
                acc[ob4+ 3] = fmaf(w4.x, sv.w, acc[ob4+ 3]);
                acc[ob4+ 4] = fmaf(w4.y, sv.x, acc[ob4+ 4]);
                acc[ob4+ 5] = fmaf(w4.y, sv.y, acc[ob4+ 5]);
                acc[ob4+ 6] = fmaf(w4.y, sv.z, acc[ob4+ 6]);
                acc[ob4+ 7] = fmaf(w4.y, sv.w, acc[ob4+ 7]);
                acc[ob4+ 8] = fmaf(w4.z, sv.x, acc[ob4+ 8]);
                acc[ob4+ 9] = fmaf(w4.z, sv.y, acc[ob4+ 9]);
                acc[ob4+10] = fmaf(w4.z, sv.z, acc[ob4+10]);
                acc[ob4+11] = fmaf(w4.z, sv.w, acc[ob4+11]);
                acc[ob4+12] = fmaf(w4.w, sv.x, acc[ob4+12]);
                acc[ob4+13] = fmaf(w4.w, sv.y, acc[ob4+13]);
                acc[ob4+14] = fmaf(w4.w, sv.z, acc[ob4+14]);
                acc[ob4+15] = fmaf(w4.w, sv.w, acc[ob4+15]);
            }
        }
        __syncthreads();
    }
    size_t base = (size_t)b * DD * HWC + (size_t)(p0 + lp) * WW + (q0 + q4);
    #pragma unroll
    for (int oi = 0; oi < 16; oi++) {
        int o = wv * 16 + oi;
        float4 v = make_float4(acc[oi*4+0], acc[oi*4+1], acc[oi*4+2], acc[oi*4+3]);
        *(float4*)(y + base + (size_t)o * HWC) = v;
    }
}

// ---------------- Kernel 3a/3b: BN stats (fallback tiers only) ----------------
__global__ __launch_bounds__(256) void k3_partial(
    const float* __restrict__ y, double* __restrict__ part)
{
    int blk = blockIdx.x;
    int o = blk >> 2; int sub = blk & 3; int b = sub >> 1; int half = sub & 1;
    const float4* pl = (const float4*)(y + ((size_t)b * DD + o) * HWC + half * (HWC/2));
    int tid = threadIdx.x;
    double s = 0.0, s2 = 0.0;
    for (int idx = tid; idx < HWC/8; idx += 256) {
        float4 v = pl[idx];
        s  += (double)v.x + (double)v.y + (double)v.z + (double)v.w;
        s2 += (double)v.x*v.x + (double)v.y*v.y + (double)v.z*v.z + (double)v.w*v.w;
    }
    __shared__ double ls[256], ls2[256];
    ls[tid] = s; ls2[tid] = s2;
    __syncthreads();
    for (int off = 128; off > 0; off >>= 1) {
        if (tid < off) { ls[tid] += ls[tid+off]; ls2[tid] += ls2[tid+off]; }
        __syncthreads();
    }
    if (tid == 0) { part[blk*2] = ls[0]; part[blk*2+1] = ls2[0]; }
}

__global__ __launch_bounds__(128) void k3_finalize(
    const double* __restrict__ part, const float* __restrict__ gamma,
    const float* __restrict__ beta, float* __restrict__ stats)
{
    int o = threadIdx.x;
    double s = 0.0, s2 = 0.0;
    #pragma unroll
    for (int j = 0; j < 4; j++) { s += part[(o*4+j)*2]; s2 += part[(o*4+j)*2+1]; }
    double N = (double)(BB * HWC);
    double mean = s / N;
    double var = s2 / N - mean * mean;
    double invs = 1.0 / sqrt(var + 1e-5);
    double g = (double)gamma[o];
    stats[o*2]   = (float)(g * invs);
    stats[o*2+1] = (float)((double)beta[o] - mean * g * invs);
}

// ---------------- Kernel 4: BN + exact GELU ----------------
__global__ __launch_bounds__(256) void k4_bn_gelu(
    float* __restrict__ y, const float* __restrict__ stats)
{
    size_t idx4 = (size_t)blockIdx.x * 256 + threadIdx.x;
    float4* p = (float4*)y;
    float4 v = p[idx4];
    int o = (int)((idx4 * 4) / HWC) % DD;
    float sc = stats[o*2], sh = stats[o*2+1];
    const float inv_sqrt2 = 0.70710678118654752f;
    float g0 = fmaf(v.x, sc, sh);
    float g1 = fmaf(v.y, sc, sh);
    float g2 = fmaf(v.z, sc, sh);
    float g3 = fmaf(v.w, sc, sh);
    v.x = 0.5f * g0 * (1.f + erff(g0 * inv_sqrt2));
    v.y = 0.5f * g1 * (1.f + erff(g1 * inv_sqrt2));
    v.z = 0.5f * g2 * (1.f + erff(g2 * inv_sqrt2));
    v.w = 0.5f * g3 * (1.f + erff(g3 * inv_sqrt2));
    p[idx4] = v;
}

extern "C" void kernel_launch(void* const* d_in, const int* in_sizes, int n_in,
                              void* d_out, int out_size, void* d_ws, size_t ws_size,
                              hipStream_t stream) {
    const float* bev   = (const float*)d_in[0];
    const float* offw  = (const float*)d_in[1];
    const float* offb  = (const float*)d_in[2];
    const float* wtw   = (const float*)d_in[3];
    const float* wtb   = (const float*)d_in[4];
    const float* projw = (const float*)d_in[5];
    const float* gamma = (const float*)d_in[6];
    const float* beta  = (const float*)d_in[7];
    float* out = (float*)d_out;
    float* wsf = (float*)d_ws;

    float* oa    = wsf + OA_OFF;
    float* wtT   = wsf + WTT_OFF;
    float* wp    = wsf + WP_OFF;
    float* stats = wsf + STATS_OFF;
    double* part = (double*)(wsf + PART_OFF);
    float* bevt  = wsf + BEVT_OFF;                 // tier2 f32
    ushort* bevtb = (ushort*)(wsf + BEVT_OFF);     // full3 bf16
    ushort* wbf  = (ushort*)(wsf + WBF_OFF);
    ushort* wcb  = (ushort*)(wsf + WCB_OFF);
    float* part2 = wsf + PART2_OFF;                // PACC region (no bevtb alias)

    bool full3 = ws_size >= WS_NEED_FULL3;
    bool big   = ws_size >= WS_NEED_BEVT;

    if (full3) {
        hipLaunchKernelGGL(k0bc, dim3(72), dim3(256), 0, stream,
                           projw, offw, wtw, wbf, wcb);
        hipLaunchKernelGGL(k2t_bf, dim3(2048), dim3(256), 0, stream, bev, bevtb);
        hipLaunchKernelGGL(k1m_conv_mfma, dim3(2048), dim3(256), 0, stream,
                           bevtb, wcb, offb, wtb, oa);
        hipLaunchKernelGGL(k2f_sample_proj, dim3(4096), dim3(256), 0, stream,
                           bevtb, oa, wbf, out, part2);
        hipLaunchKernelGGL(k3b_finalize2, dim3(128), dim3(256), 0, stream,
                           part2, gamma, beta, stats);
    } else if (big) {
        hipLaunchKernelGGL(k0_prep, dim3(64), dim3(256), 0, stream,
                           projw, offw, wtw, wtT, wp);
        hipLaunchKernelGGL(k2t_transpose, dim3(2048), dim3(256), 0, stream, bev, bevt);
        hipLaunchKernelGGL(k1_convs, dim3(BB*HH), dim3(256), 0, stream,
                           bev, wp, offb, wtb, oa);
        hipLaunchKernelGGL(k2_sample_proj_t, dim3(BB*256), dim3(512), 0, stream,
                           bevt, oa, wtT, out);
        hipLaunchKernelGGL(k3_partial, dim3(512), dim3(256), 0, stream, out, part);
        hipLaunchKernelGGL(k3_finalize, dim3(1), dim3(128), 0, stream,
                           part, gamma, beta, stats);
    } else {
        hipLaunchKernelGGL(k0_prep, dim3(64), dim3(256), 0, stream,
                           projw, offw, wtw, wtT, wp);
        hipLaunchKernelGGL(k1_convs, dim3(BB*HH), dim3(256), 0, stream,
                           bev, wp, offb, wtb, oa);
        hipLaunchKernelGGL(k2_sample_proj, dim3(BB*256), dim3(512), 0, stream,
                           bev, oa, wtT, out);
        hipLaunchKernelGGL(k3_partial, dim3(512), dim3(256), 0, stream, out, part);
        hipLaunchKernelGGL(k3_finalize, dim3(1), dim3(128), 0, stream,
                           part, gamma, beta, stats);
    }
    hipLaunchKernelGGL(k4_bn_gelu, dim3((BB*DD*HWC)/1024), dim3(256), 0, stream,
                       out, stats);
}

// Round 14
// 156.321 us; speedup vs baseline: 1.0273x; 1.0273x over previous
//
#include <hip/hip_runtime.h>
#include <math.h>

#define BB 2
#define DD 128
#define HH 256
#define WW 256
#define KK 4
#define HWC (HH*WW)
#define SROW2 320   // d-slice stride in S (fused fallback kernels)

typedef unsigned int u32;
typedef unsigned short ushort;
typedef __attribute__((ext_vector_type(8))) short bf16x8;
typedef __attribute__((ext_vector_type(4))) float f32x4;

// ws float layout
#define OA_OFF    0
#define WTT_OFF   1572864
#define WP_OFF    1589248
#define STATS_OFF 1603072
#define PART_OFF  1603392
#define BEVT_OFF  1605440       // full3: bevtb bf16 (16.8M ushort); tier2: f32 bevt
#define PACC_OFF  18382656
#define PART2_OFF PACC_OFF      // full3: k2f block stats [wgid][256] = 1M f32 (4MB)
#define WBF_OFF   26771264      // proj W bf16
#define WCB_OFF   26779456      // conv W bf16 padded: 9*16*128 ushort
#define WS_NEED_BEVT  ((size_t)PACC_OFF * 4)
#define WS_NEED_FULL3 ((size_t)(WCB_OFF + 9216) * 4)

__device__ __forceinline__ u32 f2bf(float x) {
    u32 u = __builtin_bit_cast(u32, x);
    return (u + 0x7fffu + ((u >> 16) & 1u)) >> 16;
}
__device__ __forceinline__ u32 pkbf(float a, float b) {
    return f2bf(a) | (f2bf(b) << 16);
}
__device__ __forceinline__ float bflo(u32 d) { return __builtin_bit_cast(float, d << 16); }
__device__ __forceinline__ float bfhi(u32 d) { return __builtin_bit_cast(float, d & 0xffff0000u); }

// ---------------- Kernel 0: weight prep (fallback tiers only) ----------------
__global__ __launch_bounds__(256) void k0_prep(
    const float* __restrict__ projw, const float* __restrict__ offw,
    const float* __restrict__ wtw, float* __restrict__ wtT, float* __restrict__ wp)
{
    int idx = blockIdx.x * 256 + threadIdx.x;
    if (idx < 16384) {
        int d = idx >> 7, o = idx & 127;
        wtT[d * 128 + o] = projw[o * 128 + d];
    }
    if (idx < 13824) {
        int c = idx / 108; int r = idx % 108; int o = r / 9; int t = r % 9;
        wp[idx] = (o < 8) ? offw[(o*128 + c)*9 + t] : wtw[((o-8)*128 + c)*9 + t];
    }
}

// ---------------- Kernel 0bc: bf16 weight prep (proj + conv) ----------------
__global__ __launch_bounds__(256) void k0bc(
    const float* __restrict__ projw, const float* __restrict__ offw,
    const float* __restrict__ wtw, ushort* __restrict__ wbf,
    ushort* __restrict__ wcb)
{
    int idx = blockIdx.x * 256 + threadIdx.x;
    if (idx < 16384) wbf[idx] = (ushort)f2bf(projw[idx]);
    if (idx < 18432) {
        int tap = idx >> 11;
        int rem = idx & 2047;
        int oo = rem >> 7, c = rem & 127;
        float v = 0.f;
        if (oo < 8)       v = offw[(oo*128 + c)*9 + tap];
        else if (oo < 12) v = wtw[((oo-8)*128 + c)*9 + tap];
        wcb[idx] = (ushort)f2bf(v);
    }
}

// ---------------- Kernel Tb: NCHW f32 -> NHWC bf16 ----------------
__global__ __launch_bounds__(256) void k2t_bf(
    const float* __restrict__ bev, ushort* __restrict__ bevtb)
{
    __shared__ float T[64 * 128];
    int tid = threadIdx.x;
    int bidx = blockIdx.x;
    int b = bidx >> 10;
    int rem = bidx & 1023;
    int yrow = rem >> 2;
    int x0 = (rem & 3) << 6;

    const float* src = bev + ((size_t)b * DD) * HWC + (size_t)yrow * WW + x0;
    #pragma unroll 4
    for (int k = 0; k < 32; k++) {
        int flat = k * 256 + tid;
        int d = flat >> 6, xl = flat & 63;
        float v = src[(size_t)d * HWC + xl];
        T[xl * 128 + (((d >> 2) ^ (xl & 31)) << 2) + (d & 3)] = v;
    }
    __syncthreads();
    ushort* dst = bevtb + (((size_t)b * HH + yrow) * WW + x0) * 128;
    #pragma unroll 4
    for (int k = 0; k < 8; k++) {
        int flat = k * 256 + tid;
        int d4 = flat & 31, xl = (flat >> 5) & 63;
        float4 v = *(const float4*)&T[xl * 128 + ((d4 ^ (xl & 31)) << 2)];
        uint2 pk;
        pk.x = pkbf(v.x, v.y);
        pk.y = pkbf(v.z, v.w);
        *(uint2*)(dst + (size_t)xl * 128 + (d4 << 2)) = pk;
    }
}

// ---------------- Kernel 1m: 3x3 convs as implicit-GEMM MFMA, LDS-staged ----------------
// R13 budget analysis: hidden runner-up at ~40-55us; 50.7KB LDS capped 3 blocks/CU with
// serialized stage->barrier->MFMA.  Fix: 128-thread block, 32-px tile -> 26.1KB LDS
// (6 blocks/CU), doubled TLP hides stage latency.  Same swizzle/MFMA identity.
__global__ __launch_bounds__(128) void k1m_conv_mfma(
    const ushort* __restrict__ bevtb, const ushort* __restrict__ wcb,
    const float* __restrict__ offb, const float* __restrict__ wtb,
    float* __restrict__ oa)
{
    __shared__ uint4 lds4[1632];   // 3 rows x 34 px x 16 slots x 16B = 26112 B

    int tid = threadIdx.x;
    int wv = tid >> 6;             // 0..1
    int l = tid & 63;
    int lm = l & 15, lk = l >> 4;
    int wgid = blockIdx.x;         // 0..4095
    int lin = (wgid & 7) * 512 + (wgid >> 3);   // bijective XCD-contiguous remap
    int b = lin >> 11;
    int i = (lin >> 3) & 255;
    int jt = lin & 7;
    int x0 = jt * 32;

    const ushort* bb = bevtb + (size_t)b * HWC * 128;
    for (int z = tid; z < 1632; z += 128) {
        int row = z / 544;
        int rem = z - row * 544;
        int pl = rem >> 4;
        int q  = rem & 15;
        int yy = i - 1 + row;
        int x  = x0 - 1 + pl;
        bool ok = ((unsigned)yy < HH) && ((unsigned)x < WW);
        uint4 v = make_uint4(0u, 0u, 0u, 0u);
        if (ok) v = *(const uint4*)(bb + ((size_t)(yy * WW + x) << 7) + q * 8);
        lds4[row * 544 + pl * 16 + (q ^ (pl & 15))] = v;
    }
    __syncthreads();

    f32x4 acc = (f32x4)(0.f);
    #pragma unroll
    for (int dy = 0; dy < 3; dy++) {
        #pragma unroll
        for (int dx = 0; dx < 3; dx++) {
            int pl = wv * 16 + lm + dx;
            const uint4* bp = &lds4[dy * 544 + pl * 16];
            int sx = pl & 15;
            const ushort* ap = wcb + (size_t)((dy*3 + dx) * 16 + lm) * 128 + lk * 8;
            #pragma unroll
            for (int kk = 0; kk < 4; kk++) {
                bf16x8 bfr = *(const bf16x8*)&bp[(kk*4 + lk) ^ sx];
                bf16x8 afr = *(const bf16x8*)(ap + kk * 32);
                acc = __builtin_amdgcn_mfma_f32_16x16x32_bf16(afr, bfr, acc, 0, 0, 0);
            }
        }
    }

    float v[4];
    #pragma unroll
    for (int r = 0; r < 4; r++) v[r] = acc[r];

    int j = x0 + wv * 16 + lm;
    if (lk < 2) {
        #pragma unroll
        for (int r = 0; r < 4; r++) v[r] += offb[lk*4 + r];   // OFFSET_SCALE = 1.0
    } else if (lk == 2) {
        float l4[4];
        #pragma unroll
        for (int r = 0; r < 4; r++) l4[r] = v[r] + wtb[r];
        float m = fmaxf(fmaxf(l4[0], l4[1]), fmaxf(l4[2], l4[3]));
        float e[4]; float se = 0.f;
        #pragma unroll
        for (int r = 0; r < 4; r++) { e[r] = expf(l4[r] - m); se += e[r]; }
        float inv = 1.f / se;
        #pragma unroll
        for (int r = 0; r < 4; r++) v[r] = e[r] * inv;
    }
    if (lk < 3) {
        size_t basep = (size_t)b * 12 * HWC + (size_t)i * WW + j;
        #pragma unroll
        for (int r = 0; r < 4; r++)
            oa[basep + (size_t)(lk*4 + r) * HWC] = v[r];
    }
}

// ---------------- Kernel 2f: FUSED sample + 1x1 MFMA proj + BN stats ----------------
// R13 post-mortem: occupancy lever flat (61.5->64); compiler's 64-VGPR budget keeps
// only ~4 loads in flight.  Fix: launch_bounds(256,4) raises cap to 128 VGPR, and the
// gather is hand-pipelined in 2x8-tap batches (L0/L1): 16 uint4 loads stay in flight
// while the previous batch's FMAs retire; each consumed slot immediately reloads the
// c=1 half (k1_convs rv[] pattern - compiler-respected before).  part2 layout is now
// [wgid][256] -> coalesced ~1KB block writes (R13's [o][wgid] scatter cost ~25MB).
#define TAPPTR(t) (bt + ((size_t)((((t) & 1) ? (pa[(t) >> 1] >> 16) : (pa[(t) >> 1] & 0xffffu))) << 7))
#define FMA8(S, V, W) do { \
    S[0] = fmaf(W, bflo((V).x), S[0]); S[1] = fmaf(W, bfhi((V).x), S[1]); \
    S[2] = fmaf(W, bflo((V).y), S[2]); S[3] = fmaf(W, bfhi((V).y), S[3]); \
    S[4] = fmaf(W, bflo((V).z), S[4]); S[5] = fmaf(W, bfhi((V).z), S[5]); \
    S[6] = fmaf(W, bflo((V).w), S[6]); S[7] = fmaf(W, bfhi((V).w), S[7]); \
} while (0)

__global__ __launch_bounds__(256, 4) void k2f_sample_proj(
    const ushort* __restrict__ bevtb, const float* __restrict__ oa,
    const ushort* __restrict__ wbf, float* __restrict__ y,
    float* __restrict__ part2)
{
    __shared__ uint4 P[32 * 16];   // 8 KB

    int tid = threadIdx.x;
    int wgid = blockIdx.x;                       // 0..4095
    int lin = (wgid & 7) * 512 + (wgid >> 3);    // bijective XCD-contiguous remap
    int b = lin >> 11;
    int pix0 = (lin & 2047) << 5;                // 32 px per block

    // ---- gather phase: thread = (pixel, d-eighth) ----
    int q8 = tid & 7;
    int pixl = tid >> 3;                         // 0..31
    int pix = pix0 + pixl;
    int p = pix >> 8;
    int q = pix & 255;

    const float* ob = oa + (size_t)b * 12 * HWC + (size_t)p * WW + q;
    unsigned pa[8]; float cw[16];
    #pragma unroll
    for (int k = 0; k < 4; k++) {
        float dx = ob[(size_t)(2*k)   * HWC];
        float dy = ob[(size_t)(2*k+1) * HWC];
        float a  = ob[(size_t)(8+k)   * HWC];
        float x  = fminf(fmaxf((float)p + dx, 0.f), (float)(WW-1));
        float yv = fminf(fmaxf((float)q + dy, 0.f), (float)(HH-1));
        float x0f = floorf(x); float y0f = floorf(yv);
        int x0 = (int)x0f; int y0 = (int)y0f;
        int x1 = min(x0 + 1, WW - 1); int y1 = min(y0 + 1, HH - 1);
        float wx = x - x0f; float wy = yv - y0f;
        pa[k*2+0] = (unsigned)(y0*WW + x0) | ((unsigned)(y0*WW + x1) << 16);
        pa[k*2+1] = (unsigned)(y1*WW + x0) | ((unsigned)(y1*WW + x1) << 16);
        cw[k*4+0] = a * (1.f - wx) * (1.f - wy);
        cw[k*4+1] = a * wx * (1.f - wy);
        cw[k*4+2] = a * (1.f - wx) * wy;
        cw[k*4+3] = a * wx * wy;
    }

    // thread owns channels {c*64 + q8*8 .. +8} for c=0,1
    const ushort* bt = bevtb + (size_t)b * HWC * 128 + q8 * 8;

    float s[2][8];
    #pragma unroll
    for (int c = 0; c < 2; c++)
        #pragma unroll
        for (int e = 0; e < 8; e++) s[c][e] = 0.f;

    uint4 L0[8], L1[8];
    #pragma unroll
    for (int t = 0; t < 8; t++) L0[t] = *(const uint4*)(TAPPTR(t));       // taps 0-7, c0
    #pragma unroll
    for (int t = 0; t < 8; t++) L1[t] = *(const uint4*)(TAPPTR(t + 8));   // taps 8-15, c0
    #pragma unroll
    for (int t = 0; t < 8; t++) {      // consume c0 batch0, reload slot with c1 batch0
        uint4 v = L0[t];
        L0[t] = *(const uint4*)(TAPPTR(t) + 64);
        FMA8(s[0], v, cw[t]);
    }
    #pragma unroll
    for (int t = 0; t < 8; t++) {      // consume c0 batch1, reload with c1 batch1
        uint4 v = L1[t];
        L1[t] = *(const uint4*)(TAPPTR(t + 8) + 64);
        FMA8(s[0], v, cw[t + 8]);
    }
    #pragma unroll
    for (int t = 0; t < 8; t++) FMA8(s[1], L0[t], cw[t]);
    #pragma unroll
    for (int t = 0; t < 8; t++) FMA8(s[1], L1[t], cw[t + 8]);

    int sxr = pixl & 15;
    #pragma unroll
    for (int c = 0; c < 2; c++) {
        uint4 pk;
        pk.x = pkbf(s[c][0], s[c][1]);
        pk.y = pkbf(s[c][2], s[c][3]);
        pk.z = pkbf(s[c][4], s[c][5]);
        pk.w = pkbf(s[c][6], s[c][7]);
        P[pixl * 16 + ((c * 8 + q8) ^ sxr)] = pk;   // slot s holds ch s*8..s*8+8
    }
    __syncthreads();

    // ---- GEMM phase ----
    int wv = tid >> 6;
    int l = tid & 63;
    int lm = l & 15, lk = l >> 4;
    int o0 = wv << 5;

    f32x4 acc[2][2];
    #pragma unroll
    for (int ot = 0; ot < 2; ot++)
        #pragma unroll
        for (int nt = 0; nt < 2; nt++)
            acc[ot][nt] = (f32x4)(0.f);

    #pragma unroll
    for (int ot = 0; ot < 2; ot++) {
        const ushort* ap = wbf + (size_t)(o0 + ot * 16 + lm) * 128 + lk * 8;
        bf16x8 a4[4];
        #pragma unroll
        for (int kk = 0; kk < 4; kk++)
            a4[kk] = *(const bf16x8*)(ap + kk * 32);
        #pragma unroll
        for (int nt = 0; nt < 2; nt++) {
            int row = nt * 16 + lm;
            #pragma unroll
            for (int kk = 0; kk < 4; kk++) {
                bf16x8 bfr = *(const bf16x8*)&P[row * 16 + ((kk * 4 + lk) ^ lm)];
                acc[ot][nt] = __builtin_amdgcn_mfma_f32_16x16x32_bf16(
                    a4[kk], bfr, acc[ot][nt], 0, 0, 0);
            }
        }
    }

    #pragma unroll
    for (int ot = 0; ot < 2; ot++)
        #pragma unroll
        for (int nt = 0; nt < 2; nt++)
            #pragma unroll
            for (int r = 0; r < 4; r++)
                y[((size_t)b * DD + o0 + ot * 16 + lk * 4 + r) * HWC + pix0 + nt * 16 + lm]
                    = acc[ot][nt][r];

    // ---- fused BN partial stats (coalesced part2[wgid][256]) ----
    float sm[2][4], sq[2][4];
    #pragma unroll
    for (int ot = 0; ot < 2; ot++)
        #pragma unroll
        for (int r = 0; r < 4; r++) { sm[ot][r] = 0.f; sq[ot][r] = 0.f; }
    #pragma unroll
    for (int ot = 0; ot < 2; ot++)
        #pragma unroll
        for (int nt = 0; nt < 2; nt++)
            #pragma unroll
            for (int r = 0; r < 4; r++) {
                float v = acc[ot][nt][r];
                sm[ot][r] += v;
                sq[ot][r] = fmaf(v, v, sq[ot][r]);
            }
    #pragma unroll
    for (int m = 1; m < 16; m <<= 1) {
        #pragma unroll
        for (int ot = 0; ot < 2; ot++)
            #pragma unroll
            for (int r = 0; r < 4; r++) {
                sm[ot][r] += __shfl_xor(sm[ot][r], m);
                sq[ot][r] += __shfl_xor(sq[ot][r], m);
            }
    }
    if (lm == 0) {
        float* pw = part2 + (size_t)wgid * 256;
        #pragma unroll
        for (int ot = 0; ot < 2; ot++)
            #pragma unroll
            for (int r = 0; r < 4; r++) {
                int o = o0 + ot * 16 + lk * 4 + r;
                pw[o] = sm[ot][r];
                pw[128 + o] = sq[ot][r];
            }
    }
}

// ---------------- Kernel 3b': finalize BN from k2f block partials ----------------
__global__ __launch_bounds__(256) void k3b_finalize2(
    const float* __restrict__ part2, const float* __restrict__ gamma,
    const float* __restrict__ beta, float* __restrict__ stats)
{
    int o = blockIdx.x; int tid = threadIdx.x;
    double s = 0.0, s2 = 0.0;
    for (int w = tid; w < 4096; w += 256) {
        s  += (double)part2[(size_t)w * 256 + o];
        s2 += (double)part2[(size_t)w * 256 + 128 + o];
    }
    __shared__ double ls[256], ls2[256];
    ls[tid] = s; ls2[tid] = s2;
    __syncthreads();
    for (int off = 128; off > 0; off >>= 1) {
        if (tid < off) { ls[tid] += ls[tid+off]; ls2[tid] += ls2[tid+off]; }
        __syncthreads();
    }
    if (tid == 0) {
        double N = (double)(BB * HWC);
        double mean = ls[0] / N;
        double var = ls2[0] / N - mean * mean;
        double invs = 1.0 / sqrt(var + 1e-5);
        double g = (double)gamma[o];
        stats[o*2]   = (float)(g * invs);
        stats[o*2+1] = (float)((double)beta[o] - mean * g * invs);
    }
}

// ---------------- Kernel 1 (tier2 fallback): full 128-channel conv ----------------
__global__ __launch_bounds__(256) void k1_convs(
    const float* __restrict__ bev, const float* __restrict__ wp,
    const float* __restrict__ offb, const float* __restrict__ wtb,
    float* __restrict__ oa)
{
    __shared__ float rows[2][3][260];
    int tid = threadIdx.x;
    int p = blockIdx.x;
    int b = p / HH; int i = p % HH; int j = tid;
    const float* bb = bev + (size_t)b * DD * HWC;

    if (tid < 12) { int bf = tid / 6, r = tid % 6; rows[bf][r >> 1][(r & 1) ? 257 : 0] = 0.f; }
    #pragma unroll
    for (int l = 0; l < 3; l++) {
        int yy = i + l - 1;
        rows[0][l][1 + tid] = ((unsigned)yy < HH) ? bb[yy * WW + tid] : 0.f;
    }
    __syncthreads();

    float acc[12];
    #pragma unroll
    for (int o = 0; o < 12; o++) acc[o] = 0.f;

    for (int c = 0; c < 128; c++) {
        int cb = c & 1, nb = cb ^ 1;
        float rv[3];
        if (c < 127) {
            const float* pln = bb + (size_t)(c + 1) * HWC;
            #pragma unroll
            for (int l = 0; l < 3; l++) {
                int yy = i + l - 1;
                rv[l] = ((unsigned)yy < HH) ? pln[yy * WW + tid] : 0.f;
            }
        }
        float v[9];
        #pragma unroll
        for (int dy = 0; dy < 3; dy++)
            #pragma unroll
            for (int dx = 0; dx < 3; dx++)
                v[dy*3 + dx] = rows[cb][dy][tid + dx];
        const float* wc = wp + c * 108;
        #pragma unroll
        for (int o = 0; o < 12; o++) {
            float s = acc[o];
            #pragma unroll
            for (int t = 0; t < 9; t++) s = fmaf(wc[o*9 + t], v[t], s);
            acc[o] = s;
        }
        if (c < 127) {
            #pragma unroll
            for (int l = 0; l < 3; l++) rows[nb][l][1 + tid] = rv[l];
        }
        __syncthreads();
    }

    float outv[12];
    #pragma unroll
    for (int o = 0; o < 8; o++) outv[o] = acc[o] + offb[o];
    float l4[4];
    #pragma unroll
    for (int k = 0; k < 4; k++) l4[k] = acc[8+k] + wtb[k];
    float m = fmaxf(fmaxf(l4[0], l4[1]), fmaxf(l4[2], l4[3]));
    float e[4]; float se = 0.f;
    #pragma unroll
    for (int k = 0; k < 4; k++) { e[k] = expf(l4[k] - m); se += e[k]; }
    float inv = 1.f / se;
    #pragma unroll
    for (int k = 0; k < 4; k++) outv[8+k] = e[k] * inv;

    size_t basep = (size_t)b * 12 * HWC + (size_t)i * WW + j;
    #pragma unroll
    for (int o = 0; o < 12; o++) oa[basep + (size_t)o * HWC] = outv[o];
}

// ---------------- Kernel T (tier2): NCHW -> NHWC f32 transpose ----------------
__global__ __launch_bounds__(256) void k2t_transpose(
    const float* __restrict__ bev, float* __restrict__ bevt)
{
    __shared__ float T[64 * 128];
    int tid = threadIdx.x;
    int bidx = blockIdx.x;
    int b = bidx >> 10;
    int rem = bidx & 1023;
    int yrow = rem >> 2;
    int x0 = (rem & 3) << 6;

    const float* src = bev + ((size_t)b * DD) * HWC + (size_t)yrow * WW + x0;
    #pragma unroll 4
    for (int k = 0; k < 32; k++) {
        int flat = k * 256 + tid;
        int d = flat >> 6, xl = flat & 63;
        float v = src[(size_t)d * HWC + xl];
        T[xl * 128 + (((d >> 2) ^ (xl & 31)) << 2) + (d & 3)] = v;
    }
    __syncthreads();
    float* dst = bevt + (((size_t)b * HH + yrow) * WW + x0) * 128;
    #pragma unroll 4
    for (int k = 0; k < 8; k++) {
        int flat = k * 256 + tid;
        int d4 = flat & 31, xl = (flat >> 5) & 63;
        float4 v = *(const float4*)&T[xl * 128 + ((d4 ^ (xl & 31)) << 2)];
        *(float4*)(dst + (size_t)xl * 128 + (d4 << 2)) = v;
    }
}

// ---------------- Kernel 2 fused fallback (tier2, NHWC f32) ----------------
__global__ __launch_bounds__(512, 2) void k2_sample_proj_t(
    const float* __restrict__ bevt, const float* __restrict__ oa,
    const float* __restrict__ wt, float* __restrict__ y)
{
    __shared__ float S[2][16 * SROW2];

    int tid = threadIdx.x;
    int bidx = blockIdx.x;
    int b  = bidx >> 8;
    int p0 = ((bidx >> 4) & 15) * 16;
    int q0 = (bidx & 15) * 16;

    int gpix = tid >> 1;
    int gp = gpix & 15;
    int gq = gpix >> 4;
    int dgrp = tid & 1;
    int swr = gp * 20 + gq;

    int wv = tid >> 6;
    int wvu = __builtin_amdgcn_readfirstlane(wv);
    int lane = tid & 63;
    int lp = lane >> 2;
    int q4 = (lane & 3) << 2;
    int soff = lp * 20 + q4;

    const float* ob = oa + (size_t)b * 12 * HWC + (size_t)(p0 + gp) * WW + (q0 + gq);
    unsigned pa[8]; float cw[16];
    #pragma unroll
    for (int k = 0; k < 4; k++) {
        float dx = ob[(size_t)(2*k)   * HWC];
        float dy = ob[(size_t)(2*k+1) * HWC];
        float a  = ob[(size_t)(8+k)   * HWC];
        float x  = fminf(fmaxf((float)(p0 + gp) + dx, 0.f), (float)(WW-1));
        float yv = fminf(fmaxf((float)(q0 + gq) + dy, 0.f), (float)(HH-1));
        float x0f = floorf(x); float y0f = floorf(yv);
        int x0 = (int)x0f; int y0 = (int)y0f;
        int x1 = min(x0 + 1, WW - 1); int y1 = min(y0 + 1, HH - 1);
        float wx = x - x0f; float wy = yv - y0f;
        pa[k*2+0] = (unsigned)(y0*WW + x0) | ((unsigned)(y0*WW + x1) << 16);
        pa[k*2+1] = (unsigned)(y1*WW + x0) | ((unsigned)(y1*WW + x1) << 16);
        cw[k*4+0] = a * (1.f - wx) * (1.f - wy);
        cw[k*4+1] = a * wx * (1.f - wy);
        cw[k*4+2] = a * (1.f - wx) * wy;
        cw[k*4+3] = a * wx * wy;
    }

    const float* bt = bevt + (size_t)b * HWC * 128 + dgrp * 8;

    float acc[64];
    #pragma unroll
    for (int t = 0; t < 64; t++) acc[t] = 0.f;

    {
        float4 s0 = make_float4(0,0,0,0), s1 = make_float4(0,0,0,0);
        #pragma unroll
        for (int t = 0; t < 16; t++) {
            unsigned pix = (t & 1) ? (pa[t >> 1] >> 16) : (pa[t >> 1] & 0xffffu);
            const float4* tp = (const float4*)(bt + ((size_t)pix << 7));
            float4 va = tp[0], vb = tp[1];
            float c = cw[t];
            s0.x = fmaf(c, va.x, s0.x); s0.y = fmaf(c, va.y, s0.y);
            s0.z = fmaf(c, va.z, s0.z); s0.w = fmaf(c, va.w, s0.w);
            s1.x = fmaf(c, vb.x, s1.x); s1.y = fmaf(c, vb.y, s1.y);
            s1.z = fmaf(c, vb.z, s1.z); s1.w = fmaf(c, vb.w, s1.w);
        }
        int r = dgrp * 8;
        S[0][(r+0)*SROW2 + swr] = s0.x; S[0][(r+1)*SROW2 + swr] = s0.y;
        S[0][(r+2)*SROW2 + swr] = s0.z; S[0][(r+3)*SROW2 + swr] = s0.w;
        S[0][(r+4)*SROW2 + swr] = s1.x; S[0][(r+5)*SROW2 + swr] = s1.y;
        S[0][(r+6)*SROW2 + swr] = s1.z; S[0][(r+7)*SROW2 + swr] = s1.w;
    }
    __syncthreads();

    for (int c = 0; c < 8; c++) {
        int cur = c & 1;
        const float* Sc = &S[cur][0];
        float* Sn = &S[cur ^ 1][0];
        int d0 = c * 16;
        int dn = d0 + 16;
        bool more = (c < 7);

        float4 g0 = make_float4(0,0,0,0), g1 = make_float4(0,0,0,0);
        float4 pf0, pf1;
        if (more) {
            unsigned pix = pa[0] & 0xffffu;
            const float4* tp = (const float4*)(bt + ((size_t)pix << 7) + dn);
            pf0 = tp[0]; pf1 = tp[1];
        }

        #pragma unroll
        for (int dl = 0; dl < 16; dl++) {
            float4 cur0 = pf0, cur1 = pf1;
            if (more && dl < 15) {
                int t = dl + 1;
                unsigned pix = (t & 1) ? (pa[t >> 1] >> 16) : (pa[t >> 1] & 0xffffu);
                const float4* tp = (const float4*)(bt + ((size_t)pix << 7) + dn);
                pf0 = tp[0]; pf1 = tp[1];
            }

            float4 sv = *(const float4*)(Sc + dl * SROW2 + soff);
            const float4* wq = (const float4*)(wt + (size_t)(d0 + dl) * 128 + wvu * 16);
            #pragma unroll
            for (int oi4 = 0; oi4 < 4; oi4++) {
                float4 w4 = wq[oi4];
                int ob4 = oi4 * 16;
                acc[ob4+ 0] = fmaf(w4.x, sv.x, acc[ob4+ 0]);
                acc[ob4+ 1] = fmaf(w4.x, sv.y, acc[ob4+ 1]);
                acc[ob4+ 2] = fmaf(w4.x, sv.z, acc[ob4+ 2]);
                acc[ob4+ 3] = fmaf(w4.x, sv.w, acc[ob4+ 3]);
                acc[ob4+ 4] = fmaf(w4.y, sv.x, acc[ob4+ 4]);
                acc[ob4+ 5] = fmaf(w4.y, sv.y, acc[ob4+ 5]);
                acc[ob4+ 6] = fmaf(w4.y, sv.z, acc[ob4+ 6]);
                acc[ob4+ 7] = fmaf(w4.y, sv.w, acc[ob4+ 7]);
                acc[ob4+ 8] = fmaf(w4.z, sv.x, acc[ob4+ 8]);
                acc[ob4+ 9] = fmaf(w4.z, sv.y, acc[ob4+ 9]);
                acc[ob4+10] = fmaf(w4.z, sv.z, acc[ob4+10]);
                acc[ob4+11] = fmaf(w4.z, sv.w, acc[ob4+11]);
                acc[ob4+12] = fmaf(w4.w, sv.x, acc[ob4+12]);
                acc[ob4+13] = fmaf(w4.w, sv.y, acc[ob4+13]);
                acc[ob4+14] = fmaf(w4.w, sv.z, acc[ob4+14]);
                acc[ob4+15] = fmaf(w4.w, sv.w, acc[ob4+15]);
            }

            if (more) {
                float cwt = cw[dl];
                g0.x = fmaf(cwt, cur0.x, g0.x); g0.y = fmaf(cwt, cur0.y, g0.y);
                g0.z = fmaf(cwt, cur0.z, g0.z); g0.w = fmaf(cwt, cur0.w, g0.w);
                g1.x = fmaf(cwt, cur1.x, g1.x); g1.y = fmaf(cwt, cur1.y, g1.y);
                g1.z = fmaf(cwt, cur1.z, g1.z); g1.w = fmaf(cwt, cur1.w, g1.w);
            }
        }

        if (more) {
            int r = dgrp * 8;
            Sn[(r+0)*SROW2 + swr] = g0.x; Sn[(r+1)*SROW2 + swr] = g0.y;
            Sn[(r+2)*SROW2 + swr] = g0.z; Sn[(r+3)*SROW2 + swr] = g0.w;
            Sn[(r+4)*SROW2 + swr] = g1.x; Sn[(r+5)*SROW2 + swr] = g1.y;
            Sn[(r+6)*SROW2 + swr] = g1.z; Sn[(r+7)*SROW2 + swr] = g1.w;
        }
        __syncthreads();
    }

    size_t base = (size_t)b * DD * HWC + (size_t)(p0 + lp) * WW + (q0 + q4);
    #pragma unroll
    for (int oi = 0; oi < 16; oi++) {
        int o = wv * 16 + oi;
        float4 v = make_float4(acc[oi*4+0], acc[oi*4+1], acc[oi*4+2], acc[oi*4+3]);
        *(float4*)(y + base + (size_t)o * HWC) = v;
    }
}

// ---------------- Kernel 2 fallback (tier3, NCHW) ----------------
__global__ __launch_bounds__(512, 2) void k2_sample_proj(
    const float* __restrict__ bev, const float* __restrict__ oa,
    const float* __restrict__ wt, float* __restrict__ y)
{
    __shared__ float S[2][16 * SROW2];
    int tid = threadIdx.x;
    int bidx = blockIdx.x;
    int b  = bidx >> 8;
    int p0 = ((bidx >> 4) & 15) * 16;
    int q0 = (bidx & 15) * 16;
    int pix = tid & 255;
    int gq = pix >> 4;
    int gp = pix & 15;
    int dgrp = tid >> 8;
    int swr = gp * 20 + gq;
    int wv = tid >> 6;
    int wvu = __builtin_amdgcn_readfirstlane(wv);
    int lane = tid & 63;
    int lp = lane >> 2;
    int q4 = (lane & 3) << 2;
    int soff = lp * 20 + q4;

    const float* ob = oa + (size_t)b * 12 * HWC + (size_t)(p0 + gp) * WW + (q0 + gq);
    unsigned pa[8]; float cw[16];
    #pragma unroll
    for (int k = 0; k < 4; k++) {
        float dx = ob[(size_t)(2*k)   * HWC];
        float dy = ob[(size_t)(2*k+1) * HWC];
        float a  = ob[(size_t)(8+k)   * HWC];
        float x  = fminf(fmaxf((float)(p0 + gp) + dx, 0.f), (float)(WW-1));
        float yv = fminf(fmaxf((float)(q0 + gq) + dy, 0.f), (float)(HH-1));
        float x0f = floorf(x); float y0f = floorf(yv);
        int x0 = (int)x0f; int y0 = (int)y0f;
        int x1 = min(x0 + 1, WW - 1); int y1 = min(y0 + 1, HH - 1);
        float wx = x - x0f; float wy = yv - y0f;
        pa[k*2+0] = (unsigned)(y0*WW + x0) | ((unsigned)(y0*WW + x1) << 16);
        pa[k*2+1] = (unsigned)(y1*WW + x0) | ((unsigned)(y1*WW + x1) << 16);
        cw[k*4+0] = a * (1.f - wx) * (1.f - wy);
        cw[k*4+1] = a * wx * (1.f - wy);
        cw[k*4+2] = a * (1.f - wx) * wy;
        cw[k*4+3] = a * wx * wy;
    }
    const float* bb = bev + (size_t)b * DD * HWC;
    float acc[64];
    #pragma unroll
    for (int t = 0; t < 64; t++) acc[t] = 0.f;
    #pragma unroll
    for (int dd = 0; dd < 8; dd++) {
        const float* pl = bb + (size_t)(dgrp*8 + dd) * HWC;
        float s = 0.f;
        #pragma unroll
        for (int t = 0; t < 8; t++) {
            unsigned a01 = pa[t];
            s = fmaf(cw[2*t],   pl[a01 & 0xffffu], s);
            s = fmaf(cw[2*t+1], pl[a01 >> 16], s);
        }
        S[0][(dgrp*8 + dd) * SROW2 + swr] = s;
    }
    __syncthreads();
    for (int c = 0; c < 8; c++) {
        int cur = c & 1;
        const float* Sc = &S[cur][0];
        float* Sn = &S[cur ^ 1][0];
        int d0 = c * 16;
        int d0n = d0 + 16;
        bool more = (c < 7);
        #pragma unroll
        for (int dl = 0; dl < 16; dl++) {
            if (dl < 8) {
                if (more) {
                    const float* pl = bb + (size_t)(d0n + dgrp*8 + dl) * HWC;
                    float s = 0.f;
                    #pragma unroll
                    for (int t = 0; t < 8; t++) {
                        unsigned a01 = pa[t];
                        s = fmaf(cw[2*t],   pl[a01 & 0xffffu], s);
                        s = fmaf(cw[2*t+1], pl[a01 >> 16], s);
                    }
                    Sn[(dgrp*8 + dl) * SROW2 + swr] = s;
                }
            }
            float4 sv = *(const float4*)(Sc + dl * SROW2 + soff);
            const float4* wq = (const float4*)(wt + (size_t)(d0 + dl) * 128 + wvu * 16);
            #pragma unroll
            for (int oi4 = 0; oi4 < 4; oi4++) {
                float4 w4 = wq[oi4];
                int ob4 = oi4 * 16;
                acc[ob4+ 0] = fmaf(w4.x, sv.x, acc[ob4+ 0]);
                acc[ob4+ 1] = fmaf(w4.x, sv.y, acc[ob4+ 1]);
                acc[ob4+ 2] = fmaf(w4.x, sv.z, acc[ob4+ 2]);
                acc[ob4+ 3] = fmaf(w4.x, sv.w, acc[ob4+ 3]);
                acc[ob4+ 4] = fmaf(w4.y, sv.x, acc[ob4+ 4]);
                acc[ob4+ 5] = fmaf(w4.y, sv.y, acc[ob4+ 5]);
                acc[ob4+ 6] = fmaf(w4.y, sv.z, acc[ob4+ 6]);
                acc[ob4+ 7] = fmaf(w4.y, sv.w, acc[ob4+ 7]);
                acc[ob4+ 8] = fmaf(w4.z, sv.x, acc[ob4+ 8]);
                acc[ob4+ 9] = fmaf(w4.z, sv.y, acc[ob4+ 9]);
                acc[ob4+10] = fmaf(w4.z, sv.z, acc[ob4+10]);
                acc[ob4+11] = fmaf(w4.z, sv.w, acc[ob4+11]);
                acc[ob4+12] = fmaf(w4.w, sv.x, acc[ob4+12]);
                acc[ob4+13] = fmaf(w4.w, sv.y, acc[ob4+13]);
                acc[ob4+14] = fmaf(w4.w, sv.z, acc[ob4+14]);
                acc[ob4+15] = fmaf(w4.w, sv.w, acc[ob4+15]);
            }
        }
        __syncthreads();
    }
    size_t base = (size_t)b * DD * HWC + (size_t)(p0 + lp) * WW + (q0 + q4);
    #pragma unroll
    for (int oi = 0; oi < 16; oi++) {
        int o = wv * 16 + oi;
        float4 v = make_float4(acc[oi*4+0], acc[oi*4+1], acc[oi*4+2], acc[oi*4+3]);
        *(float4*)(y + base + (size_t)o * HWC) = v;
    }
}

// ---------------- Kernel 3a/3b: BN stats (fallback tiers only) ----------------
__global__ __launch_bounds__(256) void k3_partial(
    const float* __restrict__ y, double* __restrict__ part)
{
    int blk = blockIdx.x;
    int o = blk >> 2; int sub = blk & 3; int b = sub >> 1; int half = sub & 1;
    const float4* pl = (const float4*)(y + ((size_t)b * DD + o) * HWC + half * (HWC/2));
    int tid = threadIdx.x;
    double s = 0.0, s2 = 0.0;
    for (int idx = tid; idx < HWC/8; idx += 256) {
        float4 v = pl[idx];
        s  += (double)v.x + (double)v.y + (double)v.z + (double)v.w;
        s2 += (double)v.x*v.x + (double)v.y*v.y + (double)v.z*v.z + (double)v.w*v.w;
    }
    __shared__ double ls[256], ls2[256];
    ls[tid] = s; ls2[tid] = s2;
    __syncthreads();
    for (int off = 128; off > 0; off >>= 1) {
        if (tid < off) { ls[tid] += ls[tid+off]; ls2[tid] += ls2[tid+off]; }
        __syncthreads();
    }
    if (tid == 0) { part[blk*2] = ls[0]; part[blk*2+1] = ls2[0]; }
}

__global__ __launch_bounds__(128) void k3_finalize(
    const double* __restrict__ part, const float* __restrict__ gamma,
    const float* __restrict__ beta, float* __restrict__ stats)
{
    int o = threadIdx.x;
    double s = 0.0, s2 = 0.0;
    #pragma unroll
    for (int j = 0; j < 4; j++) { s += part[(o*4+j)*2]; s2 += part[(o*4+j)*2+1]; }
    double N = (double)(BB * HWC);
    double mean = s / N;
    double var = s2 / N - mean * mean;
    double invs = 1.0 / sqrt(var + 1e-5);
    double g = (double)gamma[o];
    stats[o*2]   = (float)(g * invs);
    stats[o*2+1] = (float)((double)beta[o] - mean * g * invs);
}

// ---------------- Kernel 4: BN + exact GELU ----------------
__global__ __launch_bounds__(256) void k4_bn_gelu(
    float* __restrict__ y, const float* __restrict__ stats)
{
    size_t idx4 = (size_t)blockIdx.x * 256 + threadIdx.x;
    float4* p = (float4*)y;
    float4 v = p[idx4];
    int o = (int)((idx4 * 4) / HWC) % DD;
    float sc = stats[o*2], sh = stats[o*2+1];
    const float inv_sqrt2 = 0.70710678118654752f;
    float g0 = fmaf(v.x, sc, sh);
    float g1 = fmaf(v.y, sc, sh);
    float g2 = fmaf(v.z, sc, sh);
    float g3 = fmaf(v.w, sc, sh);
    v.x = 0.5f * g0 * (1.f + erff(g0 * inv_sqrt2));
    v.y = 0.5f * g1 * (1.f + erff(g1 * inv_sqrt2));
    v.z = 0.5f * g2 * (1.f + erff(g2 * inv_sqrt2));
    v.w = 0.5f * g3 * (1.f + erff(g3 * inv_sqrt2));
    p[idx4] = v;
}

extern "C" void kernel_launch(void* const* d_in, const int* in_sizes, int n_in,
                              void* d_out, int out_size, void* d_ws, size_t ws_size,
                              hipStream_t stream) {
    const float* bev   = (const float*)d_in[0];
    const float* offw  = (const float*)d_in[1];
    const float* offb  = (const float*)d_in[2];
    const float* wtw   = (const float*)d_in[3];
    const float* wtb   = (const float*)d_in[4];
    const float* projw = (const float*)d_in[5];
    const float* gamma = (const float*)d_in[6];
    const float* beta  = (const float*)d_in[7];
    float* out = (float*)d_out;
    float* wsf = (float*)d_ws;

    float* oa    = wsf + OA_OFF;
    float* wtT   = wsf + WTT_OFF;
    float* wp    = wsf + WP_OFF;
    float* stats = wsf + STATS_OFF;
    double* part = (double*)(wsf + PART_OFF);
    float* bevt  = wsf + BEVT_OFF;                 // tier2 f32
    ushort* bevtb = (ushort*)(wsf + BEVT_OFF);     // full3 bf16
    ushort* wbf  = (ushort*)(wsf + WBF_OFF);
    ushort* wcb  = (ushort*)(wsf + WCB_OFF);
    float* part2 = wsf + PART2_OFF;                // PACC region (no bevtb alias)

    bool full3 = ws_size >= WS_NEED_FULL3;
    bool big   = ws_size >= WS_NEED_BEVT;

    if (full3) {
        hipLaunchKernelGGL(k0bc, dim3(72), dim3(256), 0, stream,
                           projw, offw, wtw, wbf, wcb);
        hipLaunchKernelGGL(k2t_bf, dim3(2048), dim3(256), 0, stream, bev, bevtb);
        hipLaunchKernelGGL(k1m_conv_mfma, dim3(4096), dim3(128), 0, stream,
                           bevtb, wcb, offb, wtb, oa);
        hipLaunchKernelGGL(k2f_sample_proj, dim3(4096), dim3(256), 0, stream,
                           bevtb, oa, wbf, out, part2);
        hipLaunchKernelGGL(k3b_finalize2, dim3(128), dim3(256), 0, stream,
                           part2, gamma, beta, stats);
    } else if (big) {
        hipLaunchKernelGGL(k0_prep, dim3(64), dim3(256), 0, stream,
                           projw, offw, wtw, wtT, wp);
        hipLaunchKernelGGL(k2t_transpose, dim3(2048), dim3(256), 0, stream, bev, bevt);
        hipLaunchKernelGGL(k1_convs, dim3(BB*HH), dim3(256), 0, stream,
                           bev, wp, offb, wtb, oa);
        hipLaunchKernelGGL(k2_sample_proj_t, dim3(BB*256), dim3(512), 0, stream,
                           bevt, oa, wtT, out);
        hipLaunchKernelGGL(k3_partial, dim3(512), dim3(256), 0, stream, out, part);
        hipLaunchKernelGGL(k3_finalize, dim3(1), dim3(128), 0, stream,
                           part, gamma, beta, stats);
    } else {
        hipLaunchKernelGGL(k0_prep, dim3(64), dim3(256), 0, stream,
                           projw, offw, wtw, wtT, wp);
        hipLaunchKernelGGL(k1_convs, dim3(BB*HH), dim3(256), 0, stream,
                           bev, wp, offb, wtb, oa);
        hipLaunchKernelGGL(k2_sample_proj, dim3(BB*256), dim3(512), 0, stream,
                           bev, oa, wtT, out);
        hipLaunchKernelGGL(k3_partial, dim3(512), dim3(256), 0, stream, out, part);
        hipLaunchKernelGGL(k3_finalize, dim3(1), dim3(128), 0, stream,
                           part, gamma, beta, stats);
    }
    hipLaunchKernelGGL(k4_bn_gelu, dim3((BB*DD*HWC)/1024), dim3(256), 0, stream,
                       out, stats);
}

// Round 15
// 151.251 us; speedup vs baseline: 1.0617x; 1.0335x over previous
//
#include <hip/hip_runtime.h>
#include <math.h>

#define BB 2
#define DD 128
#define HH 256
#define WW 256
#define KK 4
#define HWC (HH*WW)
#define SROW2 320   // d-slice stride in S (fused fallback kernels)

typedef unsigned int u32;
typedef unsigned short ushort;
typedef __attribute__((ext_vector_type(8))) short bf16x8;
typedef __attribute__((ext_vector_type(4))) float f32x4;

// ws float layout
#define OA_OFF    0
#define WTT_OFF   1572864
#define WP_OFF    1589248
#define STATS_OFF 1603072
#define PART_OFF  1603392
#define BEVT_OFF  1605440       // full3: bevtb bf16 (16.8M ushort = 8.39M float-slots)
#define YBF_OFF   9994048       // full3: pre-BN y bf16 (16.8M ushort) - 2nd half of BEVT region
#define PACC_OFF  18382656
#define PART2_OFF PACC_OFF      // full3: k2f block stats [wgid][256] f32
#define WBF_OFF   26771264      // proj W bf16
#define WCB_OFF   26779456      // conv W bf16 padded: 9*16*128 ushort
#define WS_NEED_BEVT  ((size_t)PACC_OFF * 4)
#define WS_NEED_FULL3 ((size_t)(WCB_OFF + 9216) * 4)

__device__ __forceinline__ u32 f2bf(float x) {
    u32 u = __builtin_bit_cast(u32, x);
    return (u + 0x7fffu + ((u >> 16) & 1u)) >> 16;
}
__device__ __forceinline__ u32 pkbf(float a, float b) {
    return f2bf(a) | (f2bf(b) << 16);
}
__device__ __forceinline__ float bflo(u32 d) { return __builtin_bit_cast(float, d << 16); }
__device__ __forceinline__ float bfhi(u32 d) { return __builtin_bit_cast(float, d & 0xffff0000u); }

// ---------------- Kernel 0: weight prep (fallback tiers only) ----------------
__global__ __launch_bounds__(256) void k0_prep(
    const float* __restrict__ projw, const float* __restrict__ offw,
    const float* __restrict__ wtw, float* __restrict__ wtT, float* __restrict__ wp)
{
    int idx = blockIdx.x * 256 + threadIdx.x;
    if (idx < 16384) {
        int d = idx >> 7, o = idx & 127;
        wtT[d * 128 + o] = projw[o * 128 + d];
    }
    if (idx < 13824) {
        int c = idx / 108; int r = idx % 108; int o = r / 9; int t = r % 9;
        wp[idx] = (o < 8) ? offw[(o*128 + c)*9 + t] : wtw[((o-8)*128 + c)*9 + t];
    }
}

// ---------------- Kernel 0bc: bf16 weight prep (proj + conv) ----------------
__global__ __launch_bounds__(256) void k0bc(
    const float* __restrict__ projw, const float* __restrict__ offw,
    const float* __restrict__ wtw, ushort* __restrict__ wbf,
    ushort* __restrict__ wcb)
{
    int idx = blockIdx.x * 256 + threadIdx.x;
    if (idx < 16384) wbf[idx] = (ushort)f2bf(projw[idx]);
    if (idx < 18432) {
        int tap = idx >> 11;
        int rem = idx & 2047;
        int oo = rem >> 7, c = rem & 127;
        float v = 0.f;
        if (oo < 8)       v = offw[(oo*128 + c)*9 + tap];
        else if (oo < 12) v = wtw[((oo-8)*128 + c)*9 + tap];
        wcb[idx] = (ushort)f2bf(v);
    }
}

// ---------------- Kernel Tb: NCHW f32 -> NHWC bf16 ----------------
__global__ __launch_bounds__(256) void k2t_bf(
    const float* __restrict__ bev, ushort* __restrict__ bevtb)
{
    __shared__ float T[64 * 128];
    int tid = threadIdx.x;
    int bidx = blockIdx.x;
    int b = bidx >> 10;
    int rem = bidx & 1023;
    int yrow = rem >> 2;
    int x0 = (rem & 3) << 6;

    const float* src = bev + ((size_t)b * DD) * HWC + (size_t)yrow * WW + x0;
    #pragma unroll 4
    for (int k = 0; k < 32; k++) {
        int flat = k * 256 + tid;
        int d = flat >> 6, xl = flat & 63;
        float v = src[(size_t)d * HWC + xl];
        T[xl * 128 + (((d >> 2) ^ (xl & 31)) << 2) + (d & 3)] = v;
    }
    __syncthreads();
    ushort* dst = bevtb + (((size_t)b * HH + yrow) * WW + x0) * 128;
    #pragma unroll 4
    for (int k = 0; k < 8; k++) {
        int flat = k * 256 + tid;
        int d4 = flat & 31, xl = (flat >> 5) & 63;
        float4 v = *(const float4*)&T[xl * 128 + ((d4 ^ (xl & 31)) << 2)];
        uint2 pk;
        pk.x = pkbf(v.x, v.y);
        pk.y = pkbf(v.z, v.w);
        *(uint2*)(dst + (size_t)xl * 128 + (d4 << 2)) = pk;
    }
}

// ---------------- Kernel 1m: 3x3 convs as implicit-GEMM MFMA, LDS-staged ----------------
// R14 post-mortem: 128-thread tile REGRESSED non-k2f time by ~8us -> revert to the
// R12-measured-best shape: 256 threads, 64-px tile, 50.7KB LDS, grid 2048.
__global__ __launch_bounds__(256) void k1m_conv_mfma(
    const ushort* __restrict__ bevtb, const ushort* __restrict__ wcb,
    const float* __restrict__ offb, const float* __restrict__ wtb,
    float* __restrict__ oa)
{
    __shared__ uint4 lds4[3168];   // 3 rows x 66 px x 16 slots x 16B = 50688 B

    int tid = threadIdx.x;
    int wv = tid >> 6;
    int l = tid & 63;
    int lm = l & 15, lk = l >> 4;
    int wgid = blockIdx.x;
    int lin = (wgid & 7) * 256 + (wgid >> 3);   // bijective XCD-contiguous remap
    int b = lin >> 10;
    int i = (lin >> 2) & 255;
    int jt = lin & 3;
    int x0 = jt * 64;

    const ushort* bb = bevtb + (size_t)b * HWC * 128;
    for (int z = tid; z < 3168; z += 256) {
        int row = z / 1056;
        int rem = z - row * 1056;
        int pl = rem >> 4;
        int q  = rem & 15;
        int yy = i - 1 + row;
        int x  = x0 - 1 + pl;
        bool ok = ((unsigned)yy < HH) && ((unsigned)x < WW);
        uint4 v = make_uint4(0u, 0u, 0u, 0u);
        if (ok) v = *(const uint4*)(bb + ((size_t)(yy * WW + x) << 7) + q * 8);
        lds4[row * 1056 + pl * 16 + (q ^ (pl & 15))] = v;
    }
    __syncthreads();

    f32x4 acc = (f32x4)(0.f);
    #pragma unroll
    for (int dy = 0; dy < 3; dy++) {
        #pragma unroll
        for (int dx = 0; dx < 3; dx++) {
            int pl = wv * 16 + lm + dx;
            const uint4* bp = &lds4[dy * 1056 + pl * 16];
            int sx = pl & 15;
            const ushort* ap = wcb + (size_t)((dy*3 + dx) * 16 + lm) * 128 + lk * 8;
            #pragma unroll
            for (int kk = 0; kk < 4; kk++) {
                bf16x8 bfr = *(const bf16x8*)&bp[(kk*4 + lk) ^ sx];
                bf16x8 afr = *(const bf16x8*)(ap + kk * 32);
                acc = __builtin_amdgcn_mfma_f32_16x16x32_bf16(afr, bfr, acc, 0, 0, 0);
            }
        }
    }

    float v[4];
    #pragma unroll
    for (int r = 0; r < 4; r++) v[r] = acc[r];

    int j = x0 + wv * 16 + lm;
    if (lk < 2) {
        #pragma unroll
        for (int r = 0; r < 4; r++) v[r] += offb[lk*4 + r];   // OFFSET_SCALE = 1.0
    } else if (lk == 2) {
        float l4[4];
        #pragma unroll
        for (int r = 0; r < 4; r++) l4[r] = v[r] + wtb[r];
        float m = fmaxf(fmaxf(l4[0], l4[1]), fmaxf(l4[2], l4[3]));
        float e[4]; float se = 0.f;
        #pragma unroll
        for (int r = 0; r < 4; r++) { e[r] = expf(l4[r] - m); se += e[r]; }
        float inv = 1.f / se;
        #pragma unroll
        for (int r = 0; r < 4; r++) v[r] = e[r] * inv;
    }
    if (lk < 3) {
        size_t basep = (size_t)b * 12 * HWC + (size_t)i * WW + j;
        #pragma unroll
        for (int r = 0; r < 4; r++)
            oa[basep + (size_t)(lk*4 + r) * HWC] = v[r];
    }
}

// ---------------- Kernel 2f: FUSED sample + 1x1 MFMA proj + BN stats ----------------
// R14: batched-ILP gather kept (proved -11us).  NEW: pre-BN y is written bf16 to ybf
// (33.5MB, free 2nd half of BEVT region) instead of f32 to d_out: k2f WRITE 70->36MB,
// k4 traffic 134->100MB.  BN stats still from exact f32 accumulators.
#define TAPPTR(t) (bt + ((size_t)((((t) & 1) ? (pa[(t) >> 1] >> 16) : (pa[(t) >> 1] & 0xffffu))) << 7))
#define FMA8(S, V, W) do { \
    S[0] = fmaf(W, bflo((V).x), S[0]); S[1] = fmaf(W, bfhi((V).x), S[1]); \
    S[2] = fmaf(W, bflo((V).y), S[2]); S[3] = fmaf(W, bfhi((V).y), S[3]); \
    S[4] = fmaf(W, bflo((V).z), S[4]); S[5] = fmaf(W, bfhi((V).z), S[5]); \
    S[6] = fmaf(W, bflo((V).w), S[6]); S[7] = fmaf(W, bfhi((V).w), S[7]); \
} while (0)

__global__ __launch_bounds__(256, 4) void k2f_sample_proj(
    const ushort* __restrict__ bevtb, const float* __restrict__ oa,
    const ushort* __restrict__ wbf, ushort* __restrict__ ybf,
    float* __restrict__ part2)
{
    __shared__ uint4 P[32 * 16];   // 8 KB

    int tid = threadIdx.x;
    int wgid = blockIdx.x;                       // 0..4095
    int lin = (wgid & 7) * 512 + (wgid >> 3);    // bijective XCD-contiguous remap
    int b = lin >> 11;
    int pix0 = (lin & 2047) << 5;                // 32 px per block

    // ---- gather phase: thread = (pixel, d-eighth) ----
    int q8 = tid & 7;
    int pixl = tid >> 3;                         // 0..31
    int pix = pix0 + pixl;
    int p = pix >> 8;
    int q = pix & 255;

    const float* ob = oa + (size_t)b * 12 * HWC + (size_t)p * WW + q;
    unsigned pa[8]; float cw[16];
    #pragma unroll
    for (int k = 0; k < 4; k++) {
        float dx = ob[(size_t)(2*k)   * HWC];
        float dy = ob[(size_t)(2*k+1) * HWC];
        float a  = ob[(size_t)(8+k)   * HWC];
        float x  = fminf(fmaxf((float)p + dx, 0.f), (float)(WW-1));
        float yv = fminf(fmaxf((float)q + dy, 0.f), (float)(HH-1));
        float x0f = floorf(x); float y0f = floorf(yv);
        int x0 = (int)x0f; int y0 = (int)y0f;
        int x1 = min(x0 + 1, WW - 1); int y1 = min(y0 + 1, HH - 1);
        float wx = x - x0f; float wy = yv - y0f;
        pa[k*2+0] = (unsigned)(y0*WW + x0) | ((unsigned)(y0*WW + x1) << 16);
        pa[k*2+1] = (unsigned)(y1*WW + x0) | ((unsigned)(y1*WW + x1) << 16);
        cw[k*4+0] = a * (1.f - wx) * (1.f - wy);
        cw[k*4+1] = a * wx * (1.f - wy);
        cw[k*4+2] = a * (1.f - wx) * wy;
        cw[k*4+3] = a * wx * wy;
    }

    const ushort* bt = bevtb + (size_t)b * HWC * 128 + q8 * 8;

    float s[2][8];
    #pragma unroll
    for (int c = 0; c < 2; c++)
        #pragma unroll
        for (int e = 0; e < 8; e++) s[c][e] = 0.f;

    uint4 L0[8], L1[8];
    #pragma unroll
    for (int t = 0; t < 8; t++) L0[t] = *(const uint4*)(TAPPTR(t));
    #pragma unroll
    for (int t = 0; t < 8; t++) L1[t] = *(const uint4*)(TAPPTR(t + 8));
    #pragma unroll
    for (int t = 0; t < 8; t++) {
        uint4 v = L0[t];
        L0[t] = *(const uint4*)(TAPPTR(t) + 64);
        FMA8(s[0], v, cw[t]);
    }
    #pragma unroll
    for (int t = 0; t < 8; t++) {
        uint4 v = L1[t];
        L1[t] = *(const uint4*)(TAPPTR(t + 8) + 64);
        FMA8(s[0], v, cw[t + 8]);
    }
    #pragma unroll
    for (int t = 0; t < 8; t++) FMA8(s[1], L0[t], cw[t]);
    #pragma unroll
    for (int t = 0; t < 8; t++) FMA8(s[1], L1[t], cw[t + 8]);

    int sxr = pixl & 15;
    #pragma unroll
    for (int c = 0; c < 2; c++) {
        uint4 pk;
        pk.x = pkbf(s[c][0], s[c][1]);
        pk.y = pkbf(s[c][2], s[c][3]);
        pk.z = pkbf(s[c][4], s[c][5]);
        pk.w = pkbf(s[c][6], s[c][7]);
        P[pixl * 16 + ((c * 8 + q8) ^ sxr)] = pk;
    }
    __syncthreads();

    // ---- GEMM phase ----
    int wv = tid >> 6;
    int l = tid & 63;
    int lm = l & 15, lk = l >> 4;
    int o0 = wv << 5;

    f32x4 acc[2][2];
    #pragma unroll
    for (int ot = 0; ot < 2; ot++)
        #pragma unroll
        for (int nt = 0; nt < 2; nt++)
            acc[ot][nt] = (f32x4)(0.f);

    #pragma unroll
    for (int ot = 0; ot < 2; ot++) {
        const ushort* ap = wbf + (size_t)(o0 + ot * 16 + lm) * 128 + lk * 8;
        bf16x8 a4[4];
        #pragma unroll
        for (int kk = 0; kk < 4; kk++)
            a4[kk] = *(const bf16x8*)(ap + kk * 32);
        #pragma unroll
        for (int nt = 0; nt < 2; nt++) {
            int row = nt * 16 + lm;
            #pragma unroll
            for (int kk = 0; kk < 4; kk++) {
                bf16x8 bfr = *(const bf16x8*)&P[row * 16 + ((kk * 4 + lk) ^ lm)];
                acc[ot][nt] = __builtin_amdgcn_mfma_f32_16x16x32_bf16(
                    a4[kk], bfr, acc[ot][nt], 0, 0, 0);
            }
        }
    }

    // pre-BN y -> bf16 (BN stats stay f32-exact below)
    #pragma unroll
    for (int ot = 0; ot < 2; ot++)
        #pragma unroll
        for (int nt = 0; nt < 2; nt++)
            #pragma unroll
            for (int r = 0; r < 4; r++)
                ybf[((size_t)b * DD + o0 + ot * 16 + lk * 4 + r) * HWC + pix0 + nt * 16 + lm]
                    = (ushort)f2bf(acc[ot][nt][r]);

    float sm[2][4], sq[2][4];
    #pragma unroll
    for (int ot = 0; ot < 2; ot++)
        #pragma unroll
        for (int r = 0; r < 4; r++) { sm[ot][r] = 0.f; sq[ot][r] = 0.f; }
    #pragma unroll
    for (int ot = 0; ot < 2; ot++)
        #pragma unroll
        for (int nt = 0; nt < 2; nt++)
            #pragma unroll
            for (int r = 0; r < 4; r++) {
                float v = acc[ot][nt][r];
                sm[ot][r] += v;
                sq[ot][r] = fmaf(v, v, sq[ot][r]);
            }
    #pragma unroll
    for (int m = 1; m < 16; m <<= 1) {
        #pragma unroll
        for (int ot = 0; ot < 2; ot++)
            #pragma unroll
            for (int r = 0; r < 4; r++) {
                sm[ot][r] += __shfl_xor(sm[ot][r], m);
                sq[ot][r] += __shfl_xor(sq[ot][r], m);
            }
    }
    if (lm == 0) {
        float* pw = part2 + (size_t)wgid * 256;
        #pragma unroll
        for (int ot = 0; ot < 2; ot++)
            #pragma unroll
            for (int r = 0; r < 4; r++) {
                int o = o0 + ot * 16 + lk * 4 + r;
                pw[o] = sm[ot][r];
                pw[128 + o] = sq[ot][r];
            }
    }
}

// ---------------- Kernel 3b': finalize BN from k2f block partials ----------------
__global__ __launch_bounds__(256) void k3b_finalize2(
    const float* __restrict__ part2, const float* __restrict__ gamma,
    const float* __restrict__ beta, float* __restrict__ stats)
{
    int o = blockIdx.x; int tid = threadIdx.x;
    double s = 0.0, s2 = 0.0;
    for (int w = tid; w < 4096; w += 256) {
        s  += (double)part2[(size_t)w * 256 + o];
        s2 += (double)part2[(size_t)w * 256 + 128 + o];
    }
    __shared__ double ls[256], ls2[256];
    ls[tid] = s; ls2[tid] = s2;
    __syncthreads();
    for (int off = 128; off > 0; off >>= 1) {
        if (tid < off) { ls[tid] += ls[tid+off]; ls2[tid] += ls2[tid+off]; }
        __syncthreads();
    }
    if (tid == 0) {
        double N = (double)(BB * HWC);
        double mean = ls[0] / N;
        double var = ls2[0] / N - mean * mean;
        double invs = 1.0 / sqrt(var + 1e-5);
        double g = (double)gamma[o];
        stats[o*2]   = (float)(g * invs);
        stats[o*2+1] = (float)((double)beta[o] - mean * g * invs);
    }
}

// ---------------- Kernel 4bf: BN + exact GELU, bf16 y -> f32 out ----------------
__global__ __launch_bounds__(256) void k4_bn_gelu_bf(
    const ushort* __restrict__ ybf, const float* __restrict__ stats,
    float* __restrict__ out)
{
    size_t idx8 = (size_t)blockIdx.x * 256 + threadIdx.x;   // 8-elem index
    uint4 v = ((const uint4*)ybf)[idx8];
    int o = (int)((idx8 * 8) / HWC) % DD;
    float sc = stats[o*2], sh = stats[o*2+1];
    const float is2 = 0.70710678118654752f;
    float g[8];
    g[0] = fmaf(bflo(v.x), sc, sh); g[1] = fmaf(bfhi(v.x), sc, sh);
    g[2] = fmaf(bflo(v.y), sc, sh); g[3] = fmaf(bfhi(v.y), sc, sh);
    g[4] = fmaf(bflo(v.z), sc, sh); g[5] = fmaf(bfhi(v.z), sc, sh);
    g[6] = fmaf(bflo(v.w), sc, sh); g[7] = fmaf(bfhi(v.w), sc, sh);
    float4 o0, o1;
    o0.x = 0.5f * g[0] * (1.f + erff(g[0] * is2));
    o0.y = 0.5f * g[1] * (1.f + erff(g[1] * is2));
    o0.z = 0.5f * g[2] * (1.f + erff(g[2] * is2));
    o0.w = 0.5f * g[3] * (1.f + erff(g[3] * is2));
    o1.x = 0.5f * g[4] * (1.f + erff(g[4] * is2));
    o1.y = 0.5f * g[5] * (1.f + erff(g[5] * is2));
    o1.z = 0.5f * g[6] * (1.f + erff(g[6] * is2));
    o1.w = 0.5f * g[7] * (1.f + erff(g[7] * is2));
    ((float4*)out)[idx8 * 2]     = o0;
    ((float4*)out)[idx8 * 2 + 1] = o1;
}

// ---------------- Kernel 1 (tier2 fallback): full 128-channel conv ----------------
__global__ __launch_bounds__(256) void k1_convs(
    const float* __restrict__ bev, const float* __restrict__ wp,
    const float* __restrict__ offb, const float* __restrict__ wtb,
    float* __restrict__ oa)
{
    __shared__ float rows[2][3][260];
    int tid = threadIdx.x;
    int p = blockIdx.x;
    int b = p / HH; int i = p % HH; int j = tid;
    const float* bb = bev + (size_t)b * DD * HWC;

    if (tid < 12) { int bf = tid / 6, r = tid % 6; rows[bf][r >> 1][(r & 1) ? 257 : 0] = 0.f; }
    #pragma unroll
    for (int l = 0; l < 3; l++) {
        int yy = i + l - 1;
        rows[0][l][1 + tid] = ((unsigned)yy < HH) ? bb[yy * WW + tid] : 0.f;
    }
    __syncthreads();

    float acc[12];
    #pragma unroll
    for (int o = 0; o < 12; o++) acc[o] = 0.f;

    for (int c = 0; c < 128; c++) {
        int cb = c & 1, nb = cb ^ 1;
        float rv[3];
        if (c < 127) {
            const float* pln = bb + (size_t)(c + 1) * HWC;
            #pragma unroll
            for (int l = 0; l < 3; l++) {
                int yy = i + l - 1;
                rv[l] = ((unsigned)yy < HH) ? pln[yy * WW + tid] : 0.f;
            }
        }
        float v[9];
        #pragma unroll
        for (int dy = 0; dy < 3; dy++)
            #pragma unroll
            for (int dx = 0; dx < 3; dx++)
                v[dy*3 + dx] = rows[cb][dy][tid + dx];
        const float* wc = wp + c * 108;
        #pragma unroll
        for (int o = 0; o < 12; o++) {
            float s = acc[o];
            #pragma unroll
            for (int t = 0; t < 9; t++) s = fmaf(wc[o*9 + t], v[t], s);
            acc[o] = s;
        }
        if (c < 127) {
            #pragma unroll
            for (int l = 0; l < 3; l++) rows[nb][l][1 + tid] = rv[l];
        }
        __syncthreads();
    }

    float outv[12];
    #pragma unroll
    for (int o = 0; o < 8; o++) outv[o] = acc[o] + offb[o];
    float l4[4];
    #pragma unroll
    for (int k = 0; k < 4; k++) l4[k] = acc[8+k] + wtb[k];
    float m = fmaxf(fmaxf(l4[0], l4[1]), fmaxf(l4[2], l4[3]));
    float e[4]; float se = 0.f;
    #pragma unroll
    for (int k = 0; k < 4; k++) { e[k] = expf(l4[k] - m); se += e[k]; }
    float inv = 1.f / se;
    #pragma unroll
    for (int k = 0; k < 4; k++) outv[8+k] = e[k] * inv;

    size_t basep = (size_t)b * 12 * HWC + (size_t)i * WW + j;
    #pragma unroll
    for (int o = 0; o < 12; o++) oa[basep + (size_t)o * HWC] = outv[o];
}

// ---------------- Kernel 2 fallback (tier2/3, NCHW) ----------------
__global__ __launch_bounds__(512, 2) void k2_sample_proj(
    const float* __restrict__ bev, const float* __restrict__ oa,
    const float* __restrict__ wt, float* __restrict__ y)
{
    __shared__ float S[2][16 * SROW2];
    int tid = threadIdx.x;
    int bidx = blockIdx.x;
    int b  = bidx >> 8;
    int p0 = ((bidx >> 4) & 15) * 16;
    int q0 = (bidx & 15) * 16;
    int pix = tid & 255;
    int gq = pix >> 4;
    int gp = pix & 15;
    int dgrp = tid >> 8;
    int swr = gp * 20 + gq;
    int wv = tid >> 6;
    int wvu = __builtin_amdgcn_readfirstlane(wv);
    int lane = tid & 63;
    int lp = lane >> 2;
    int q4 = (lane & 3) << 2;
    int soff = lp * 20 + q4;

    const float* ob = oa + (size_t)b * 12 * HWC + (size_t)(p0 + gp) * WW + (q0 + gq);
    unsigned pa[8]; float cw[16];
    #pragma unroll
    for (int k = 0; k < 4; k++) {
        float dx = ob[(size_t)(2*k)   * HWC];
        float dy = ob[(size_t)(2*k+1) * HWC];
        float a  = ob[(size_t)(8+k)   * HWC];
        float x  = fminf(fmaxf((float)(p0 + gp) + dx, 0.f), (float)(WW-1));
        float yv = fminf(fmaxf((float)(q0 + gq) + dy, 0.f), (float)(HH-1));
        float x0f = floorf(x); float y0f = floorf(yv);
        int x0 = (int)x0f; int y0 = (int)y0f;
        int x1 = min(x0 + 1, WW - 1); int y1 = min(y0 + 1, HH - 1);
        float wx = x - x0f; float wy = yv - y0f;
        pa[k*2+0] = (unsigned)(y0*WW + x0) | ((unsigned)(y0*WW + x1) << 16);
        pa[k*2+1] = (unsigned)(y1*WW + x0) | ((unsigned)(y1*WW + x1) << 16);
        cw[k*4+0] = a * (1.f - wx) * (1.f - wy);
        cw[k*4+1] = a * wx * (1.f - wy);
        cw[k*4+2] = a * (1.f - wx) * wy;
        cw[k*4+3] = a * wx * wy;
    }
    const float* bb = bev + (size_t)b * DD * HWC;
    float acc[64];
    #pragma unroll
    for (int t = 0; t < 64; t++) acc[t] = 0.f;
    #pragma unroll
    for (int dd = 0; dd < 8; dd++) {
        const float* pl = bb + (size_t)(dgrp*8 + dd) * HWC;
        float s = 0.f;
        #pragma unroll
        for (int t = 0; t < 8; t++) {
            unsigned a01 = pa[t];
            s = fmaf(cw[2*t],   pl[a01 & 0xffffu], s);
            s = fmaf(cw[2*t+1], pl[a01 >> 16], s);
        }
        S[0][(dgrp*8 + dd) * SROW2 + swr] = s;
    }
    __syncthreads();
    for (int c = 0; c < 8; c++) {
        int cur = c & 1;
        const float* Sc = &S[cur][0];
        float* Sn = &S[cur ^ 1][0];
        int d0 = c * 16;
        int d0n = d0 + 16;
        bool more = (c < 7);
        #pragma unroll
        for (int dl = 0; dl < 16; dl++) {
            if (dl < 8) {
                if (more) {
                    const float* pl = bb + (size_t)(d0n + dgrp*8 + dl) * HWC;
                    float s = 0.f;
                    #pragma unroll
                    for (int t = 0; t < 8; t++) {
                        unsigned a01 = pa[t];
                        s = fmaf(cw[2*t],   pl[a01 & 0xffffu], s);
                        s = fmaf(cw[2*t+1], pl[a01 >> 16], s);
                    }
                    Sn[(dgrp*8 + dl) * SROW2 + swr] = s;
                }
            }
            float4 sv = *(const float4*)(Sc + dl * SROW2 + soff);
            const float4* wq = (const float4*)(wt + (size_t)(d0 + dl) * 128 + wvu * 16);
            #pragma unroll
            for (int oi4 = 0; oi4 < 4; oi4++) {
                float4 w4 = wq[oi4];
                int ob4 = oi4 * 16;
                acc[ob4+ 0] = fmaf(w4.x, sv.x, acc[ob4+ 0]);
                acc[ob4+ 1] = fmaf(w4.x, sv.y, acc[ob4+ 1]);
                acc[ob4+ 2] = fmaf(w4.x, sv.z, acc[ob4+ 2]);
                acc[ob4+ 3] = fmaf(w4.x, sv.w, acc[ob4+ 3]);
                acc[ob4+ 4] = fmaf(w4.y, sv.x, acc[ob4+ 4]);
                acc[ob4+ 5] = fmaf(w4.y, sv.y, acc[ob4+ 5]);
                acc[ob4+ 6] = fmaf(w4.y, sv.z, acc[ob4+ 6]);
                acc[ob4+ 7] = fmaf(w4.y, sv.w, acc[ob4+ 7]);
                acc[ob4+ 8] = fmaf(w4.z, sv.x, acc[ob4+ 8]);
                acc[ob4+ 9] = fmaf(w4.z, sv.y, acc[ob4+ 9]);
                acc[ob4+10] = fmaf(w4.z, sv.z, acc[ob4+10]);
                acc[ob4+11] = fmaf(w4.z, sv.w, acc[ob4+11]);
                acc[ob4+12] = fmaf(w4.w, sv.x, acc[ob4+12]);
                acc[ob4+13] = fmaf(w4.w, sv.y, acc[ob4+13]);
                acc[ob4+14] = fmaf(w4.w, sv.z, acc[ob4+14]);
                acc[ob4+15] = fmaf(w4.w, sv.w, acc[ob4+15]);
            }
        }
        __syncthreads();
    }
    size_t base = (size_t)b * DD * HWC + (size_t)(p0 + lp) * WW + (q0 + q4);
    #pragma unroll
    for (int oi = 0; oi < 16; oi++) {
        int o = wv * 16 + oi;
        float4 v = make_float4(acc[oi*4+0], acc[oi*4+1], acc[oi*4+2], acc[oi*4+3]);
        *(float4*)(y + base + (size_t)o * HWC) = v;
    }
}

// ---------------- Kernel 3a/3b: BN stats (fallback tiers only) ----------------
__global__ __launch_bounds__(256) void k3_partial(
    const float* __restrict__ y, double* __restrict__ part)
{
    int blk = blockIdx.x;
    int o = blk >> 2; int sub = blk & 3; int b = sub >> 1; int half = sub & 1;
    const float4* pl = (const float4*)(y + ((size_t)b * DD + o) * HWC + half * (HWC/2));
    int tid = threadIdx.x;
    double s = 0.0, s2 = 0.0;
    for (int idx = tid; idx < HWC/8; idx += 256) {
        float4 v = pl[idx];
        s  += (double)v.x + (double)v.y + (double)v.z + (double)v.w;
        s2 += (double)v.x*v.x + (double)v.y*v.y + (double)v.z*v.z + (double)v.w*v.w;
    }
    __shared__ double ls[256], ls2[256];
    ls[tid] = s; ls2[tid] = s2;
    __syncthreads();
    for (int off = 128; off > 0; off >>= 1) {
        if (tid < off) { ls[tid] += ls[tid+off]; ls2[tid] += ls2[tid+off]; }
        __syncthreads();
    }
    if (tid == 0) { part[blk*2] = ls[0]; part[blk*2+1] = ls2[0]; }
}

__global__ __launch_bounds__(128) void k3_finalize(
    const double* __restrict__ part, const float* __restrict__ gamma,
    const float* __restrict__ beta, float* __restrict__ stats)
{
    int o = threadIdx.x;
    double s = 0.0, s2 = 0.0;
    #pragma unroll
    for (int j = 0; j < 4; j++) { s += part[(o*4+j)*2]; s2 += part[(o*4+j)*2+1]; }
    double N = (double)(BB * HWC);
    double mean = s / N;
    double var = s2 / N - mean * mean;
    double invs = 1.0 / sqrt(var + 1e-5);
    double g = (double)gamma[o];
    stats[o*2]   = (float)(g * invs);
    stats[o*2+1] = (float)((double)beta[o] - mean * g * invs);
}

// ---------------- Kernel 4: BN + exact GELU, f32 in-place (fallback tiers) ----------------
__global__ __launch_bounds__(256) void k4_bn_gelu(
    float* __restrict__ y, const float* __restrict__ stats)
{
    size_t idx4 = (size_t)blockIdx.x * 256 + threadIdx.x;
    float4* p = (float4*)y;
    float4 v = p[idx4];
    int o = (int)((idx4 * 4) / HWC) % DD;
    float sc = stats[o*2], sh = stats[o*2+1];
    const float inv_sqrt2 = 0.70710678118654752f;
    float g0 = fmaf(v.x, sc, sh);
    float g1 = fmaf(v.y, sc, sh);
    float g2 = fmaf(v.z, sc, sh);
    float g3 = fmaf(v.w, sc, sh);
    v.x = 0.5f * g0 * (1.f + erff(g0 * inv_sqrt2));
    v.y = 0.5f * g1 * (1.f + erff(g1 * inv_sqrt2));
    v.z = 0.5f * g2 * (1.f + erff(g2 * inv_sqrt2));
    v.w = 0.5f * g3 * (1.f + erff(g3 * inv_sqrt2));
    p[idx4] = v;
}

extern "C" void kernel_launch(void* const* d_in, const int* in_sizes, int n_in,
                              void* d_out, int out_size, void* d_ws, size_t ws_size,
                              hipStream_t stream) {
    const float* bev   = (const float*)d_in[0];
    const float* offw  = (const float*)d_in[1];
    const float* offb  = (const float*)d_in[2];
    const float* wtw   = (const float*)d_in[3];
    const float* wtb   = (const float*)d_in[4];
    const float* projw = (const float*)d_in[5];
    const float* gamma = (const float*)d_in[6];
    const float* beta  = (const float*)d_in[7];
    float* out = (float*)d_out;
    float* wsf = (float*)d_ws;

    float* oa    = wsf + OA_OFF;
    float* wtT   = wsf + WTT_OFF;
    float* wp    = wsf + WP_OFF;
    float* stats = wsf + STATS_OFF;
    double* part = (double*)(wsf + PART_OFF);
    ushort* bevtb = (ushort*)(wsf + BEVT_OFF);     // full3 bf16
    ushort* ybf   = (ushort*)(wsf + YBF_OFF);      // full3 pre-BN y bf16
    ushort* wbf  = (ushort*)(wsf + WBF_OFF);
    ushort* wcb  = (ushort*)(wsf + WCB_OFF);
    float* part2 = wsf + PART2_OFF;

    bool full3 = ws_size >= WS_NEED_FULL3;

    if (full3) {
        hipLaunchKernelGGL(k0bc, dim3(72), dim3(256), 0, stream,
                           projw, offw, wtw, wbf, wcb);
        hipLaunchKernelGGL(k2t_bf, dim3(2048), dim3(256), 0, stream, bev, bevtb);
        hipLaunchKernelGGL(k1m_conv_mfma, dim3(2048), dim3(256), 0, stream,
                           bevtb, wcb, offb, wtb, oa);
        hipLaunchKernelGGL(k2f_sample_proj, dim3(4096), dim3(256), 0, stream,
                           bevtb, oa, wbf, ybf, part2);
        hipLaunchKernelGGL(k3b_finalize2, dim3(128), dim3(256), 0, stream,
                           part2, gamma, beta, stats);
        hipLaunchKernelGGL(k4_bn_gelu_bf, dim3((BB*DD*HWC)/2048), dim3(256), 0, stream,
                           ybf, stats, out);
    } else {
        hipLaunchKernelGGL(k0_prep, dim3(64), dim3(256), 0, stream,
                           projw, offw, wtw, wtT, wp);
        hipLaunchKernelGGL(k1_convs, dim3(BB*HH), dim3(256), 0, stream,
                           bev, wp, offb, wtb, oa);
        hipLaunchKernelGGL(k2_sample_proj, dim3(BB*256), dim3(512), 0, stream,
                           bev, oa, wtT, out);
        hipLaunchKernelGGL(k3_partial, dim3(512), dim3(256), 0, stream, out, part);
        hipLaunchKernelGGL(k3_finalize, dim3(1), dim3(128), 0, stream,
                           part, gamma, beta, stats);
        hipLaunchKernelGGL(k4_bn_gelu, dim3((BB*DD*HWC)/1024), dim3(256), 0, stream,
                           out, stats);
    }
}

// Round 16
// 140.013 us; speedup vs baseline: 1.1470x; 1.0803x over previous
//
#include <hip/hip_runtime.h>
#include <math.h>

#define BB 2
#define DD 128
#define HH 256
#define WW 256
#define KK 4
#define HWC (HH*WW)
#define SROW2 320   // d-slice stride in S (fused fallback kernels)

typedef unsigned int u32;
typedef unsigned short ushort;
typedef __attribute__((ext_vector_type(8))) short bf16x8;
typedef __attribute__((ext_vector_type(4))) float f32x4;

// ws float layout
#define OA_OFF    0
#define WTT_OFF   1572864
#define WP_OFF    1589248
#define STATS_OFF 1603072
#define PART_OFF  1603392
#define BEVT_OFF  1605440       // full3: bevtb bf16 (16.8M ushort = 8.39M float-slots)
#define YBF_OFF   9994048       // full3: pre-BN y bf16 (16.8M ushort) - 2nd half of BEVT region
#define PACC_OFF  18382656
#define PART2_OFF PACC_OFF      // full3: k2f block stats [wgid][256] f32
#define WBF_OFF   26771264      // proj W bf16
#define WCB_OFF   26779456      // conv W bf16 padded: 9*16*128 ushort
#define WS_NEED_BEVT  ((size_t)PACC_OFF * 4)
#define WS_NEED_FULL3 ((size_t)(WCB_OFF + 9216) * 4)

__device__ __forceinline__ u32 f2bf(float x) {
    u32 u = __builtin_bit_cast(u32, x);
    return (u + 0x7fffu + ((u >> 16) & 1u)) >> 16;
}
__device__ __forceinline__ u32 pkbf(float a, float b) {
    return f2bf(a) | (f2bf(b) << 16);
}
__device__ __forceinline__ float bflo(u32 d) { return __builtin_bit_cast(float, d << 16); }
__device__ __forceinline__ float bfhi(u32 d) { return __builtin_bit_cast(float, d & 0xffff0000u); }

// ---------------- Kernel 0: weight prep (fallback tier only) ----------------
__global__ __launch_bounds__(256) void k0_prep(
    const float* __restrict__ projw, const float* __restrict__ offw,
    const float* __restrict__ wtw, float* __restrict__ wtT, float* __restrict__ wp)
{
    int idx = blockIdx.x * 256 + threadIdx.x;
    if (idx < 16384) {
        int d = idx >> 7, o = idx & 127;
        wtT[d * 128 + o] = projw[o * 128 + d];
    }
    if (idx < 13824) {
        int c = idx / 108; int r = idx % 108; int o = r / 9; int t = r % 9;
        wp[idx] = (o < 8) ? offw[(o*128 + c)*9 + t] : wtw[((o-8)*128 + c)*9 + t];
    }
}

// ---------------- Kernel 0bc: bf16 weight prep (proj + conv) ----------------
__global__ __launch_bounds__(256) void k0bc(
    const float* __restrict__ projw, const float* __restrict__ offw,
    const float* __restrict__ wtw, ushort* __restrict__ wbf,
    ushort* __restrict__ wcb)
{
    int idx = blockIdx.x * 256 + threadIdx.x;
    if (idx < 16384) wbf[idx] = (ushort)f2bf(projw[idx]);
    if (idx < 18432) {
        int tap = idx >> 11;
        int rem = idx & 2047;
        int oo = rem >> 7, c = rem & 127;
        float v = 0.f;
        if (oo < 8)       v = offw[(oo*128 + c)*9 + tap];
        else if (oo < 12) v = wtw[((oo-8)*128 + c)*9 + tap];
        wcb[idx] = (ushort)f2bf(v);
    }
}

// ---------------- Kernel Tb: NCHW f32 -> NHWC bf16 ----------------
__global__ __launch_bounds__(256) void k2t_bf(
    const float* __restrict__ bev, ushort* __restrict__ bevtb)
{
    __shared__ float T[64 * 128];
    int tid = threadIdx.x;
    int bidx = blockIdx.x;
    int b = bidx >> 10;
    int rem = bidx & 1023;
    int yrow = rem >> 2;
    int x0 = (rem & 3) << 6;

    const float* src = bev + ((size_t)b * DD) * HWC + (size_t)yrow * WW + x0;
    #pragma unroll 4
    for (int k = 0; k < 32; k++) {
        int flat = k * 256 + tid;
        int d = flat >> 6, xl = flat & 63;
        float v = src[(size_t)d * HWC + xl];
        T[xl * 128 + (((d >> 2) ^ (xl & 31)) << 2) + (d & 3)] = v;
    }
    __syncthreads();
    ushort* dst = bevtb + (((size_t)b * HH + yrow) * WW + x0) * 128;
    #pragma unroll 4
    for (int k = 0; k < 8; k++) {
        int flat = k * 256 + tid;
        int d4 = flat & 31, xl = (flat >> 5) & 63;
        float4 v = *(const float4*)&T[xl * 128 + ((d4 ^ (xl & 31)) << 2)];
        uint2 pk;
        pk.x = pkbf(v.x, v.y);
        pk.y = pkbf(v.z, v.w);
        *(uint2*)(dst + (size_t)xl * 128 + (d4 << 2)) = pk;
    }
}

// ---------------- Kernel 1m: 3x3 convs as implicit-GEMM MFMA, ROLLING row band ----------------
// R15 budget: k1m ~50us, staging-dominated (each block staged 3 rows for 1 output row ->
// every row staged 3x globally).  Fix: block = 4-row band with 3 rotating LDS row
// buffers (slot=(a+1)%3, runtime-mod LDS addressing); per row: compute -> barrier ->
// stage next row into retiring slot -> barrier.  Staging per output row: 3 -> 1.5 rows.
// Grid 512 (2 blocks/CU).  MFMA/swizzle identity unchanged (R12-verified).
__global__ __launch_bounds__(256) void k1m_conv_mfma(
    const ushort* __restrict__ bevtb, const ushort* __restrict__ wcb,
    const float* __restrict__ offb, const float* __restrict__ wtb,
    float* __restrict__ oa)
{
    __shared__ uint4 lds4[3 * 1056];   // 3 row-buffers x 66 px x 16 slots x 16B = 50688 B

    int tid = threadIdx.x;
    int wv = tid >> 6;
    int l = tid & 63;
    int lm = l & 15, lk = l >> 4;
    int wgid = blockIdx.x;                      // 0..511
    int lin = (wgid & 7) * 64 + (wgid >> 3);    // bijective XCD-contiguous remap
    int b = lin >> 8;
    int band = (lin >> 2) & 63;
    int jt = lin & 3;
    int i0 = band * 4;
    int x0 = jt * 64;

    const ushort* bb = bevtb + (size_t)b * HWC * 128;

    // stage absolute row a into buffer slot s (zero-filled OOB)
    #define STAGE_ROW(a, s) do {                                                  \
        int _a = (a); int _s = (s);                                               \
        bool rok = ((unsigned)_a < HH);                                           \
        for (int z = tid; z < 1056; z += 256) {                                   \
            int pl = z >> 4; int qq = z & 15;                                     \
            int x = x0 - 1 + pl;                                                  \
            bool ok = rok && ((unsigned)x < WW);                                  \
            uint4 v = make_uint4(0u, 0u, 0u, 0u);                                 \
            if (ok) v = *(const uint4*)(bb + ((size_t)(_a * WW + x) << 7) + qq * 8); \
            lds4[_s * 1056 + pl * 16 + (qq ^ (pl & 15))] = v;                     \
        }                                                                         \
    } while (0)

    // prologue: rows i0-1, i0, i0+1  (slot(a) = (a+1) % 3; i0-1 >= -1 so a+1 >= 0)
    STAGE_ROW(i0 - 1, i0 % 3);
    STAGE_ROW(i0,     (i0 + 1) % 3);
    STAGE_ROW(i0 + 1, (i0 + 2) % 3);
    __syncthreads();

    #pragma unroll
    for (int r = 0; r < 4; r++) {
        int i = i0 + r;
        int s0 = i % 3;           // row i-1
        int s1 = (i + 1) % 3;     // row i
        int s2 = (i + 2) % 3;     // row i+1
        int slots[3] = { s0, s1, s2 };

        f32x4 acc = (f32x4)(0.f);
        #pragma unroll
        for (int dy = 0; dy < 3; dy++) {
            #pragma unroll
            for (int dx = 0; dx < 3; dx++) {
                int pl = wv * 16 + lm + dx;
                const uint4* bp = &lds4[slots[dy] * 1056 + pl * 16];
                int sx = pl & 15;
                const ushort* ap = wcb + (size_t)((dy*3 + dx) * 16 + lm) * 128 + lk * 8;
                #pragma unroll
                for (int kk = 0; kk < 4; kk++) {
                    bf16x8 bfr = *(const bf16x8*)&bp[(kk*4 + lk) ^ sx];
                    bf16x8 afr = *(const bf16x8*)(ap + kk * 32);
                    acc = __builtin_amdgcn_mfma_f32_16x16x32_bf16(afr, bfr, acc, 0, 0, 0);
                }
            }
        }

        float v[4];
        #pragma unroll
        for (int t = 0; t < 4; t++) v[t] = acc[t];

        int j = x0 + wv * 16 + lm;
        if (lk < 2) {
            #pragma unroll
            for (int t = 0; t < 4; t++) v[t] += offb[lk*4 + t];   // OFFSET_SCALE = 1.0
        } else if (lk == 2) {
            float l4[4];
            #pragma unroll
            for (int t = 0; t < 4; t++) l4[t] = v[t] + wtb[t];
            float m = fmaxf(fmaxf(l4[0], l4[1]), fmaxf(l4[2], l4[3]));
            float e[4]; float se = 0.f;
            #pragma unroll
            for (int t = 0; t < 4; t++) { e[t] = expf(l4[t] - m); se += e[t]; }
            float inv = 1.f / se;
            #pragma unroll
            for (int t = 0; t < 4; t++) v[t] = e[t] * inv;
        }
        if (lk < 3) {
            size_t basep = (size_t)b * 12 * HWC + (size_t)i * WW + j;
            #pragma unroll
            for (int t = 0; t < 4; t++)
                oa[basep + (size_t)(lk*4 + t) * HWC] = v[t];
        }

        __syncthreads();               // all reads of the 3 rows complete
        if (r < 3) {
            STAGE_ROW(i + 2, i % 3);   // overwrite the slot of row i-1
            __syncthreads();
        }
    }
    #undef STAGE_ROW
}

// ---------------- Kernel 2f: FUSED sample + 1x1 MFMA proj + BN stats ----------------
#define TAPPTR(t) (bt + ((size_t)((((t) & 1) ? (pa[(t) >> 1] >> 16) : (pa[(t) >> 1] & 0xffffu))) << 7))
#define FMA8(S, V, W) do { \
    S[0] = fmaf(W, bflo((V).x), S[0]); S[1] = fmaf(W, bfhi((V).x), S[1]); \
    S[2] = fmaf(W, bflo((V).y), S[2]); S[3] = fmaf(W, bfhi((V).y), S[3]); \
    S[4] = fmaf(W, bflo((V).z), S[4]); S[5] = fmaf(W, bfhi((V).z), S[5]); \
    S[6] = fmaf(W, bflo((V).w), S[6]); S[7] = fmaf(W, bfhi((V).w), S[7]); \
} while (0)

__global__ __launch_bounds__(256, 4) void k2f_sample_proj(
    const ushort* __restrict__ bevtb, const float* __restrict__ oa,
    const ushort* __restrict__ wbf, ushort* __restrict__ ybf,
    float* __restrict__ part2)
{
    __shared__ uint4 P[32 * 16];   // 8 KB

    int tid = threadIdx.x;
    int wgid = blockIdx.x;                       // 0..4095
    int lin = (wgid & 7) * 512 + (wgid >> 3);    // bijective XCD-contiguous remap
    int b = lin >> 11;
    int pix0 = (lin & 2047) << 5;                // 32 px per block

    int q8 = tid & 7;
    int pixl = tid >> 3;                         // 0..31
    int pix = pix0 + pixl;
    int p = pix >> 8;
    int q = pix & 255;

    const float* ob = oa + (size_t)b * 12 * HWC + (size_t)p * WW + q;
    unsigned pa[8]; float cw[16];
    #pragma unroll
    for (int k = 0; k < 4; k++) {
        float dx = ob[(size_t)(2*k)   * HWC];
        float dy = ob[(size_t)(2*k+1) * HWC];
        float a  = ob[(size_t)(8+k)   * HWC];
        float x  = fminf(fmaxf((float)p + dx, 0.f), (float)(WW-1));
        float yv = fminf(fmaxf((float)q + dy, 0.f), (float)(HH-1));
        float x0f = floorf(x); float y0f = floorf(yv);
        int x0 = (int)x0f; int y0 = (int)y0f;
        int x1 = min(x0 + 1, WW - 1); int y1 = min(y0 + 1, HH - 1);
        float wx = x - x0f; float wy = yv - y0f;
        pa[k*2+0] = (unsigned)(y0*WW + x0) | ((unsigned)(y0*WW + x1) << 16);
        pa[k*2+1] = (unsigned)(y1*WW + x0) | ((unsigned)(y1*WW + x1) << 16);
        cw[k*4+0] = a * (1.f - wx) * (1.f - wy);
        cw[k*4+1] = a * wx * (1.f - wy);
        cw[k*4+2] = a * (1.f - wx) * wy;
        cw[k*4+3] = a * wx * wy;
    }

    const ushort* bt = bevtb + (size_t)b * HWC * 128 + q8 * 8;

    float s[2][8];
    #pragma unroll
    for (int c = 0; c < 2; c++)
        #pragma unroll
        for (int e = 0; e < 8; e++) s[c][e] = 0.f;

    uint4 L0[8], L1[8];
    #pragma unroll
    for (int t = 0; t < 8; t++) L0[t] = *(const uint4*)(TAPPTR(t));
    #pragma unroll
    for (int t = 0; t < 8; t++) L1[t] = *(const uint4*)(TAPPTR(t + 8));
    #pragma unroll
    for (int t = 0; t < 8; t++) {
        uint4 v = L0[t];
        L0[t] = *(const uint4*)(TAPPTR(t) + 64);
        FMA8(s[0], v, cw[t]);
    }
    #pragma unroll
    for (int t = 0; t < 8; t++) {
        uint4 v = L1[t];
        L1[t] = *(const uint4*)(TAPPTR(t + 8) + 64);
        FMA8(s[0], v, cw[t + 8]);
    }
    #pragma unroll
    for (int t = 0; t < 8; t++) FMA8(s[1], L0[t], cw[t]);
    #pragma unroll
    for (int t = 0; t < 8; t++) FMA8(s[1], L1[t], cw[t + 8]);

    int sxr = pixl & 15;
    #pragma unroll
    for (int c = 0; c < 2; c++) {
        uint4 pk;
        pk.x = pkbf(s[c][0], s[c][1]);
        pk.y = pkbf(s[c][2], s[c][3]);
        pk.z = pkbf(s[c][4], s[c][5]);
        pk.w = pkbf(s[c][6], s[c][7]);
        P[pixl * 16 + ((c * 8 + q8) ^ sxr)] = pk;
    }
    __syncthreads();

    int wv = tid >> 6;
    int l = tid & 63;
    int lm = l & 15, lk = l >> 4;
    int o0 = wv << 5;

    f32x4 acc[2][2];
    #pragma unroll
    for (int ot = 0; ot < 2; ot++)
        #pragma unroll
        for (int nt = 0; nt < 2; nt++)
            acc[ot][nt] = (f32x4)(0.f);

    #pragma unroll
    for (int ot = 0; ot < 2; ot++) {
        const ushort* ap = wbf + (size_t)(o0 + ot * 16 + lm) * 128 + lk * 8;
        bf16x8 a4[4];
        #pragma unroll
        for (int kk = 0; kk < 4; kk++)
            a4[kk] = *(const bf16x8*)(ap + kk * 32);
        #pragma unroll
        for (int nt = 0; nt < 2; nt++) {
            int row = nt * 16 + lm;
            #pragma unroll
            for (int kk = 0; kk < 4; kk++) {
                bf16x8 bfr = *(const bf16x8*)&P[row * 16 + ((kk * 4 + lk) ^ lm)];
                acc[ot][nt] = __builtin_amdgcn_mfma_f32_16x16x32_bf16(
                    a4[kk], bfr, acc[ot][nt], 0, 0, 0);
            }
        }
    }

    #pragma unroll
    for (int ot = 0; ot < 2; ot++)
        #pragma unroll
        for (int nt = 0; nt < 2; nt++)
            #pragma unroll
            for (int r = 0; r < 4; r++)
                ybf[((size_t)b * DD + o0 + ot * 16 + lk * 4 + r) * HWC + pix0 + nt * 16 + lm]
                    = (ushort)f2bf(acc[ot][nt][r]);

    float sm[2][4], sq[2][4];
    #pragma unroll
    for (int ot = 0; ot < 2; ot++)
        #pragma unroll
        for (int r = 0; r < 4; r++) { sm[ot][r] = 0.f; sq[ot][r] = 0.f; }
    #pragma unroll
    for (int ot = 0; ot < 2; ot++)
        #pragma unroll
        for (int nt = 0; nt < 2; nt++)
            #pragma unroll
            for (int r = 0; r < 4; r++) {
                float v = acc[ot][nt][r];
                sm[ot][r] += v;
                sq[ot][r] = fmaf(v, v, sq[ot][r]);
            }
    #pragma unroll
    for (int m = 1; m < 16; m <<= 1) {
        #pragma unroll
        for (int ot = 0; ot < 2; ot++)
            #pragma unroll
            for (int r = 0; r < 4; r++) {
                sm[ot][r] += __shfl_xor(sm[ot][r], m);
                sq[ot][r] += __shfl_xor(sq[ot][r], m);
            }
    }
    if (lm == 0) {
        float* pw = part2 + (size_t)wgid * 256;
        #pragma unroll
        for (int ot = 0; ot < 2; ot++)
            #pragma unroll
            for (int r = 0; r < 4; r++) {
                int o = o0 + ot * 16 + lk * 4 + r;
                pw[o] = sm[ot][r];
                pw[128 + o] = sq[ot][r];
            }
    }
}

// ---------------- Kernel 3b': finalize BN from k2f block partials ----------------
__global__ __launch_bounds__(256) void k3b_finalize2(
    const float* __restrict__ part2, const float* __restrict__ gamma,
    const float* __restrict__ beta, float* __restrict__ stats)
{
    int o = blockIdx.x; int tid = threadIdx.x;
    double s = 0.0, s2 = 0.0;
    for (int w = tid; w < 4096; w += 256) {
        s  += (double)part2[(size_t)w * 256 + o];
        s2 += (double)part2[(size_t)w * 256 + 128 + o];
    }
    __shared__ double ls[256], ls2[256];
    ls[tid] = s; ls2[tid] = s2;
    __syncthreads();
    for (int off = 128; off > 0; off >>= 1) {
        if (tid < off) { ls[tid] += ls[tid+off]; ls2[tid] += ls2[tid+off]; }
        __syncthreads();
    }
    if (tid == 0) {
        double N = (double)(BB * HWC);
        double mean = ls[0] / N;
        double var = ls2[0] / N - mean * mean;
        double invs = 1.0 / sqrt(var + 1e-5);
        double g = (double)gamma[o];
        stats[o*2]   = (float)(g * invs);
        stats[o*2+1] = (float)((double)beta[o] - mean * g * invs);
    }
}

// ---------------- Kernel 4bf: BN + exact GELU, bf16 y -> f32 out ----------------
__global__ __launch_bounds__(256) void k4_bn_gelu_bf(
    const ushort* __restrict__ ybf, const float* __restrict__ stats,
    float* __restrict__ out)
{
    size_t idx8 = (size_t)blockIdx.x * 256 + threadIdx.x;   // 8-elem index
    uint4 v = ((const uint4*)ybf)[idx8];
    int o = (int)((idx8 * 8) / HWC) % DD;
    float sc = stats[o*2], sh = stats[o*2+1];
    const float is2 = 0.70710678118654752f;
    float g[8];
    g[0] = fmaf(bflo(v.x), sc, sh); g[1] = fmaf(bfhi(v.x), sc, sh);
    g[2] = fmaf(bflo(v.y), sc, sh); g[3] = fmaf(bfhi(v.y), sc, sh);
    g[4] = fmaf(bflo(v.z), sc, sh); g[5] = fmaf(bfhi(v.z), sc, sh);
    g[6] = fmaf(bflo(v.w), sc, sh); g[7] = fmaf(bfhi(v.w), sc, sh);
    float4 o0, o1;
    o0.x = 0.5f * g[0] * (1.f + erff(g[0] * is2));
    o0.y = 0.5f * g[1] * (1.f + erff(g[1] * is2));
    o0.z = 0.5f * g[2] * (1.f + erff(g[2] * is2));
    o0.w = 0.5f * g[3] * (1.f + erff(g[3] * is2));
    o1.x = 0.5f * g[4] * (1.f + erff(g[4] * is2));
    o1.y = 0.5f * g[5] * (1.f + erff(g[5] * is2));
    o1.z = 0.5f * g[6] * (1.f + erff(g[6] * is2));
    o1.w = 0.5f * g[7] * (1.f + erff(g[7] * is2));
    ((float4*)out)[idx8 * 2]     = o0;
    ((float4*)out)[idx8 * 2 + 1] = o1;
}

// ---------------- Kernel 1 (fallback): full 128-channel conv ----------------
__global__ __launch_bounds__(256) void k1_convs(
    const float* __restrict__ bev, const float* __restrict__ wp,
    const float* __restrict__ offb, const float* __restrict__ wtb,
    float* __restrict__ oa)
{
    __shared__ float rows[2][3][260];
    int tid = threadIdx.x;
    int p = blockIdx.x;
    int b = p / HH; int i = p % HH; int j = tid;
    const float* bb = bev + (size_t)b * DD * HWC;

    if (tid < 12) { int bf = tid / 6, r = tid % 6; rows[bf][r >> 1][(r & 1) ? 257 : 0] = 0.f; }
    #pragma unroll
    for (int l = 0; l < 3; l++) {
        int yy = i + l - 1;
        rows[0][l][1 + tid] = ((unsigned)yy < HH) ? bb[yy * WW + tid] : 0.f;
    }
    __syncthreads();

    float acc[12];
    #pragma unroll
    for (int o = 0; o < 12; o++) acc[o] = 0.f;

    for (int c = 0; c < 128; c++) {
        int cb = c & 1, nb = cb ^ 1;
        float rv[3];
        if (c < 127) {
            const float* pln = bb + (size_t)(c + 1) * HWC;
            #pragma unroll
            for (int l = 0; l < 3; l++) {
                int yy = i + l - 1;
                rv[l] = ((unsigned)yy < HH) ? pln[yy * WW + tid] : 0.f;
            }
        }
        float v[9];
        #pragma unroll
        for (int dy = 0; dy < 3; dy++)
            #pragma unroll
            for (int dx = 0; dx < 3; dx++)
                v[dy*3 + dx] = rows[cb][dy][tid + dx];
        const float* wc = wp + c * 108;
        #pragma unroll
        for (int o = 0; o < 12; o++) {
            float s = acc[o];
            #pragma unroll
            for (int t = 0; t < 9; t++) s = fmaf(wc[o*9 + t], v[t], s);
            acc[o] = s;
        }
        if (c < 127) {
            #pragma unroll
            for (int l = 0; l < 3; l++) rows[nb][l][1 + tid] = rv[l];
        }
        __syncthreads();
    }

    float outv[12];
    #pragma unroll
    for (int o = 0; o < 8; o++) outv[o] = acc[o] + offb[o];
    float l4[4];
    #pragma unroll
    for (int k = 0; k < 4; k++) l4[k] = acc[8+k] + wtb[k];
    float m = fmaxf(fmaxf(l4[0], l4[1]), fmaxf(l4[2], l4[3]));
    float e[4]; float se = 0.f;
    #pragma unroll
    for (int k = 0; k < 4; k++) { e[k] = expf(l4[k] - m); se += e[k]; }
    float inv = 1.f / se;
    #pragma unroll
    for (int k = 0; k < 4; k++) outv[8+k] = e[k] * inv;

    size_t basep = (size_t)b * 12 * HWC + (size_t)i * WW + j;
    #pragma unroll
    for (int o = 0; o < 12; o++) oa[basep + (size_t)o * HWC] = outv[o];
}

// ---------------- Kernel 2 fallback (NCHW) ----------------
__global__ __launch_bounds__(512, 2) void k2_sample_proj(
    const float* __restrict__ bev, const float* __restrict__ oa,
    const float* __restrict__ wt, float* __restrict__ y)
{
    __shared__ float S[2][16 * SROW2];
    int tid = threadIdx.x;
    int bidx = blockIdx.x;
    int b  = bidx >> 8;
    int p0 = ((bidx >> 4) & 15) * 16;
    int q0 = (bidx & 15) * 16;
    int pix = tid & 255;
    int gq = pix >> 4;
    int gp = pix & 15;
    int dgrp = tid >> 8;
    int swr = gp * 20 + gq;
    int wv = tid >> 6;
    int wvu = __builtin_amdgcn_readfirstlane(wv);
    int lane = tid & 63;
    int lp = lane >> 2;
    int q4 = (lane & 3) << 2;
    int soff = lp * 20 + q4;

    const float* ob = oa + (size_t)b * 12 * HWC + (size_t)(p0 + gp) * WW + (q0 + gq);
    unsigned pa[8]; float cw[16];
    #pragma unroll
    for (int k = 0; k < 4; k++) {
        float dx = ob[(size_t)(2*k)   * HWC];
        float dy = ob[(size_t)(2*k+1) * HWC];
        float a  = ob[(size_t)(8+k)   * HWC];
        float x  = fminf(fmaxf((float)(p0 + gp) + dx, 0.f), (float)(WW-1));
        float yv = fminf(fmaxf((float)(q0 + gq) + dy, 0.f), (float)(HH-1));
        float x0f = floorf(x); float y0f = floorf(yv);
        int x0 = (int)x0f; int y0 = (int)y0f;
        int x1 = min(x0 + 1, WW - 1); int y1 = min(y0 + 1, HH - 1);
        float wx = x - x0f; float wy = yv - y0f;
        pa[k*2+0] = (unsigned)(y0*WW + x0) | ((unsigned)(y0*WW + x1) << 16);
        pa[k*2+1] = (unsigned)(y1*WW + x0) | ((unsigned)(y1*WW + x1) << 16);
        cw[k*4+0] = a * (1.f - wx) * (1.f - wy);
        cw[k*4+1] = a * wx * (1.f - wy);
        cw[k*4+2] = a * (1.f - wx) * wy;
        cw[k*4+3] = a * wx * wy;
    }
    const float* bb = bev + (size_t)b * DD * HWC;
    float acc[64];
    #pragma unroll
    for (int t = 0; t < 64; t++) acc[t] = 0.f;
    #pragma unroll
    for (int dd = 0; dd < 8; dd++) {
        const float* pl = bb + (size_t)(dgrp*8 + dd) * HWC;
        float s = 0.f;
        #pragma unroll
        for (int t = 0; t < 8; t++) {
            unsigned a01 = pa[t];
            s = fmaf(cw[2*t],   pl[a01 & 0xffffu], s);
            s = fmaf(cw[2*t+1], pl[a01 >> 16], s);
        }
        S[0][(dgrp*8 + dd) * SROW2 + swr] = s;
    }
    __syncthreads();
    for (int c = 0; c < 8; c++) {
        int cur = c & 1;
        const float* Sc = &S[cur][0];
        float* Sn = &S[cur ^ 1][0];
        int d0 = c * 16;
        int d0n = d0 + 16;
        bool more = (c < 7);
        #pragma unroll
        for (int dl = 0; dl < 16; dl++) {
            if (dl < 8) {
                if (more) {
                    const float* pl = bb + (size_t)(d0n + dgrp*8 + dl) * HWC;
                    float s = 0.f;
                    #pragma unroll
                    for (int t = 0; t < 8; t++) {
                        unsigned a01 = pa[t];
                        s = fmaf(cw[2*t],   pl[a01 & 0xffffu], s);
                        s = fmaf(cw[2*t+1], pl[a01 >> 16], s);
                    }
                    Sn[(dgrp*8 + dl) * SROW2 + swr] = s;
                }
            }
            float4 sv = *(const float4*)(Sc + dl * SROW2 + soff);
            const float4* wq = (const float4*)(wt + (size_t)(d0 + dl) * 128 + wvu * 16);
            #pragma unroll
            for (int oi4 = 0; oi4 < 4; oi4++) {
                float4 w4 = wq[oi4];
                int ob4 = oi4 * 16;
                acc[ob4+ 0] = fmaf(w4.x, sv.x, acc[ob4+ 0]);
                acc[ob4+ 1] = fmaf(w4.x, sv.y, acc[ob4+ 1]);
                acc[ob4+ 2] = fmaf(w4.x, sv.z, acc[ob4+ 2]);
                acc[ob4+ 3] = fmaf(w4.x, sv.w, acc[ob4+ 3]);
                acc[ob4+ 4] = fmaf(w4.y, sv.x, acc[ob4+ 4]);
                acc[ob4+ 5] = fmaf(w4.y, sv.y, acc[ob4+ 5]);
                acc[ob4+ 6] = fmaf(w4.y, sv.z, acc[ob4+ 6]);
                acc[ob4+ 7] = fmaf(w4.y, sv.w, acc[ob4+ 7]);
                acc[ob4+ 8] = fmaf(w4.z, sv.x, acc[ob4+ 8]);
                acc[ob4+ 9] = fmaf(w4.z, sv.y, acc[ob4+ 9]);
                acc[ob4+10] = fmaf(w4.z, sv.z, acc[ob4+10]);
                acc[ob4+11] = fmaf(w4.z, sv.w, acc[ob4+11]);
                acc[ob4+12] = fmaf(w4.w, sv.x, acc[ob4+12]);
                acc[ob4+13] = fmaf(w4.w, sv.y, acc[ob4+13]);
                acc[ob4+14] = fmaf(w4.w, sv.z, acc[ob4+14]);
                acc[ob4+15] = fmaf(w4.w, sv.w, acc[ob4+15]);
            }
        }
        __syncthreads();
    }
    size_t base = (size_t)b * DD * HWC + (size_t)(p0 + lp) * WW + (q0 + q4);
    #pragma unroll
    for (int oi = 0; oi < 16; oi++) {
        int o = wv * 16 + oi;
        float4 v = make_float4(acc[oi*4+0], acc[oi*4+1], acc[oi*4+2], acc[oi*4+3]);
        *(float4*)(y + base + (size_t)o * HWC) = v;
    }
}

// ---------------- Kernel 3a/3b: BN stats (fallback tier only) ----------------
__global__ __launch_bounds__(256) void k3_partial(
    const float* __restrict__ y, double* __restrict__ part)
{
    int blk = blockIdx.x;
    int o = blk >> 2; int sub = blk & 3; int b = sub >> 1; int half = sub & 1;
    const float4* pl = (const float4*)(y + ((size_t)b * DD + o) * HWC + half * (HWC/2));
    int tid = threadIdx.x;
    double s = 0.0, s2 = 0.0;
    for (int idx = tid; idx < HWC/8; idx += 256) {
        float4 v = pl[idx];
        s  += (double)v.x + (double)v.y + (double)v.z + (double)v.w;
        s2 += (double)v.x*v.x + (double)v.y*v.y + (double)v.z*v.z + (double)v.w*v.w;
    }
    __shared__ double ls[256], ls2[256];
    ls[tid] = s; ls2[tid] = s2;
    __syncthreads();
    for (int off = 128; off > 0; off >>= 1) {
        if (tid < off) { ls[tid] += ls[tid+off]; ls2[tid] += ls2[tid+off]; }
        __syncthreads();
    }
    if (tid == 0) { part[blk*2] = ls[0]; part[blk*2+1] = ls2[0]; }
}

__global__ __launch_bounds__(128) void k3_finalize(
    const double* __restrict__ part, const float* __restrict__ gamma,
    const float* __restrict__ beta, float* __restrict__ stats)
{
    int o = threadIdx.x;
    double s = 0.0, s2 = 0.0;
    #pragma unroll
    for (int j = 0; j < 4; j++) { s += part[(o*4+j)*2]; s2 += part[(o*4+j)*2+1]; }
    double N = (double)(BB * HWC);
    double mean = s / N;
    double var = s2 / N - mean * mean;
    double invs = 1.0 / sqrt(var + 1e-5);
    double g = (double)gamma[o];
    stats[o*2]   = (float)(g * invs);
    stats[o*2+1] = (float)((double)beta[o] - mean * g * invs);
}

// ---------------- Kernel 4: BN + exact GELU, f32 in-place (fallback tier) ----------------
__global__ __launch_bounds__(256) void k4_bn_gelu(
    float* __restrict__ y, const float* __restrict__ stats)
{
    size_t idx4 = (size_t)blockIdx.x * 256 + threadIdx.x;
    float4* p = (float4*)y;
    float4 v = p[idx4];
    int o = (int)((idx4 * 4) / HWC) % DD;
    float sc = stats[o*2], sh = stats[o*2+1];
    const float inv_sqrt2 = 0.70710678118654752f;
    float g0 = fmaf(v.x, sc, sh);
    float g1 = fmaf(v.y, sc, sh);
    float g2 = fmaf(v.z, sc, sh);
    float g3 = fmaf(v.w, sc, sh);
    v.x = 0.5f * g0 * (1.f + erff(g0 * inv_sqrt2));
    v.y = 0.5f * g1 * (1.f + erff(g1 * inv_sqrt2));
    v.z = 0.5f * g2 * (1.f + erff(g2 * inv_sqrt2));
    v.w = 0.5f * g3 * (1.f + erff(g3 * inv_sqrt2));
    p[idx4] = v;
}

extern "C" void kernel_launch(void* const* d_in, const int* in_sizes, int n_in,
                              void* d_out, int out_size, void* d_ws, size_t ws_size,
                              hipStream_t stream) {
    const float* bev   = (const float*)d_in[0];
    const float* offw  = (const float*)d_in[1];
    const float* offb  = (const float*)d_in[2];
    const float* wtw   = (const float*)d_in[3];
    const float* wtb   = (const float*)d_in[4];
    const float* projw = (const float*)d_in[5];
    const float* gamma = (const float*)d_in[6];
    const float* beta  = (const float*)d_in[7];
    float* out = (float*)d_out;
    float* wsf = (float*)d_ws;

    float* oa    = wsf + OA_OFF;
    float* wtT   = wsf + WTT_OFF;
    float* wp    = wsf + WP_OFF;
    float* stats = wsf + STATS_OFF;
    double* part = (double*)(wsf + PART_OFF);
    ushort* bevtb = (ushort*)(wsf + BEVT_OFF);
    ushort* ybf   = (ushort*)(wsf + YBF_OFF);
    ushort* wbf  = (ushort*)(wsf + WBF_OFF);
    ushort* wcb  = (ushort*)(wsf + WCB_OFF);
    float* part2 = wsf + PART2_OFF;

    bool full3 = ws_size >= WS_NEED_FULL3;

    if (full3) {
        hipLaunchKernelGGL(k0bc, dim3(72), dim3(256), 0, stream,
                           projw, offw, wtw, wbf, wcb);
        hipLaunchKernelGGL(k2t_bf, dim3(2048), dim3(256), 0, stream, bev, bevtb);
        hipLaunchKernelGGL(k1m_conv_mfma, dim3(512), dim3(256), 0, stream,
                           bevtb, wcb, offb, wtb, oa);
        hipLaunchKernelGGL(k2f_sample_proj, dim3(4096), dim3(256), 0, stream,
                           bevtb, oa, wbf, ybf, part2);
        hipLaunchKernelGGL(k3b_finalize2, dim3(128), dim3(256), 0, stream,
                           part2, gamma, beta, stats);
        hipLaunchKernelGGL(k4_bn_gelu_bf, dim3((BB*DD*HWC)/2048), dim3(256), 0, stream,
                           ybf, stats, out);
    } else {
        hipLaunchKernelGGL(k0_prep, dim3(64), dim3(256), 0, stream,
                           projw, offw, wtw, wtT, wp);
        hipLaunchKernelGGL(k1_convs, dim3(BB*HH), dim3(256), 0, stream,
                           bev, wp, offb, wtb, oa);
        hipLaunchKernelGGL(k2_sample_proj, dim3(BB*256), dim3(512), 0, stream,
                           bev, oa, wtT, out);
        hipLaunchKernelGGL(k3_partial, dim3(512), dim3(256), 0, stream, out, part);
        hipLaunchKernelGGL(k3_finalize, dim3(1), dim3(128), 0, stream,
                           part, gamma, beta, stats);
        hipLaunchKernelGGL(k4_bn_gelu, dim3((BB*DD*HWC)/1024), dim3(256), 0, stream,
                           out, stats);
    }
}

// Round 17
// 136.553 us; speedup vs baseline: 1.1760x; 1.0253x over previous
//
#include <hip/hip_runtime.h>
#include <math.h>

#define BB 2
#define DD 128
#define HH 256
#define WW 256
#define KK 4
#define HWC (HH*WW)
#define SROW2 320   // d-slice stride in S (fused fallback kernels)

typedef unsigned int u32;
typedef unsigned short ushort;
typedef __attribute__((ext_vector_type(8))) short bf16x8;
typedef __attribute__((ext_vector_type(4))) float f32x4;

// ws float layout
#define OA_OFF    0
#define WTT_OFF   1572864
#define WP_OFF    1589248
#define STATS_OFF 1603072
#define PART_OFF  1603392
#define BEVT_OFF  1605440       // full3: bevtb bf16 (16.8M ushort = 8.39M float-slots)
#define YBF_OFF   9994048       // full3: pre-BN y bf16 (16.8M ushort) - 2nd half of BEVT region
#define PACC_OFF  18382656
#define PART2_OFF PACC_OFF      // full3: k2f block stats [wgid][256] f32
#define WBF_OFF   26771264      // proj W bf16
#define WCB_OFF   26779456      // conv W bf16 padded: 9*16*128 ushort
#define WS_NEED_BEVT  ((size_t)PACC_OFF * 4)
#define WS_NEED_FULL3 ((size_t)(WCB_OFF + 9216) * 4)

__device__ __forceinline__ u32 f2bf(float x) {
    u32 u = __builtin_bit_cast(u32, x);
    return (u + 0x7fffu + ((u >> 16) & 1u)) >> 16;
}
__device__ __forceinline__ u32 pkbf(float a, float b) {
    return f2bf(a) | (f2bf(b) << 16);
}
__device__ __forceinline__ float bflo(u32 d) { return __builtin_bit_cast(float, d << 16); }
__device__ __forceinline__ float bfhi(u32 d) { return __builtin_bit_cast(float, d & 0xffff0000u); }

// ---------------- Kernel 0: weight prep (fallback tier only) ----------------
__global__ __launch_bounds__(256) void k0_prep(
    const float* __restrict__ projw, const float* __restrict__ offw,
    const float* __restrict__ wtw, float* __restrict__ wtT, float* __restrict__ wp)
{
    int idx = blockIdx.x * 256 + threadIdx.x;
    if (idx < 16384) {
        int d = idx >> 7, o = idx & 127;
        wtT[d * 128 + o] = projw[o * 128 + d];
    }
    if (idx < 13824) {
        int c = idx / 108; int r = idx % 108; int o = r / 9; int t = r % 9;
        wp[idx] = (o < 8) ? offw[(o*128 + c)*9 + t] : wtw[((o-8)*128 + c)*9 + t];
    }
}

// ---------------- Kernel 0bc: bf16 weight prep (proj + conv) ----------------
__global__ __launch_bounds__(256) void k0bc(
    const float* __restrict__ projw, const float* __restrict__ offw,
    const float* __restrict__ wtw, ushort* __restrict__ wbf,
    ushort* __restrict__ wcb)
{
    int idx = blockIdx.x * 256 + threadIdx.x;
    if (idx < 16384) wbf[idx] = (ushort)f2bf(projw[idx]);
    if (idx < 18432) {
        int tap = idx >> 11;
        int rem = idx & 2047;
        int oo = rem >> 7, c = rem & 127;
        float v = 0.f;
        if (oo < 8)       v = offw[(oo*128 + c)*9 + tap];
        else if (oo < 12) v = wtw[((oo-8)*128 + c)*9 + tap];
        wcb[idx] = (ushort)f2bf(v);
    }
}

// ---------------- Kernel Tb: NCHW f32 -> NHWC bf16 ----------------
__global__ __launch_bounds__(256) void k2t_bf(
    const float* __restrict__ bev, ushort* __restrict__ bevtb)
{
    __shared__ float T[64 * 128];
    int tid = threadIdx.x;
    int bidx = blockIdx.x;
    int b = bidx >> 10;
    int rem = bidx & 1023;
    int yrow = rem >> 2;
    int x0 = (rem & 3) << 6;

    const float* src = bev + ((size_t)b * DD) * HWC + (size_t)yrow * WW + x0;
    #pragma unroll 4
    for (int k = 0; k < 32; k++) {
        int flat = k * 256 + tid;
        int d = flat >> 6, xl = flat & 63;
        float v = src[(size_t)d * HWC + xl];
        T[xl * 128 + (((d >> 2) ^ (xl & 31)) << 2) + (d & 3)] = v;
    }
    __syncthreads();
    ushort* dst = bevtb + (((size_t)b * HH + yrow) * WW + x0) * 128;
    #pragma unroll 4
    for (int k = 0; k < 8; k++) {
        int flat = k * 256 + tid;
        int d4 = flat & 31, xl = (flat >> 5) & 63;
        float4 v = *(const float4*)&T[xl * 128 + ((d4 ^ (xl & 31)) << 2)];
        uint2 pk;
        pk.x = pkbf(v.x, v.y);
        pk.y = pkbf(v.z, v.w);
        *(uint2*)(dst + (size_t)xl * 128 + (d4 << 2)) = pk;
    }
}

// ---------------- Kernel 1m: 3x3 convs as implicit-GEMM MFMA, ROLLING band + async stage ----------------
// R16: rolling band cut k1m ~50->~35.  R17: async-STAGE split (guide G15/T14) - the
// per-row staging was {barrier, global-load+ds_write, barrier} putting ~500cy load
// latency on the critical path.  Now STAGE_LOAD (5 predicated uint4 -> regs) issues
// BEFORE the row's 36 MFMAs (latency hidden under compute); after the barrier only
// the ds_write remains.  Rolling-slot invariants unchanged (loads are global-only).
__global__ __launch_bounds__(256) void k1m_conv_mfma(
    const ushort* __restrict__ bevtb, const ushort* __restrict__ wcb,
    const float* __restrict__ offb, const float* __restrict__ wtb,
    float* __restrict__ oa)
{
    __shared__ uint4 lds4[3 * 1056];   // 3 row-buffers x 66 px x 16 slots x 16B = 50688 B

    int tid = threadIdx.x;
    int wv = tid >> 6;
    int l = tid & 63;
    int lm = l & 15, lk = l >> 4;
    int wgid = blockIdx.x;                      // 0..511
    int lin = (wgid & 7) * 64 + (wgid >> 3);    // bijective XCD-contiguous remap
    int b = lin >> 8;
    int band = (lin >> 2) & 63;
    int jt = lin & 3;
    int i0 = band * 4;
    int x0 = jt * 64;

    const ushort* bb = bevtb + (size_t)b * HWC * 128;

    // direct stage (prologue only): load + ds_write
    #define STAGE_ROW(a, s) do {                                                  \
        int _a = (a); int _s = (s);                                               \
        bool rok = ((unsigned)_a < HH);                                           \
        for (int z = tid; z < 1056; z += 256) {                                   \
            int pl = z >> 4; int qq = z & 15;                                     \
            int x = x0 - 1 + pl;                                                  \
            bool ok = rok && ((unsigned)x < WW);                                  \
            uint4 v = make_uint4(0u, 0u, 0u, 0u);                                 \
            if (ok) v = *(const uint4*)(bb + ((size_t)(_a * WW + x) << 7) + qq * 8); \
            lds4[_s * 1056 + pl * 16 + (qq ^ (pl & 15))] = v;                     \
        }                                                                         \
    } while (0)

    // prologue: rows i0-1, i0, i0+1  (slot(a) = (a+1) % 3)
    STAGE_ROW(i0 - 1, i0 % 3);
    STAGE_ROW(i0,     (i0 + 1) % 3);
    STAGE_ROW(i0 + 1, (i0 + 2) % 3);
    __syncthreads();

    #pragma unroll
    for (int r = 0; r < 4; r++) {
        int i = i0 + r;
        int s0 = i % 3;           // row i-1
        int s1 = (i + 1) % 3;     // row i
        int s2 = (i + 2) % 3;     // row i+1
        int slots[3] = { s0, s1, s2 };

        // ---- async-stage: ISSUE loads for row i+2 now (latency hides under MFMAs) ----
        uint4 rv[5];
        if (r < 3) {
            int a = i + 2;
            bool rok = ((unsigned)a < HH);
            #pragma unroll
            for (int u = 0; u < 5; u++) {
                int z = tid + u * 256;
                uint4 v = make_uint4(0u, 0u, 0u, 0u);
                if (z < 1056) {
                    int pl = z >> 4; int qq = z & 15;
                    int x = x0 - 1 + pl;
                    if (rok && ((unsigned)x < WW))
                        v = *(const uint4*)(bb + ((size_t)(a * WW + x) << 7) + qq * 8);
                }
                rv[u] = v;
            }
        }

        f32x4 acc = (f32x4)(0.f);
        #pragma unroll
        for (int dy = 0; dy < 3; dy++) {
            #pragma unroll
            for (int dx = 0; dx < 3; dx++) {
                int pl = wv * 16 + lm + dx;
                const uint4* bp = &lds4[slots[dy] * 1056 + pl * 16];
                int sx = pl & 15;
                const ushort* ap = wcb + (size_t)((dy*3 + dx) * 16 + lm) * 128 + lk * 8;
                #pragma unroll
                for (int kk = 0; kk < 4; kk++) {
                    bf16x8 bfr = *(const bf16x8*)&bp[(kk*4 + lk) ^ sx];
                    bf16x8 afr = *(const bf16x8*)(ap + kk * 32);
                    acc = __builtin_amdgcn_mfma_f32_16x16x32_bf16(afr, bfr, acc, 0, 0, 0);
                }
            }
        }

        float v[4];
        #pragma unroll
        for (int t = 0; t < 4; t++) v[t] = acc[t];

        int j = x0 + wv * 16 + lm;
        if (lk < 2) {
            #pragma unroll
            for (int t = 0; t < 4; t++) v[t] += offb[lk*4 + t];   // OFFSET_SCALE = 1.0
        } else if (lk == 2) {
            float l4[4];
            #pragma unroll
            for (int t = 0; t < 4; t++) l4[t] = v[t] + wtb[t];
            float m = fmaxf(fmaxf(l4[0], l4[1]), fmaxf(l4[2], l4[3]));
            float e[4]; float se = 0.f;
            #pragma unroll
            for (int t = 0; t < 4; t++) { e[t] = expf(l4[t] - m); se += e[t]; }
            float inv = 1.f / se;
            #pragma unroll
            for (int t = 0; t < 4; t++) v[t] = e[t] * inv;
        }
        if (lk < 3) {
            size_t basep = (size_t)b * 12 * HWC + (size_t)i * WW + j;
            #pragma unroll
            for (int t = 0; t < 4; t++)
                oa[basep + (size_t)(lk*4 + t) * HWC] = v[t];
        }

        __syncthreads();               // all reads of the 3 rows complete
        if (r < 3) {
            // ---- write-late: pure ds_write of the prefetched row ----
            int s = i % 3;             // retiring slot (row i-1)
            #pragma unroll
            for (int u = 0; u < 5; u++) {
                int z = tid + u * 256;
                if (z < 1056) {
                    int pl = z >> 4; int qq = z & 15;
                    lds4[s * 1056 + pl * 16 + (qq ^ (pl & 15))] = rv[u];
                }
            }
            __syncthreads();
        }
    }
    #undef STAGE_ROW
}

// ---------------- Kernel 2f: FUSED sample + 1x1 MFMA proj + BN stats ----------------
#define TAPPTR(t) (bt + ((size_t)((((t) & 1) ? (pa[(t) >> 1] >> 16) : (pa[(t) >> 1] & 0xffffu))) << 7))
#define FMA8(S, V, W) do { \
    S[0] = fmaf(W, bflo((V).x), S[0]); S[1] = fmaf(W, bfhi((V).x), S[1]); \
    S[2] = fmaf(W, bflo((V).y), S[2]); S[3] = fmaf(W, bfhi((V).y), S[3]); \
    S[4] = fmaf(W, bflo((V).z), S[4]); S[5] = fmaf(W, bfhi((V).z), S[5]); \
    S[6] = fmaf(W, bflo((V).w), S[6]); S[7] = fmaf(W, bfhi((V).w), S[7]); \
} while (0)

__global__ __launch_bounds__(256, 4) void k2f_sample_proj(
    const ushort* __restrict__ bevtb, const float* __restrict__ oa,
    const ushort* __restrict__ wbf, ushort* __restrict__ ybf,
    float* __restrict__ part2)
{
    __shared__ uint4 P[32 * 16];   // 8 KB

    int tid = threadIdx.x;
    int wgid = blockIdx.x;                       // 0..4095
    int lin = (wgid & 7) * 512 + (wgid >> 3);    // bijective XCD-contiguous remap
    int b = lin >> 11;
    int pix0 = (lin & 2047) << 5;                // 32 px per block

    int q8 = tid & 7;
    int pixl = tid >> 3;                         // 0..31
    int pix = pix0 + pixl;
    int p = pix >> 8;
    int q = pix & 255;

    const float* ob = oa + (size_t)b * 12 * HWC + (size_t)p * WW + q;
    unsigned pa[8]; float cw[16];
    #pragma unroll
    for (int k = 0; k < 4; k++) {
        float dx = ob[(size_t)(2*k)   * HWC];
        float dy = ob[(size_t)(2*k+1) * HWC];
        float a  = ob[(size_t)(8+k)   * HWC];
        float x  = fminf(fmaxf((float)p + dx, 0.f), (float)(WW-1));
        float yv = fminf(fmaxf((float)q + dy, 0.f), (float)(HH-1));
        float x0f = floorf(x); float y0f = floorf(yv);
        int x0 = (int)x0f; int y0 = (int)y0f;
        int x1 = min(x0 + 1, WW - 1); int y1 = min(y0 + 1, HH - 1);
        float wx = x - x0f; float wy = yv - y0f;
        pa[k*2+0] = (unsigned)(y0*WW + x0) | ((unsigned)(y0*WW + x1) << 16);
        pa[k*2+1] = (unsigned)(y1*WW + x0) | ((unsigned)(y1*WW + x1) << 16);
        cw[k*4+0] = a * (1.f - wx) * (1.f - wy);
        cw[k*4+1] = a * wx * (1.f - wy);
        cw[k*4+2] = a * (1.f - wx) * wy;
        cw[k*4+3] = a * wx * wy;
    }

    const ushort* bt = bevtb + (size_t)b * HWC * 128 + q8 * 8;

    float s[2][8];
    #pragma unroll
    for (int c = 0; c < 2; c++)
        #pragma unroll
        for (int e = 0; e < 8; e++) s[c][e] = 0.f;

    uint4 L0[8], L1[8];
    #pragma unroll
    for (int t = 0; t < 8; t++) L0[t] = *(const uint4*)(TAPPTR(t));
    #pragma unroll
    for (int t = 0; t < 8; t++) L1[t] = *(const uint4*)(TAPPTR(t + 8));
    #pragma unroll
    for (int t = 0; t < 8; t++) {
        uint4 v = L0[t];
        L0[t] = *(const uint4*)(TAPPTR(t) + 64);
        FMA8(s[0], v, cw[t]);
    }
    #pragma unroll
    for (int t = 0; t < 8; t++) {
        uint4 v = L1[t];
        L1[t] = *(const uint4*)(TAPPTR(t + 8) + 64);
        FMA8(s[0], v, cw[t + 8]);
    }
    #pragma unroll
    for (int t = 0; t < 8; t++) FMA8(s[1], L0[t], cw[t]);
    #pragma unroll
    for (int t = 0; t < 8; t++) FMA8(s[1], L1[t], cw[t + 8]);

    int sxr = pixl & 15;
    #pragma unroll
    for (int c = 0; c < 2; c++) {
        uint4 pk;
        pk.x = pkbf(s[c][0], s[c][1]);
        pk.y = pkbf(s[c][2], s[c][3]);
        pk.z = pkbf(s[c][4], s[c][5]);
        pk.w = pkbf(s[c][6], s[c][7]);
        P[pixl * 16 + ((c * 8 + q8) ^ sxr)] = pk;
    }
    __syncthreads();

    int wv = tid >> 6;
    int l = tid & 63;
    int lm = l & 15, lk = l >> 4;
    int o0 = wv << 5;

    f32x4 acc[2][2];
    #pragma unroll
    for (int ot = 0; ot < 2; ot++)
        #pragma unroll
        for (int nt = 0; nt < 2; nt++)
            acc[ot][nt] = (f32x4)(0.f);

    #pragma unroll
    for (int ot = 0; ot < 2; ot++) {
        const ushort* ap = wbf + (size_t)(o0 + ot * 16 + lm) * 128 + lk * 8;
        bf16x8 a4[4];
        #pragma unroll
        for (int kk = 0; kk < 4; kk++)
            a4[kk] = *(const bf16x8*)(ap + kk * 32);
        #pragma unroll
        for (int nt = 0; nt < 2; nt++) {
            int row = nt * 16 + lm;
            #pragma unroll
            for (int kk = 0; kk < 4; kk++) {
                bf16x8 bfr = *(const bf16x8*)&P[row * 16 + ((kk * 4 + lk) ^ lm)];
                acc[ot][nt] = __builtin_amdgcn_mfma_f32_16x16x32_bf16(
                    a4[kk], bfr, acc[ot][nt], 0, 0, 0);
            }
        }
    }

    #pragma unroll
    for (int ot = 0; ot < 2; ot++)
        #pragma unroll
        for (int nt = 0; nt < 2; nt++)
            #pragma unroll
            for (int r = 0; r < 4; r++)
                ybf[((size_t)b * DD + o0 + ot * 16 + lk * 4 + r) * HWC + pix0 + nt * 16 + lm]
                    = (ushort)f2bf(acc[ot][nt][r]);

    float sm[2][4], sq[2][4];
    #pragma unroll
    for (int ot = 0; ot < 2; ot++)
        #pragma unroll
        for (int r = 0; r < 4; r++) { sm[ot][r] = 0.f; sq[ot][r] = 0.f; }
    #pragma unroll
    for (int ot = 0; ot < 2; ot++)
        #pragma unroll
        for (int nt = 0; nt < 2; nt++)
            #pragma unroll
            for (int r = 0; r < 4; r++) {
                float v = acc[ot][nt][r];
                sm[ot][r] += v;
                sq[ot][r] = fmaf(v, v, sq[ot][r]);
            }
    #pragma unroll
    for (int m = 1; m < 16; m <<= 1) {
        #pragma unroll
        for (int ot = 0; ot < 2; ot++)
            #pragma unroll
            for (int r = 0; r < 4; r++) {
                sm[ot][r] += __shfl_xor(sm[ot][r], m);
                sq[ot][r] += __shfl_xor(sq[ot][r], m);
            }
    }
    if (lm == 0) {
        float* pw = part2 + (size_t)wgid * 256;
        #pragma unroll
        for (int ot = 0; ot < 2; ot++)
            #pragma unroll
            for (int r = 0; r < 4; r++) {
                int o = o0 + ot * 16 + lk * 4 + r;
                pw[o] = sm[ot][r];
                pw[128 + o] = sq[ot][r];
            }
    }
}

// ---------------- Kernel 3b': finalize BN from k2f block partials ----------------
__global__ __launch_bounds__(256) void k3b_finalize2(
    const float* __restrict__ part2, const float* __restrict__ gamma,
    const float* __restrict__ beta, float* __restrict__ stats)
{
    int o = blockIdx.x; int tid = threadIdx.x;
    double s = 0.0, s2 = 0.0;
    for (int w = tid; w < 4096; w += 256) {
        s  += (double)part2[(size_t)w * 256 + o];
        s2 += (double)part2[(size_t)w * 256 + 128 + o];
    }
    __shared__ double ls[256], ls2[256];
    ls[tid] = s; ls2[tid] = s2;
    __syncthreads();
    for (int off = 128; off > 0; off >>= 1) {
        if (tid < off) { ls[tid] += ls[tid+off]; ls2[tid] += ls2[tid+off]; }
        __syncthreads();
    }
    if (tid == 0) {
        double N = (double)(BB * HWC);
        double mean = ls[0] / N;
        double var = ls2[0] / N - mean * mean;
        double invs = 1.0 / sqrt(var + 1e-5);
        double g = (double)gamma[o];
        stats[o*2]   = (float)(g * invs);
        stats[o*2+1] = (float)((double)beta[o] - mean * g * invs);
    }
}

// ---------------- Kernel 4bf: BN + exact GELU, bf16 y -> f32 out ----------------
__global__ __launch_bounds__(256) void k4_bn_gelu_bf(
    const ushort* __restrict__ ybf, const float* __restrict__ stats,
    float* __restrict__ out)
{
    size_t idx8 = (size_t)blockIdx.x * 256 + threadIdx.x;   // 8-elem index
    uint4 v = ((const uint4*)ybf)[idx8];
    int o = (int)((idx8 * 8) / HWC) % DD;
    float sc = stats[o*2], sh = stats[o*2+1];
    const float is2 = 0.70710678118654752f;
    float g[8];
    g[0] = fmaf(bflo(v.x), sc, sh); g[1] = fmaf(bfhi(v.x), sc, sh);
    g[2] = fmaf(bflo(v.y), sc, sh); g[3] = fmaf(bfhi(v.y), sc, sh);
    g[4] = fmaf(bflo(v.z), sc, sh); g[5] = fmaf(bfhi(v.z), sc, sh);
    g[6] = fmaf(bflo(v.w), sc, sh); g[7] = fmaf(bfhi(v.w), sc, sh);
    float4 o0, o1;
    o0.x = 0.5f * g[0] * (1.f + erff(g[0] * is2));
    o0.y = 0.5f * g[1] * (1.f + erff(g[1] * is2));
    o0.z = 0.5f * g[2] * (1.f + erff(g[2] * is2));
    o0.w = 0.5f * g[3] * (1.f + erff(g[3] * is2));
    o1.x = 0.5f * g[4] * (1.f + erff(g[4] * is2));
    o1.y = 0.5f * g[5] * (1.f + erff(g[5] * is2));
    o1.z = 0.5f * g[6] * (1.f + erff(g[6] * is2));
    o1.w = 0.5f * g[7] * (1.f + erff(g[7] * is2));
    ((float4*)out)[idx8 * 2]     = o0;
    ((float4*)out)[idx8 * 2 + 1] = o1;
}

// ---------------- Kernel 1 (fallback): full 128-channel conv ----------------
__global__ __launch_bounds__(256) void k1_convs(
    const float* __restrict__ bev, const float* __restrict__ wp,
    const float* __restrict__ offb, const float* __restrict__ wtb,
    float* __restrict__ oa)
{
    __shared__ float rows[2][3][260];
    int tid = threadIdx.x;
    int p = blockIdx.x;
    int b = p / HH; int i = p % HH; int j = tid;
    const float* bb = bev + (size_t)b * DD * HWC;

    if (tid < 12) { int bf = tid / 6, r = tid % 6; rows[bf][r >> 1][(r & 1) ? 257 : 0] = 0.f; }
    #pragma unroll
    for (int l = 0; l < 3; l++) {
        int yy = i + l - 1;
        rows[0][l][1 + tid] = ((unsigned)yy < HH) ? bb[yy * WW + tid] : 0.f;
    }
    __syncthreads();

    float acc[12];
    #pragma unroll
    for (int o = 0; o < 12; o++) acc[o] = 0.f;

    for (int c = 0; c < 128; c++) {
        int cb = c & 1, nb = cb ^ 1;
        float rv[3];
        if (c < 127) {
            const float* pln = bb + (size_t)(c + 1) * HWC;
            #pragma unroll
            for (int l = 0; l < 3; l++) {
                int yy = i + l - 1;
                rv[l] = ((unsigned)yy < HH) ? pln[yy * WW + tid] : 0.f;
            }
        }
        float v[9];
        #pragma unroll
        for (int dy = 0; dy < 3; dy++)
            #pragma unroll
            for (int dx = 0; dx < 3; dx++)
                v[dy*3 + dx] = rows[cb][dy][tid + dx];
        const float* wc = wp + c * 108;
        #pragma unroll
        for (int o = 0; o < 12; o++) {
            float s = acc[o];
            #pragma unroll
            for (int t = 0; t < 9; t++) s = fmaf(wc[o*9 + t], v[t], s);
            acc[o] = s;
        }
        if (c < 127) {
            #pragma unroll
            for (int l = 0; l < 3; l++) rows[nb][l][1 + tid] = rv[l];
        }
        __syncthreads();
    }

    float outv[12];
    #pragma unroll
    for (int o = 0; o < 8; o++) outv[o] = acc[o] + offb[o];
    float l4[4];
    #pragma unroll
    for (int k = 0; k < 4; k++) l4[k] = acc[8+k] + wtb[k];
    float m = fmaxf(fmaxf(l4[0], l4[1]), fmaxf(l4[2], l4[3]));
    float e[4]; float se = 0.f;
    #pragma unroll
    for (int k = 0; k < 4; k++) { e[k] = expf(l4[k] - m); se += e[k]; }
    float inv = 1.f / se;
    #pragma unroll
    for (int k = 0; k < 4; k++) outv[8+k] = e[k] * inv;

    size_t basep = (size_t)b * 12 * HWC + (size_t)i * WW + j;
    #pragma unroll
    for (int o = 0; o < 12; o++) oa[basep + (size_t)o * HWC] = outv[o];
}

// ---------------- Kernel 2 fallback (NCHW) ----------------
__global__ __launch_bounds__(512, 2) void k2_sample_proj(
    const float* __restrict__ bev, const float* __restrict__ oa,
    const float* __restrict__ wt, float* __restrict__ y)
{
    __shared__ float S[2][16 * SROW2];
    int tid = threadIdx.x;
    int bidx = blockIdx.x;
    int b  = bidx >> 8;
    int p0 = ((bidx >> 4) & 15) * 16;
    int q0 = (bidx & 15) * 16;
    int pix = tid & 255;
    int gq = pix >> 4;
    int gp = pix & 15;
    int dgrp = tid >> 8;
    int swr = gp * 20 + gq;
    int wv = tid >> 6;
    int wvu = __builtin_amdgcn_readfirstlane(wv);
    int lane = tid & 63;
    int lp = lane >> 2;
    int q4 = (lane & 3) << 2;
    int soff = lp * 20 + q4;

    const float* ob = oa + (size_t)b * 12 * HWC + (size_t)(p0 + gp) * WW + (q0 + gq);
    unsigned pa[8]; float cw[16];
    #pragma unroll
    for (int k = 0; k < 4; k++) {
        float dx = ob[(size_t)(2*k)   * HWC];
        float dy = ob[(size_t)(2*k+1) * HWC];
        float a  = ob[(size_t)(8+k)   * HWC];
        float x  = fminf(fmaxf((float)(p0 + gp) + dx, 0.f), (float)(WW-1));
        float yv = fminf(fmaxf((float)(q0 + gq) + dy, 0.f), (float)(HH-1));
        float x0f = floorf(x); float y0f = floorf(yv);
        int x0 = (int)x0f; int y0 = (int)y0f;
        int x1 = min(x0 + 1, WW - 1); int y1 = min(y0 + 1, HH - 1);
        float wx = x - x0f; float wy = yv - y0f;
        pa[k*2+0] = (unsigned)(y0*WW + x0) | ((unsigned)(y0*WW + x1) << 16);
        pa[k*2+1] = (unsigned)(y1*WW + x0) | ((unsigned)(y1*WW + x1) << 16);
        cw[k*4+0] = a * (1.f - wx) * (1.f - wy);
        cw[k*4+1] = a * wx * (1.f - wy);
        cw[k*4+2] = a * (1.f - wx) * wy;
        cw[k*4+3] = a * wx * wy;
    }
    const float* bb = bev + (size_t)b * DD * HWC;
    float acc[64];
    #pragma unroll
    for (int t = 0; t < 64; t++) acc[t] = 0.f;
    #pragma unroll
    for (int dd = 0; dd < 8; dd++) {
        const float* pl = bb + (size_t)(dgrp*8 + dd) * HWC;
        float s = 0.f;
        #pragma unroll
        for (int t = 0; t < 8; t++) {
            unsigned a01 = pa[t];
            s = fmaf(cw[2*t],   pl[a01 & 0xffffu], s);
            s = fmaf(cw[2*t+1], pl[a01 >> 16], s);
        }
        S[0][(dgrp*8 + dd) * SROW2 + swr] = s;
    }
    __syncthreads();
    for (int c = 0; c < 8; c++) {
        int cur = c & 1;
        const float* Sc = &S[cur][0];
        float* Sn = &S[cur ^ 1][0];
        int d0 = c * 16;
        int d0n = d0 + 16;
        bool more = (c < 7);
        #pragma unroll
        for (int dl = 0; dl < 16; dl++) {
            if (dl < 8) {
                if (more) {
                    const float* pl = bb + (size_t)(d0n + dgrp*8 + dl) * HWC;
                    float s = 0.f;
                    #pragma unroll
                    for (int t = 0; t < 8; t++) {
                        unsigned a01 = pa[t];
                        s = fmaf(cw[2*t],   pl[a01 & 0xffffu], s);
                        s = fmaf(cw[2*t+1], pl[a01 >> 16], s);
                    }
                    Sn[(dgrp*8 + dl) * SROW2 + swr] = s;
                }
            }
            float4 sv = *(const float4*)(Sc + dl * SROW2 + soff);
            const float4* wq = (const float4*)(wt + (size_t)(d0 + dl) * 128 + wvu * 16);
            #pragma unroll
            for (int oi4 = 0; oi4 < 4; oi4++) {
                float4 w4 = wq[oi4];
                int ob4 = oi4 * 16;
                acc[ob4+ 0] = fmaf(w4.x, sv.x, acc[ob4+ 0]);
                acc[ob4+ 1] = fmaf(w4.x, sv.y, acc[ob4+ 1]);
                acc[ob4+ 2] = fmaf(w4.x, sv.z, acc[ob4+ 2]);
                acc[ob4+ 3] = fmaf(w4.x, sv.w, acc[ob4+ 3]);
                acc[ob4+ 4] = fmaf(w4.y, sv.x, acc[ob4+ 4]);
                acc[ob4+ 5] = fmaf(w4.y, sv.y, acc[ob4+ 5]);
                acc[ob4+ 6] = fmaf(w4.y, sv.z, acc[ob4+ 6]);
                acc[ob4+ 7] = fmaf(w4.y, sv.w, acc[ob4+ 7]);
                acc[ob4+ 8] = fmaf(w4.z, sv.x, acc[ob4+ 8]);
                acc[ob4+ 9] = fmaf(w4.z, sv.y, acc[ob4+ 9]);
                acc[ob4+10] = fmaf(w4.z, sv.z, acc[ob4+10]);
                acc[ob4+11] = fmaf(w4.z, sv.w, acc[ob4+11]);
                acc[ob4+12] = fmaf(w4.w, sv.x, acc[ob4+12]);
                acc[ob4+13] = fmaf(w4.w, sv.y, acc[ob4+13]);
                acc[ob4+14] = fmaf(w4.w, sv.z, acc[ob4+14]);
                acc[ob4+15] = fmaf(w4.w, sv.w, acc[ob4+15]);
            }
        }
        __syncthreads();
    }
    size_t base = (size_t)b * DD * HWC + (size_t)(p0 + lp) * WW + (q0 + q4);
    #pragma unroll
    for (int oi = 0; oi < 16; oi++) {
        int o = wv * 16 + oi;
        float4 v = make_float4(acc[oi*4+0], acc[oi*4+1], acc[oi*4+2], acc[oi*4+3]);
        *(float4*)(y + base + (size_t)o * HWC) = v;
    }
}

// ---------------- Kernel 3a/3b: BN stats (fallback tier only) ----------------
__global__ __launch_bounds__(256) void k3_partial(
    const float* __restrict__ y, double* __restrict__ part)
{
    int blk = blockIdx.x;
    int o = blk >> 2; int sub = blk & 3; int b = sub >> 1; int half = sub & 1;
    const float4* pl = (const float4*)(y + ((size_t)b * DD + o) * HWC + half * (HWC/2));
    int tid = threadIdx.x;
    double s = 0.0, s2 = 0.0;
    for (int idx = tid; idx < HWC/8; idx += 256) {
        float4 v = pl[idx];
        s  += (double)v.x + (double)v.y + (double)v.z + (double)v.w;
        s2 += (double)v.x*v.x + (double)v.y*v.y + (double)v.z*v.z + (double)v.w*v.w;
    }
    __shared__ double ls[256], ls2[256];
    ls[tid] = s; ls2[tid] = s2;
    __syncthreads();
    for (int off = 128; off > 0; off >>= 1) {
        if (tid < off) { ls[tid] += ls[tid+off]; ls2[tid] += ls2[tid+off]; }
        __syncthreads();
    }
    if (tid == 0) { part[blk*2] = ls[0]; part[blk*2+1] = ls2[0]; }
}

__global__ __launch_bounds__(128) void k3_finalize(
    const double* __restrict__ part, const float* __restrict__ gamma,
    const float* __restrict__ beta, float* __restrict__ stats)
{
    int o = threadIdx.x;
    double s = 0.0, s2 = 0.0;
    #pragma unroll
    for (int j = 0; j < 4; j++) { s += part[(o*4+j)*2]; s2 += part[(o*4+j)*2+1]; }
    double N = (double)(BB * HWC);
    double mean = s / N;
    double var = s2 / N - mean * mean;
    double invs = 1.0 / sqrt(var + 1e-5);
    double g = (double)gamma[o];
    stats[o*2]   = (float)(g * invs);
    stats[o*2+1] = (float)((double)beta[o] - mean * g * invs);
}

// ---------------- Kernel 4: BN + exact GELU, f32 in-place (fallback tier) ----------------
__global__ __launch_bounds__(256) void k4_bn_gelu(
    float* __restrict__ y, const float* __restrict__ stats)
{
    size_t idx4 = (size_t)blockIdx.x * 256 + threadIdx.x;
    float4* p = (float4*)y;
    float4 v = p[idx4];
    int o = (int)((idx4 * 4) / HWC) % DD;
    float sc = stats[o*2], sh = stats[o*2+1];
    const float inv_sqrt2 = 0.70710678118654752f;
    float g0 = fmaf(v.x, sc, sh);
    float g1 = fmaf(v.y, sc, sh);
    float g2 = fmaf(v.z, sc, sh);
    float g3 = fmaf(v.w, sc, sh);
    v.x = 0.5f * g0 * (1.f + erff(g0 * inv_sqrt2));
    v.y = 0.5f * g1 * (1.f + erff(g1 * inv_sqrt2));
    v.z = 0.5f * g2 * (1.f + erff(g2 * inv_sqrt2));
    v.w = 0.5f * g3 * (1.f + erff(g3 * inv_sqrt2));
    p[idx4] = v;
}

extern "C" void kernel_launch(void* const* d_in, const int* in_sizes, int n_in,
                              void* d_out, int out_size, void* d_ws, size_t ws_size,
                              hipStream_t stream) {
    const float* bev   = (const float*)d_in[0];
    const float* offw  = (const float*)d_in[1];
    const float* offb  = (const float*)d_in[2];
    const float* wtw   = (const float*)d_in[3];
    const float* wtb   = (const float*)d_in[4];
    const float* projw = (const float*)d_in[5];
    const float* gamma = (const float*)d_in[6];
    const float* beta  = (const float*)d_in[7];
    float* out = (float*)d_out;
    float* wsf = (float*)d_ws;

    float* oa    = wsf + OA_OFF;
    float* wtT   = wsf + WTT_OFF;
    float* wp    = wsf + WP_OFF;
    float* stats = wsf + STATS_OFF;
    double* part = (double*)(wsf + PART_OFF);
    ushort* bevtb = (ushort*)(wsf + BEVT_OFF);
    ushort* ybf   = (ushort*)(wsf + YBF_OFF);
    ushort* wbf  = (ushort*)(wsf + WBF_OFF);
    ushort* wcb  = (ushort*)(wsf + WCB_OFF);
    float* part2 = wsf + PART2_OFF;

    bool full3 = ws_size >= WS_NEED_FULL3;

    if (full3) {
        hipLaunchKernelGGL(k0bc, dim3(72), dim3(256), 0, stream,
                           projw, offw, wtw, wbf, wcb);
        hipLaunchKernelGGL(k2t_bf, dim3(2048), dim3(256), 0, stream, bev, bevtb);
        hipLaunchKernelGGL(k1m_conv_mfma, dim3(512), dim3(256), 0, stream,
                           bevtb, wcb, offb, wtb, oa);
        hipLaunchKernelGGL(k2f_sample_proj, dim3(4096), dim3(256), 0, stream,
                           bevtb, oa, wbf, ybf, part2);
        hipLaunchKernelGGL(k3b_finalize2, dim3(128), dim3(256), 0, stream,
                           part2, gamma, beta, stats);
        hipLaunchKernelGGL(k4_bn_gelu_bf, dim3((BB*DD*HWC)/2048), dim3(256), 0, stream,
                           ybf, stats, out);
    } else {
        hipLaunchKernelGGL(k0_prep, dim3(64), dim3(256), 0, stream,
                           projw, offw, wtw, wtT, wp);
        hipLaunchKernelGGL(k1_convs, dim3(BB*HH), dim3(256), 0, stream,
                           bev, wp, offb, wtb, oa);
        hipLaunchKernelGGL(k2_sample_proj, dim3(BB*256), dim3(512), 0, stream,
                           bev, oa, wtT, out);
        hipLaunchKernelGGL(k3_partial, dim3(512), dim3(256), 0, stream, out, part);
        hipLaunchKernelGGL(k3_finalize, dim3(1), dim3(128), 0, stream,
                           part, gamma, beta, stats);
        hipLaunchKernelGGL(k4_bn_gelu, dim3((BB*DD*HWC)/1024), dim3(256), 0, stream,
                           out, stats);
    }
}

// Round 18
// 132.459 us; speedup vs baseline: 1.2124x; 1.0309x over previous
//
#include <hip/hip_runtime.h>
#include <math.h>

#define BB 2
#define DD 128
#define HH 256
#define WW 256
#define KK 4
#define HWC (HH*WW)
#define SROW2 320   // d-slice stride in S (fused fallback kernels)

typedef unsigned int u32;
typedef unsigned short ushort;
typedef __attribute__((ext_vector_type(8))) short bf16x8;
typedef __attribute__((ext_vector_type(4))) float f32x4;

// ws float layout
#define OA_OFF    0
#define WTT_OFF   1572864
#define WP_OFF    1589248
#define STATS_OFF 1603072
#define PART_OFF  1603392
#define BEVT_OFF  1605440       // full3: bevtb bf16 (16.8M ushort = 8.39M float-slots)
#define YBF_OFF   9994048       // full3: pre-BN y bf16 (16.8M ushort) - 2nd half of BEVT region
#define PACC_OFF  18382656
#define PART2_OFF PACC_OFF      // full3: k2f block stats [wgid][256] f32
#define WBF_OFF   26771264      // proj W bf16
#define WCB_OFF   26779456      // conv W bf16 padded: 9*16*128 ushort
#define WS_NEED_BEVT  ((size_t)PACC_OFF * 4)
#define WS_NEED_FULL3 ((size_t)(WCB_OFF + 9216) * 4)

__device__ __forceinline__ u32 f2bf(float x) {
    u32 u = __builtin_bit_cast(u32, x);
    return (u + 0x7fffu + ((u >> 16) & 1u)) >> 16;
}
__device__ __forceinline__ u32 pkbf(float a, float b) {
    return f2bf(a) | (f2bf(b) << 16);
}
__device__ __forceinline__ float bflo(u32 d) { return __builtin_bit_cast(float, d << 16); }
__device__ __forceinline__ float bfhi(u32 d) { return __builtin_bit_cast(float, d & 0xffff0000u); }

// ---------------- Kernel 0: weight prep (fallback tier only) ----------------
__global__ __launch_bounds__(256) void k0_prep(
    const float* __restrict__ projw, const float* __restrict__ offw,
    const float* __restrict__ wtw, float* __restrict__ wtT, float* __restrict__ wp)
{
    int idx = blockIdx.x * 256 + threadIdx.x;
    if (idx < 16384) {
        int d = idx >> 7, o = idx & 127;
        wtT[d * 128 + o] = projw[o * 128 + d];
    }
    if (idx < 13824) {
        int c = idx / 108; int r = idx % 108; int o = r / 9; int t = r % 9;
        wp[idx] = (o < 8) ? offw[(o*128 + c)*9 + t] : wtw[((o-8)*128 + c)*9 + t];
    }
}

// ---------------- Kernel Tb: NCHW f32 -> NHWC bf16  (+ fused bf16 weight prep) ----------------
// R18: k0bc folded into the first 72 blocks (removes one dispatch + gap).  wbf/wcb
// are consumed only by k1m/k2f which launch after this kernel completes.
__global__ __launch_bounds__(256) void k2t_bf(
    const float* __restrict__ bev, ushort* __restrict__ bevtb,
    const float* __restrict__ projw, const float* __restrict__ offw,
    const float* __restrict__ wtw, ushort* __restrict__ wbf,
    ushort* __restrict__ wcb)
{
    __shared__ float T[64 * 128];
    int tid = threadIdx.x;
    int bidx = blockIdx.x;

    // fused weight prep (blocks 0..71 cover 18432 elements)
    if (bidx < 72) {
        int idx = bidx * 256 + tid;
        if (idx < 16384) wbf[idx] = (ushort)f2bf(projw[idx]);
        if (idx < 18432) {
            int tap = idx >> 11;
            int rem = idx & 2047;
            int oo = rem >> 7, c = rem & 127;
            float v = 0.f;
            if (oo < 8)       v = offw[(oo*128 + c)*9 + tap];
            else if (oo < 12) v = wtw[((oo-8)*128 + c)*9 + tap];
            wcb[idx] = (ushort)f2bf(v);
        }
    }

    int b = bidx >> 10;
    int rem = bidx & 1023;
    int yrow = rem >> 2;
    int x0 = (rem & 3) << 6;

    const float* src = bev + ((size_t)b * DD) * HWC + (size_t)yrow * WW + x0;
    #pragma unroll 4
    for (int k = 0; k < 32; k++) {
        int flat = k * 256 + tid;
        int d = flat >> 6, xl = flat & 63;
        float v = src[(size_t)d * HWC + xl];
        T[xl * 128 + (((d >> 2) ^ (xl & 31)) << 2) + (d & 3)] = v;
    }
    __syncthreads();
    ushort* dst = bevtb + (((size_t)b * HH + yrow) * WW + x0) * 128;
    #pragma unroll 4
    for (int k = 0; k < 8; k++) {
        int flat = k * 256 + tid;
        int d4 = flat & 31, xl = (flat >> 5) & 63;
        float4 v = *(const float4*)&T[xl * 128 + ((d4 ^ (xl & 31)) << 2)];
        uint2 pk;
        pk.x = pkbf(v.x, v.y);
        pk.y = pkbf(v.z, v.w);
        *(uint2*)(dst + (size_t)xl * 128 + (d4 << 2)) = pk;
    }
}

// ---------------- Kernel 1m: 3x3 convs as implicit-GEMM MFMA, ROLLING band + async stage ----------------
__global__ __launch_bounds__(256) void k1m_conv_mfma(
    const ushort* __restrict__ bevtb, const ushort* __restrict__ wcb,
    const float* __restrict__ offb, const float* __restrict__ wtb,
    float* __restrict__ oa)
{
    __shared__ uint4 lds4[3 * 1056];   // 3 row-buffers x 66 px x 16 slots x 16B = 50688 B

    int tid = threadIdx.x;
    int wv = tid >> 6;
    int l = tid & 63;
    int lm = l & 15, lk = l >> 4;
    int wgid = blockIdx.x;                      // 0..511
    int lin = (wgid & 7) * 64 + (wgid >> 3);    // bijective XCD-contiguous remap
    int b = lin >> 8;
    int band = (lin >> 2) & 63;
    int jt = lin & 3;
    int i0 = band * 4;
    int x0 = jt * 64;

    const ushort* bb = bevtb + (size_t)b * HWC * 128;

    #define STAGE_ROW(a, s) do {                                                  \
        int _a = (a); int _s = (s);                                               \
        bool rok = ((unsigned)_a < HH);                                           \
        for (int z = tid; z < 1056; z += 256) {                                   \
            int pl = z >> 4; int qq = z & 15;                                     \
            int x = x0 - 1 + pl;                                                  \
            bool ok = rok && ((unsigned)x < WW);                                  \
            uint4 v = make_uint4(0u, 0u, 0u, 0u);                                 \
            if (ok) v = *(const uint4*)(bb + ((size_t)(_a * WW + x) << 7) + qq * 8); \
            lds4[_s * 1056 + pl * 16 + (qq ^ (pl & 15))] = v;                     \
        }                                                                         \
    } while (0)

    STAGE_ROW(i0 - 1, i0 % 3);
    STAGE_ROW(i0,     (i0 + 1) % 3);
    STAGE_ROW(i0 + 1, (i0 + 2) % 3);
    __syncthreads();

    #pragma unroll
    for (int r = 0; r < 4; r++) {
        int i = i0 + r;
        int s0 = i % 3;
        int s1 = (i + 1) % 3;
        int s2 = (i + 2) % 3;
        int slots[3] = { s0, s1, s2 };

        uint4 rv[5];
        if (r < 3) {
            int a = i + 2;
            bool rok = ((unsigned)a < HH);
            #pragma unroll
            for (int u = 0; u < 5; u++) {
                int z = tid + u * 256;
                uint4 v = make_uint4(0u, 0u, 0u, 0u);
                if (z < 1056) {
                    int pl = z >> 4; int qq = z & 15;
                    int x = x0 - 1 + pl;
                    if (rok && ((unsigned)x < WW))
                        v = *(const uint4*)(bb + ((size_t)(a * WW + x) << 7) + qq * 8);
                }
                rv[u] = v;
            }
        }

        f32x4 acc = (f32x4)(0.f);
        #pragma unroll
        for (int dy = 0; dy < 3; dy++) {
            #pragma unroll
            for (int dx = 0; dx < 3; dx++) {
                int pl = wv * 16 + lm + dx;
                const uint4* bp = &lds4[slots[dy] * 1056 + pl * 16];
                int sx = pl & 15;
                const ushort* ap = wcb + (size_t)((dy*3 + dx) * 16 + lm) * 128 + lk * 8;
                #pragma unroll
                for (int kk = 0; kk < 4; kk++) {
                    bf16x8 bfr = *(const bf16x8*)&bp[(kk*4 + lk) ^ sx];
                    bf16x8 afr = *(const bf16x8*)(ap + kk * 32);
                    acc = __builtin_amdgcn_mfma_f32_16x16x32_bf16(afr, bfr, acc, 0, 0, 0);
                }
            }
        }

        float v[4];
        #pragma unroll
        for (int t = 0; t < 4; t++) v[t] = acc[t];

        int j = x0 + wv * 16 + lm;
        if (lk < 2) {
            #pragma unroll
            for (int t = 0; t < 4; t++) v[t] += offb[lk*4 + t];   // OFFSET_SCALE = 1.0
        } else if (lk == 2) {
            float l4[4];
            #pragma unroll
            for (int t = 0; t < 4; t++) l4[t] = v[t] + wtb[t];
            float m = fmaxf(fmaxf(l4[0], l4[1]), fmaxf(l4[2], l4[3]));
            float e[4]; float se = 0.f;
            #pragma unroll
            for (int t = 0; t < 4; t++) { e[t] = expf(l4[t] - m); se += e[t]; }
            float inv = 1.f / se;
            #pragma unroll
            for (int t = 0; t < 4; t++) v[t] = e[t] * inv;
        }
        if (lk < 3) {
            size_t basep = (size_t)b * 12 * HWC + (size_t)i * WW + j;
            #pragma unroll
            for (int t = 0; t < 4; t++)
                oa[basep + (size_t)(lk*4 + t) * HWC] = v[t];
        }

        __syncthreads();
        if (r < 3) {
            int s = i % 3;
            #pragma unroll
            for (int u = 0; u < 5; u++) {
                int z = tid + u * 256;
                if (z < 1056) {
                    int pl = z >> 4; int qq = z & 15;
                    lds4[s * 1056 + pl * 16 + (qq ^ (pl & 15))] = rv[u];
                }
            }
            __syncthreads();
        }
    }
    #undef STAGE_ROW
}

// ---------------- Kernel 2f: FUSED sample + 1x1 MFMA proj + BN stats ----------------
#define TAPPTR(t) (bt + ((size_t)((((t) & 1) ? (pa[(t) >> 1] >> 16) : (pa[(t) >> 1] & 0xffffu))) << 7))
#define FMA8(S, V, W) do { \
    S[0] = fmaf(W, bflo((V).x), S[0]); S[1] = fmaf(W, bfhi((V).x), S[1]); \
    S[2] = fmaf(W, bflo((V).y), S[2]); S[3] = fmaf(W, bfhi((V).y), S[3]); \
    S[4] = fmaf(W, bflo((V).z), S[4]); S[5] = fmaf(W, bfhi((V).z), S[5]); \
    S[6] = fmaf(W, bflo((V).w), S[6]); S[7] = fmaf(W, bfhi((V).w), S[7]); \
} while (0)

__global__ __launch_bounds__(256, 4) void k2f_sample_proj(
    const ushort* __restrict__ bevtb, const float* __restrict__ oa,
    const ushort* __restrict__ wbf, ushort* __restrict__ ybf,
    float* __restrict__ part2)
{
    __shared__ uint4 P[32 * 16];   // 8 KB

    int tid = threadIdx.x;
    int wgid = blockIdx.x;                       // 0..4095
    int lin = (wgid & 7) * 512 + (wgid >> 3);    // bijective XCD-contiguous remap
    int b = lin >> 11;
    int pix0 = (lin & 2047) << 5;                // 32 px per block

    int q8 = tid & 7;
    int pixl = tid >> 3;                         // 0..31
    int pix = pix0 + pixl;
    int p = pix >> 8;
    int q = pix & 255;

    const float* ob = oa + (size_t)b * 12 * HWC + (size_t)p * WW + q;
    unsigned pa[8]; float cw[16];
    #pragma unroll
    for (int k = 0; k < 4; k++) {
        float dx = ob[(size_t)(2*k)   * HWC];
        float dy = ob[(size_t)(2*k+1) * HWC];
        float a  = ob[(size_t)(8+k)   * HWC];
        float x  = fminf(fmaxf((float)p + dx, 0.f), (float)(WW-1));
        float yv = fminf(fmaxf((float)q + dy, 0.f), (float)(HH-1));
        float x0f = floorf(x); float y0f = floorf(yv);
        int x0 = (int)x0f; int y0 = (int)y0f;
        int x1 = min(x0 + 1, WW - 1); int y1 = min(y0 + 1, HH - 1);
        float wx = x - x0f; float wy = yv - y0f;
        pa[k*2+0] = (unsigned)(y0*WW + x0) | ((unsigned)(y0*WW + x1) << 16);
        pa[k*2+1] = (unsigned)(y1*WW + x0) | ((unsigned)(y1*WW + x1) << 16);
        cw[k*4+0] = a * (1.f - wx) * (1.f - wy);
        cw[k*4+1] = a * wx * (1.f - wy);
        cw[k*4+2] = a * (1.f - wx) * wy;
        cw[k*4+3] = a * wx * wy;
    }

    const ushort* bt = bevtb + (size_t)b * HWC * 128 + q8 * 8;

    float s[2][8];
    #pragma unroll
    for (int c = 0; c < 2; c++)
        #pragma unroll
        for (int e = 0; e < 8; e++) s[c][e] = 0.f;

    uint4 L0[8], L1[8];
    #pragma unroll
    for (int t = 0; t < 8; t++) L0[t] = *(const uint4*)(TAPPTR(t));
    #pragma unroll
    for (int t = 0; t < 8; t++) L1[t] = *(const uint4*)(TAPPTR(t + 8));
    #pragma unroll
    for (int t = 0; t < 8; t++) {
        uint4 v = L0[t];
        L0[t] = *(const uint4*)(TAPPTR(t) + 64);
        FMA8(s[0], v, cw[t]);
    }
    #pragma unroll
    for (int t = 0; t < 8; t++) {
        uint4 v = L1[t];
        L1[t] = *(const uint4*)(TAPPTR(t + 8) + 64);
        FMA8(s[0], v, cw[t + 8]);
    }
    #pragma unroll
    for (int t = 0; t < 8; t++) FMA8(s[1], L0[t], cw[t]);
    #pragma unroll
    for (int t = 0; t < 8; t++) FMA8(s[1], L1[t], cw[t + 8]);

    int sxr = pixl & 15;
    #pragma unroll
    for (int c = 0; c < 2; c++) {
        uint4 pk;
        pk.x = pkbf(s[c][0], s[c][1]);
        pk.y = pkbf(s[c][2], s[c][3]);
        pk.z = pkbf(s[c][4], s[c][5]);
        pk.w = pkbf(s[c][6], s[c][7]);
        P[pixl * 16 + ((c * 8 + q8) ^ sxr)] = pk;
    }
    __syncthreads();

    int wv = tid >> 6;
    int l = tid & 63;
    int lm = l & 15, lk = l >> 4;
    int o0 = wv << 5;

    f32x4 acc[2][2];
    #pragma unroll
    for (int ot = 0; ot < 2; ot++)
        #pragma unroll
        for (int nt = 0; nt < 2; nt++)
            acc[ot][nt] = (f32x4)(0.f);

    #pragma unroll
    for (int ot = 0; ot < 2; ot++) {
        const ushort* ap = wbf + (size_t)(o0 + ot * 16 + lm) * 128 + lk * 8;
        bf16x8 a4[4];
        #pragma unroll
        for (int kk = 0; kk < 4; kk++)
            a4[kk] = *(const bf16x8*)(ap + kk * 32);
        #pragma unroll
        for (int nt = 0; nt < 2; nt++) {
            int row = nt * 16 + lm;
            #pragma unroll
            for (int kk = 0; kk < 4; kk++) {
                bf16x8 bfr = *(const bf16x8*)&P[row * 16 + ((kk * 4 + lk) ^ lm)];
                acc[ot][nt] = __builtin_amdgcn_mfma_f32_16x16x32_bf16(
                    a4[kk], bfr, acc[ot][nt], 0, 0, 0);
            }
        }
    }

    #pragma unroll
    for (int ot = 0; ot < 2; ot++)
        #pragma unroll
        for (int nt = 0; nt < 2; nt++)
            #pragma unroll
            for (int r = 0; r < 4; r++)
                ybf[((size_t)b * DD + o0 + ot * 16 + lk * 4 + r) * HWC + pix0 + nt * 16 + lm]
                    = (ushort)f2bf(acc[ot][nt][r]);

    float sm[2][4], sq[2][4];
    #pragma unroll
    for (int ot = 0; ot < 2; ot++)
        #pragma unroll
        for (int r = 0; r < 4; r++) { sm[ot][r] = 0.f; sq[ot][r] = 0.f; }
    #pragma unroll
    for (int ot = 0; ot < 2; ot++)
        #pragma unroll
        for (int nt = 0; nt < 2; nt++)
            #pragma unroll
            for (int r = 0; r < 4; r++) {
                float v = acc[ot][nt][r];
                sm[ot][r] += v;
                sq[ot][r] = fmaf(v, v, sq[ot][r]);
            }
    #pragma unroll
    for (int m = 1; m < 16; m <<= 1) {
        #pragma unroll
        for (int ot = 0; ot < 2; ot++)
            #pragma unroll
            for (int r = 0; r < 4; r++) {
                sm[ot][r] += __shfl_xor(sm[ot][r], m);
                sq[ot][r] += __shfl_xor(sq[ot][r], m);
            }
    }
    if (lm == 0) {
        float* pw = part2 + (size_t)wgid * 256;
        #pragma unroll
        for (int ot = 0; ot < 2; ot++)
            #pragma unroll
            for (int r = 0; r < 4; r++) {
                int o = o0 + ot * 16 + lk * 4 + r;
                pw[o] = sm[ot][r];
                pw[128 + o] = sq[ot][r];
            }
    }
}

// ---------------- Kernel 3b': finalize BN from k2f block partials ----------------
__global__ __launch_bounds__(256) void k3b_finalize2(
    const float* __restrict__ part2, const float* __restrict__ gamma,
    const float* __restrict__ beta, float* __restrict__ stats)
{
    int o = blockIdx.x; int tid = threadIdx.x;
    double s = 0.0, s2 = 0.0;
    for (int w = tid; w < 4096; w += 256) {
        s  += (double)part2[(size_t)w * 256 + o];
        s2 += (double)part2[(size_t)w * 256 + 128 + o];
    }
    __shared__ double ls[256], ls2[256];
    ls[tid] = s; ls2[tid] = s2;
    __syncthreads();
    for (int off = 128; off > 0; off >>= 1) {
        if (tid < off) { ls[tid] += ls[tid+off]; ls2[tid] += ls2[tid+off]; }
        __syncthreads();
    }
    if (tid == 0) {
        double N = (double)(BB * HWC);
        double mean = ls[0] / N;
        double var = ls2[0] / N - mean * mean;
        double invs = 1.0 / sqrt(var + 1e-5);
        double g = (double)gamma[o];
        stats[o*2]   = (float)(g * invs);
        stats[o*2+1] = (float)((double)beta[o] - mean * g * invs);
    }
}

// ---------------- Kernel 4bf: BN + exact GELU, bf16 y -> f32 out ----------------
__global__ __launch_bounds__(256) void k4_bn_gelu_bf(
    const ushort* __restrict__ ybf, const float* __restrict__ stats,
    float* __restrict__ out)
{
    size_t idx8 = (size_t)blockIdx.x * 256 + threadIdx.x;   // 8-elem index
    uint4 v = ((const uint4*)ybf)[idx8];
    int o = (int)((idx8 * 8) / HWC) % DD;
    float sc = stats[o*2], sh = stats[o*2+1];
    const float is2 = 0.70710678118654752f;
    float g[8];
    g[0] = fmaf(bflo(v.x), sc, sh); g[1] = fmaf(bfhi(v.x), sc, sh);
    g[2] = fmaf(bflo(v.y), sc, sh); g[3] = fmaf(bfhi(v.y), sc, sh);
    g[4] = fmaf(bflo(v.z), sc, sh); g[5] = fmaf(bfhi(v.z), sc, sh);
    g[6] = fmaf(bflo(v.w), sc, sh); g[7] = fmaf(bfhi(v.w), sc, sh);
    float4 o0, o1;
    o0.x = 0.5f * g[0] * (1.f + erff(g[0] * is2));
    o0.y = 0.5f * g[1] * (1.f + erff(g[1] * is2));
    o0.z = 0.5f * g[2] * (1.f + erff(g[2] * is2));
    o0.w = 0.5f * g[3] * (1.f + erff(g[3] * is2));
    o1.x = 0.5f * g[4] * (1.f + erff(g[4] * is2));
    o1.y = 0.5f * g[5] * (1.f + erff(g[5] * is2));
    o1.z = 0.5f * g[6] * (1.f + erff(g[6] * is2));
    o1.w = 0.5f * g[7] * (1.f + erff(g[7] * is2));
    ((float4*)out)[idx8 * 2]     = o0;
    ((float4*)out)[idx8 * 2 + 1] = o1;
}

// ---------------- Kernel 1 (fallback): full 128-channel conv ----------------
__global__ __launch_bounds__(256) void k1_convs(
    const float* __restrict__ bev, const float* __restrict__ wp,
    const float* __restrict__ offb, const float* __restrict__ wtb,
    float* __restrict__ oa)
{
    __shared__ float rows[2][3][260];
    int tid = threadIdx.x;
    int p = blockIdx.x;
    int b = p / HH; int i = p % HH; int j = tid;
    const float* bb = bev + (size_t)b * DD * HWC;

    if (tid < 12) { int bf = tid / 6, r = tid % 6; rows[bf][r >> 1][(r & 1) ? 257 : 0] = 0.f; }
    #pragma unroll
    for (int l = 0; l < 3; l++) {
        int yy = i + l - 1;
        rows[0][l][1 + tid] = ((unsigned)yy < HH) ? bb[yy * WW + tid] : 0.f;
    }
    __syncthreads();

    float acc[12];
    #pragma unroll
    for (int o = 0; o < 12; o++) acc[o] = 0.f;

    for (int c = 0; c < 128; c++) {
        int cb = c & 1, nb = cb ^ 1;
        float rv[3];
        if (c < 127) {
            const float* pln = bb + (size_t)(c + 1) * HWC;
            #pragma unroll
            for (int l = 0; l < 3; l++) {
                int yy = i + l - 1;
                rv[l] = ((unsigned)yy < HH) ? pln[yy * WW + tid] : 0.f;
            }
        }
        float v[9];
        #pragma unroll
        for (int dy = 0; dy < 3; dy++)
            #pragma unroll
            for (int dx = 0; dx < 3; dx++)
                v[dy*3 + dx] = rows[cb][dy][tid + dx];
        const float* wc = wp + c * 108;
        #pragma unroll
        for (int o = 0; o < 12; o++) {
            float s = acc[o];
            #pragma unroll
            for (int t = 0; t < 9; t++) s = fmaf(wc[o*9 + t], v[t], s);
            acc[o] = s;
        }
        if (c < 127) {
            #pragma unroll
            for (int l = 0; l < 3; l++) rows[nb][l][1 + tid] = rv[l];
        }
        __syncthreads();
    }

    float outv[12];
    #pragma unroll
    for (int o = 0; o < 8; o++) outv[o] = acc[o] + offb[o];
    float l4[4];
    #pragma unroll
    for (int k = 0; k < 4; k++) l4[k] = acc[8+k] + wtb[k];
    float m = fmaxf(fmaxf(l4[0], l4[1]), fmaxf(l4[2], l4[3]));
    float e[4]; float se = 0.f;
    #pragma unroll
    for (int k = 0; k < 4; k++) { e[k] = expf(l4[k] - m); se += e[k]; }
    float inv = 1.f / se;
    #pragma unroll
    for (int k = 0; k < 4; k++) outv[8+k] = e[k] * inv;

    size_t basep = (size_t)b * 12 * HWC + (size_t)i * WW + j;
    #pragma unroll
    for (int o = 0; o < 12; o++) oa[basep + (size_t)o * HWC] = outv[o];
}

// ---------------- Kernel 2 fallback (NCHW) ----------------
__global__ __launch_bounds__(512, 2) void k2_sample_proj(
    const float* __restrict__ bev, const float* __restrict__ oa,
    const float* __restrict__ wt, float* __restrict__ y)
{
    __shared__ float S[2][16 * SROW2];
    int tid = threadIdx.x;
    int bidx = blockIdx.x;
    int b  = bidx >> 8;
    int p0 = ((bidx >> 4) & 15) * 16;
    int q0 = (bidx & 15) * 16;
    int pix = tid & 255;
    int gq = pix >> 4;
    int gp = pix & 15;
    int dgrp = tid >> 8;
    int swr = gp * 20 + gq;
    int wv = tid >> 6;
    int wvu = __builtin_amdgcn_readfirstlane(wv);
    int lane = tid & 63;
    int lp = lane >> 2;
    int q4 = (lane & 3) << 2;
    int soff = lp * 20 + q4;

    const float* ob = oa + (size_t)b * 12 * HWC + (size_t)(p0 + gp) * WW + (q0 + gq);
    unsigned pa[8]; float cw[16];
    #pragma unroll
    for (int k = 0; k < 4; k++) {
        float dx = ob[(size_t)(2*k)   * HWC];
        float dy = ob[(size_t)(2*k+1) * HWC];
        float a  = ob[(size_t)(8+k)   * HWC];
        float x  = fminf(fmaxf((float)(p0 + gp) + dx, 0.f), (float)(WW-1));
        float yv = fminf(fmaxf((float)(q0 + gq) + dy, 0.f), (float)(HH-1));
        float x0f = floorf(x); float y0f = floorf(yv);
        int x0 = (int)x0f; int y0 = (int)y0f;
        int x1 = min(x0 + 1, WW - 1); int y1 = min(y0 + 1, HH - 1);
        float wx = x - x0f; float wy = yv - y0f;
        pa[k*2+0] = (unsigned)(y0*WW + x0) | ((unsigned)(y0*WW + x1) << 16);
        pa[k*2+1] = (unsigned)(y1*WW + x0) | ((unsigned)(y1*WW + x1) << 16);
        cw[k*4+0] = a * (1.f - wx) * (1.f - wy);
        cw[k*4+1] = a * wx * (1.f - wy);
        cw[k*4+2] = a * (1.f - wx) * wy;
        cw[k*4+3] = a * wx * wy;
    }
    const float* bb = bev + (size_t)b * DD * HWC;
    float acc[64];
    #pragma unroll
    for (int t = 0; t < 64; t++) acc[t] = 0.f;
    #pragma unroll
    for (int dd = 0; dd < 8; dd++) {
        const float* pl = bb + (size_t)(dgrp*8 + dd) * HWC;
        float s = 0.f;
        #pragma unroll
        for (int t = 0; t < 8; t++) {
            unsigned a01 = pa[t];
            s = fmaf(cw[2*t],   pl[a01 & 0xffffu], s);
            s = fmaf(cw[2*t+1], pl[a01 >> 16], s);
        }
        S[0][(dgrp*8 + dd) * SROW2 + swr] = s;
    }
    __syncthreads();
    for (int c = 0; c < 8; c++) {
        int cur = c & 1;
        const float* Sc = &S[cur][0];
        float* Sn = &S[cur ^ 1][0];
        int d0 = c * 16;
        int d0n = d0 + 16;
        bool more = (c < 7);
        #pragma unroll
        for (int dl = 0; dl < 16; dl++) {
            if (dl < 8) {
                if (more) {
                    const float* pl = bb + (size_t)(d0n + dgrp*8 + dl) * HWC;
                    float s = 0.f;
                    #pragma unroll
                    for (int t = 0; t < 8; t++) {
                        unsigned a01 = pa[t];
                        s = fmaf(cw[2*t],   pl[a01 & 0xffffu], s);
                        s = fmaf(cw[2*t+1], pl[a01 >> 16], s);
                    }
                    Sn[(dgrp*8 + dl) * SROW2 + swr] = s;
                }
            }
            float4 sv = *(const float4*)(Sc + dl * SROW2 + soff);
            const float4* wq = (const float4*)(wt + (size_t)(d0 + dl) * 128 + wvu * 16);
            #pragma unroll
            for (int oi4 = 0; oi4 < 4; oi4++) {
                float4 w4 = wq[oi4];
                int ob4 = oi4 * 16;
                acc[ob4+ 0] = fmaf(w4.x, sv.x, acc[ob4+ 0]);
                acc[ob4+ 1] = fmaf(w4.x, sv.y, acc[ob4+ 1]);
                acc[ob4+ 2] = fmaf(w4.x, sv.z, acc[ob4+ 2]);
                acc[ob4+ 3] = fmaf(w4.x, sv.w, acc[ob4+ 3]);
                acc[ob4+ 4] = fmaf(w4.y, sv.x, acc[ob4+ 4]);
                acc[ob4+ 5] = fmaf(w4.y, sv.y, acc[ob4+ 5]);
                acc[ob4+ 6] = fmaf(w4.y, sv.z, acc[ob4+ 6]);
                acc[ob4+ 7] = fmaf(w4.y, sv.w, acc[ob4+ 7]);
                acc[ob4+ 8] = fmaf(w4.z, sv.x, acc[ob4+ 8]);
                acc[ob4+ 9] = fmaf(w4.z, sv.y, acc[ob4+ 9]);
                acc[ob4+10] = fmaf(w4.z, sv.z, acc[ob4+10]);
                acc[ob4+11] = fmaf(w4.z, sv.w, acc[ob4+11]);
                acc[ob4+12] = fmaf(w4.w, sv.x, acc[ob4+12]);
                acc[ob4+13] = fmaf(w4.w, sv.y, acc[ob4+13]);
                acc[ob4+14] = fmaf(w4.w, sv.z, acc[ob4+14]);
                acc[ob4+15] = fmaf(w4.w, sv.w, acc[ob4+15]);
            }
        }
        __syncthreads();
    }
    size_t base = (size_t)b * DD * HWC + (size_t)(p0 + lp) * WW + (q0 + q4);
    #pragma unroll
    for (int oi = 0; oi < 16; oi++) {
        int o = wv * 16 + oi;
        float4 v = make_float4(acc[oi*4+0], acc[oi*4+1], acc[oi*4+2], acc[oi*4+3]);
        *(float4*)(y + base + (size_t)o * HWC) = v;
    }
}

// ---------------- Kernel 3a/3b: BN stats (fallback tier only) ----------------
__global__ __launch_bounds__(256) void k3_partial(
    const float* __restrict__ y, double* __restrict__ part)
{
    int blk = blockIdx.x;
    int o = blk >> 2; int sub = blk & 3; int b = sub >> 1; int half = sub & 1;
    const float4* pl = (const float4*)(y + ((size_t)b * DD + o) * HWC + half * (HWC/2));
    int tid = threadIdx.x;
    double s = 0.0, s2 = 0.0;
    for (int idx = tid; idx < HWC/8; idx += 256) {
        float4 v = pl[idx];
        s  += (double)v.x + (double)v.y + (double)v.z + (double)v.w;
        s2 += (double)v.x*v.x + (double)v.y*v.y + (double)v.z*v.z + (double)v.w*v.w;
    }
    __shared__ double ls[256], ls2[256];
    ls[tid] = s; ls2[tid] = s2;
    __syncthreads();
    for (int off = 128; off > 0; off >>= 1) {
        if (tid < off) { ls[tid] += ls[tid+off]; ls2[tid] += ls2[tid+off]; }
        __syncthreads();
    }
    if (tid == 0) { part[blk*2] = ls[0]; part[blk*2+1] = ls2[0]; }
}

__global__ __launch_bounds__(128) void k3_finalize(
    const double* __restrict__ part, const float* __restrict__ gamma,
    const float* __restrict__ beta, float* __restrict__ stats)
{
    int o = threadIdx.x;
    double s = 0.0, s2 = 0.0;
    #pragma unroll
    for (int j = 0; j < 4; j++) { s += part[(o*4+j)*2]; s2 += part[(o*4+j)*2+1]; }
    double N = (double)(BB * HWC);
    double mean = s / N;
    double var = s2 / N - mean * mean;
    double invs = 1.0 / sqrt(var + 1e-5);
    double g = (double)gamma[o];
    stats[o*2]   = (float)(g * invs);
    stats[o*2+1] = (float)((double)beta[o] - mean * g * invs);
}

// ---------------- Kernel 4: BN + exact GELU, f32 in-place (fallback tier) ----------------
__global__ __launch_bounds__(256) void k4_bn_gelu(
    float* __restrict__ y, const float* __restrict__ stats)
{
    size_t idx4 = (size_t)blockIdx.x * 256 + threadIdx.x;
    float4* p = (float4*)y;
    float4 v = p[idx4];
    int o = (int)((idx4 * 4) / HWC) % DD;
    float sc = stats[o*2], sh = stats[o*2+1];
    const float inv_sqrt2 = 0.70710678118654752f;
    float g0 = fmaf(v.x, sc, sh);
    float g1 = fmaf(v.y, sc, sh);
    float g2 = fmaf(v.z, sc, sh);
    float g3 = fmaf(v.w, sc, sh);
    v.x = 0.5f * g0 * (1.f + erff(g0 * inv_sqrt2));
    v.y = 0.5f * g1 * (1.f + erff(g1 * inv_sqrt2));
    v.z = 0.5f * g2 * (1.f + erff(g2 * inv_sqrt2));
    v.w = 0.5f * g3 * (1.f + erff(g3 * inv_sqrt2));
    p[idx4] = v;
}

extern "C" void kernel_launch(void* const* d_in, const int* in_sizes, int n_in,
                              void* d_out, int out_size, void* d_ws, size_t ws_size,
                              hipStream_t stream) {
    const float* bev   = (const float*)d_in[0];
    const float* offw  = (const float*)d_in[1];
    const float* offb  = (const float*)d_in[2];
    const float* wtw   = (const float*)d_in[3];
    const float* wtb   = (const float*)d_in[4];
    const float* projw = (const float*)d_in[5];
    const float* gamma = (const float*)d_in[6];
    const float* beta  = (const float*)d_in[7];
    float* out = (float*)d_out;
    float* wsf = (float*)d_ws;

    float* oa    = wsf + OA_OFF;
    float* wtT   = wsf + WTT_OFF;
    float* wp    = wsf + WP_OFF;
    float* stats = wsf + STATS_OFF;
    double* part = (double*)(wsf + PART_OFF);
    ushort* bevtb = (ushort*)(wsf + BEVT_OFF);
    ushort* ybf   = (ushort*)(wsf + YBF_OFF);
    ushort* wbf  = (ushort*)(wsf + WBF_OFF);
    ushort* wcb  = (ushort*)(wsf + WCB_OFF);
    float* part2 = wsf + PART2_OFF;

    bool full3 = ws_size >= WS_NEED_FULL3;

    if (full3) {
        hipLaunchKernelGGL(k2t_bf, dim3(2048), dim3(256), 0, stream,
                           bev, bevtb, projw, offw, wtw, wbf, wcb);
        hipLaunchKernelGGL(k1m_conv_mfma, dim3(512), dim3(256), 0, stream,
                           bevtb, wcb, offb, wtb, oa);
        hipLaunchKernelGGL(k2f_sample_proj, dim3(4096), dim3(256), 0, stream,
                           bevtb, oa, wbf, ybf, part2);
        hipLaunchKernelGGL(k3b_finalize2, dim3(128), dim3(256), 0, stream,
                           part2, gamma, beta, stats);
        hipLaunchKernelGGL(k4_bn_gelu_bf, dim3((BB*DD*HWC)/2048), dim3(256), 0, stream,
                           ybf, stats, out);
    } else {
        hipLaunchKernelGGL(k0_prep, dim3(64), dim3(256), 0, stream,
                           projw, offw, wtw, wtT, wp);
        hipLaunchKernelGGL(k1_convs, dim3(BB*HH), dim3(256), 0, stream,
                           bev, wp, offb, wtb, oa);
        hipLaunchKernelGGL(k2_sample_proj, dim3(BB*256), dim3(512), 0, stream,
                           bev, oa, wtT, out);
        hipLaunchKernelGGL(k3_partial, dim3(512), dim3(256), 0, stream, out, part);
        hipLaunchKernelGGL(k3_finalize, dim3(1), dim3(128), 0, stream,
                           part, gamma, beta, stats);
        hipLaunchKernelGGL(k4_bn_gelu, dim3((BB*DD*HWC)/1024), dim3(256), 0, stream,
                           out, stats);
    }
}